// Round 6
// baseline (1104.201 us; speedup 1.0000x reference)
//
#include <hip/hip_runtime.h>
#include <hip/hip_bf16.h>

#define Bq    4
#define NPTS  16384
#define SPTS  2048
#define NCH   8
#define SCH   (SPTS/NCH)   // 256
#define CNTF  65536.0f
#define BNEPS 1e-5f

typedef unsigned short u16t;
typedef unsigned int   u32t;
typedef __attribute__((ext_vector_type(8))) short s16x8;
typedef __attribute__((ext_vector_type(4))) float f32x4;

__device__ __forceinline__ float b2f(u16t u){
  union { u32t i; float f; } v; v.i = ((u32t)u) << 16; return v.f;
}
__device__ __forceinline__ u16t f2b(float f){
  __hip_bfloat16 h = __float2bfloat16(f);
  return *reinterpret_cast<u16t*>(&h);
}
__device__ __forceinline__ float lrelu(float x){ return x >= 0.0f ? x : 0.2f*x; }

// ---- stats f32 offsets: per-channel [sum,sumsq] pairs ----
#define ST_WG  0
#define ST_WX  128
#define ST_PSI 256
#define ST_BN1 272
#define ST_BN2 784

// ---- bf16 weight element offsets inside WB region ----
#define WOFF_C1 0
#define WOFF_C2 98304
#define WOFF_WG 131072
#define WOFF_WX 147456
#define WTOTAL  155648

// ---- ws byte offsets (time-disjoint aliasing; total ~84.6 MB) ----
#define O_STATS  0u
#define O_WB     8192u
#define O_PSIPRE 319488u
#define O_P2T    581632u        // 4 MB bf16 [B][S][256]
#define O_P1T    4775936u       // 16.7 MB bf16 [B][N][128]; psi-scaled IN PLACE
#define O_INT    21553152u      // 33.5 MB bf16 [B][N][256] interp; h2t aliases later
#define O_H1     55107584u      // 33.5 MB bf16 [B][N][256] h1; bnrelu IN PLACE
// knn scratch lives inside the (not-yet-written) H1 region:
#define O_PD     O_H1                    // 6.29 MB f32 partial dists [B][N][NCH][3]
#define O_PI     (O_H1 + 6291456u)       // 6.29 MB i32 partial idx
#define O_IDX3   (O_H1 + 12582912u)      // 786 KB
#define O_W3     (O_H1 + 13369344u)      // 786 KB (all dead before ygt written)
#define O_YG     O_H1                    // ygt/yxt live steps 5-8, dead before h1 written
#define O_YX     (O_H1 + 8388608u)
#define O_H2     O_INT                   // h2 bf16, written after interp dead
// end = 55107584 + 33554432 = 88662016 B

// ---- 3-NN part 1: per-chunk top-3 over SCH s-points (full occupancy) ----
__global__ __launch_bounds__(256) void knn_part_kernel(const float* __restrict__ xyz1, const float* __restrict__ xyz2,
                                                       float* __restrict__ pd, int* __restrict__ pi){
  __shared__ float4 sp[SCH];
  const int b = blockIdx.z;
  const int c = blockIdx.y;
  const int t = threadIdx.x;
  {
    int s = c*SCH + t;
    float x = xyz2[(b*3+0)*SPTS+s];
    float y = xyz2[(b*3+1)*SPTS+s];
    float z = xyz2[(b*3+2)*SPTS+s];
    sp[t] = make_float4(x, y, z, x*x+y*y+z*z);
  }
  __syncthreads();
  const int n = blockIdx.x*256 + t;
  float px = xyz1[(b*3+0)*NPTS+n];
  float py = xyz1[(b*3+1)*NPTS+n];
  float pz = xyz1[(b*3+2)*NPTS+n];
  float s1 = px*px+py*py+pz*pz;
  float d0=3.4e38f, d1=3.4e38f, d2=3.4e38f;
  int   i0=0, i1=0, i2=0;
  for (int s=0; s<SCH; ++s){
    float4 q = sp[s];
    float dot = fmaf(pz, q.z, fmaf(py, q.y, px*q.x));
    float key = (s1 + q.w) - 2.0f*dot;   // same arithmetic as passing round-4 scan
    if (key < d2){
      int gi = c*SCH + s;
      if (key < d1){
        if (key < d0){ d2=d1; i2=i1; d1=d0; i1=i0; d0=key; i0=gi; }
        else         { d2=d1; i2=i1; d1=key; i1=gi; }
      } else         { d2=key; i2=gi; }
    }
  }
  size_t base = (((size_t)b*NPTS + n)*NCH + c)*3;
  pd[base]=d0; pd[base+1]=d1; pd[base+2]=d2;
  pi[base]=i0; pi[base+1]=i1; pi[base+2]=i2;
}

// ---- 3-NN part 2: merge NCH partial top-3 lists (chunk-order => stable ties) ----
__global__ __launch_bounds__(256) void knn_merge_kernel(const float* __restrict__ pd, const int* __restrict__ pi,
                                                        int* __restrict__ idx3, float* __restrict__ w3){
  const int p = blockIdx.x*256 + threadIdx.x;   // [0, B*N)
  const float* dp = pd + (size_t)p*NCH*3;
  const int*   ip = pi + (size_t)p*NCH*3;
  float d0=3.4e38f, d1=3.4e38f, d2=3.4e38f;
  int   i0=0, i1=0, i2=0;
  #pragma unroll
  for (int k=0; k<NCH*3; ++k){
    float key = dp[k]; int gi = ip[k];
    if (key < d2){
      if (key < d1){
        if (key < d0){ d2=d1; i2=i1; d1=d0; i1=i0; d0=key; i0=gi; }
        else         { d2=d1; i2=i1; d1=key; i1=gi; }
      } else         { d2=key; i2=gi; }
    }
  }
  float r0=1.0f/(d0+1e-8f), r1=1.0f/(d1+1e-8f), r2=1.0f/(d2+1e-8f);
  float rs = r0+r1+r2;
  size_t base = (size_t)p*3;
  idx3[base]=i0; idx3[base+1]=i1; idx3[base+2]=i2;
  w3[base]=r0/rs; w3[base+1]=r1/rs; w3[base+2]=r2/rs;
}

// ---- tiled transpose: src f32 [B][C][NN] -> dst bf16 [B][NN][C] ----
template<int C, int NN>
__global__ __launch_bounds__(256) void tpose_kernel(const float* __restrict__ src, u16t* __restrict__ dst){
  __shared__ float tile[64][65];
  const int n0 = blockIdx.x * 64;
  const int c0 = blockIdx.y * 64;
  const int b  = blockIdx.z;
  const int t  = threadIdx.x;
  #pragma unroll
  for (int i = 0; i < 16; ++i){
    int idx = t + i*256;
    int cc = idx >> 6, nn = idx & 63;
    tile[cc][nn] = src[((size_t)b*C + c0 + cc)*NN + n0 + nn];
  }
  __syncthreads();
  #pragma unroll
  for (int i = 0; i < 16; ++i){
    int idx = t + i*256;
    int nn = idx >> 6, cc = idx & 63;
    dst[((size_t)b*NN + n0 + nn)*C + c0 + cc] = f2b(tile[cc][nn]);
  }
}

// ---- weight convert f32 -> bf16 into WB ----
__global__ __launch_bounds__(256) void wcvt_kernel(const float* __restrict__ w1, const float* __restrict__ w2,
                                                   const float* __restrict__ wg, const float* __restrict__ wx,
                                                   u16t* __restrict__ wb){
  int i = blockIdx.x*256 + threadIdx.x;
  if (i >= WTOTAL) return;
  float v;
  if      (i < WOFF_C2) v = w1[i];
  else if (i < WOFF_WG) v = w2[i - WOFF_C2];
  else if (i < WOFF_WX) v = wg[i - WOFF_WG];
  else                  v = wx[i - WOFF_WX];
  wb[i] = f2b(v);
}

// ---- interp: point-major out [B][N][256] ----
__global__ __launch_bounds__(256) void interp_kernel(const u16t* __restrict__ p2t, const int* __restrict__ idx3,
                                                     const float* __restrict__ w3, u16t* __restrict__ it){
  const int bid = blockIdx.x;
  const int b = bid >> 8;
  const int n0 = (bid & 255) * 64;
  const int wv = threadIdx.x >> 6;
  const int lane = threadIdx.x & 63;
  const int n = n0 + lane;
  size_t pb = ((size_t)b*NPTS + n)*3;
  int i0 = idx3[pb], i1 = idx3[pb+1], i2 = idx3[pb+2];
  float w0 = w3[pb], w1 = w3[pb+1], w2 = w3[pb+2];
  const u16t* r0 = p2t + ((size_t)b*SPTS + i0)*256;
  const u16t* r1 = p2t + ((size_t)b*SPTS + i1)*256;
  const u16t* r2 = p2t + ((size_t)b*SPTS + i2)*256;
  u16t* orow = it + ((size_t)b*NPTS + n)*256;
  for (int c = wv*64; c < wv*64 + 64; c += 8){
    uint4 q0 = *reinterpret_cast<const uint4*>(r0 + c);
    uint4 q1 = *reinterpret_cast<const uint4*>(r1 + c);
    uint4 q2 = *reinterpret_cast<const uint4*>(r2 + c);
    const u32t* a0 = reinterpret_cast<const u32t*>(&q0);
    const u32t* a1 = reinterpret_cast<const u32t*>(&q1);
    const u32t* a2 = reinterpret_cast<const u32t*>(&q2);
    u32t ow[4];
    #pragma unroll
    for (int j = 0; j < 4; ++j){
      u32t u0 = a0[j], u1 = a1[j], u2 = a2[j];
      float lo = fmaf(w2, b2f((u16t)u2), fmaf(w1, b2f((u16t)u1), w0*b2f((u16t)u0)));
      float hi = fmaf(w2, b2f((u16t)(u2>>16)), fmaf(w1, b2f((u16t)(u1>>16)), w0*b2f((u16t)(u0>>16))));
      ow[j] = (u32t)f2b(lo) | ((u32t)f2b(hi) << 16);
    }
    *reinterpret_cast<uint4*>(orow + c) = make_uint4(ow[0], ow[1], ow[2], ow[3]);
  }
}

// ---- MFMA conv1x1 + FUSED batch stats ----
// y[B][N][OUT] = W[OUT][CIN] . x[B][N][CIN] + bias (raw, pre-BN)
// stats[c*2],[c*2+1] += sum/sumsq of f32 outputs (pre-bf16-rounding; closer to ref than bf16)
template<int CIN, int OUT, bool SPLIT>
__global__ __launch_bounds__(256, 1) void mfma_conv_kernel(const u16t* __restrict__ xa, const u16t* __restrict__ xb,
                                                           const u16t* __restrict__ W, const float* __restrict__ bias,
                                                           u16t* __restrict__ y, float* __restrict__ stats){
  constexpr int MW = OUT/4;      // per-wave M slice
  constexpr int MF = MW/16;      // m-fragments per wave
  constexpr int KS = CIN/32;     // k-steps
  const int bid = blockIdx.x;
  const int b = bid >> 8;
  const int n0 = (bid & 255) * 64;
  const int wv = threadIdx.x >> 6;
  const int lane = threadIdx.x & 63;
  const int lr = lane & 15;
  const int kg = lane >> 4;
  const int m0 = wv * MW;

  f32x4 acc[MF][4];
  #pragma unroll
  for (int mf = 0; mf < MF; ++mf)
    #pragma unroll
    for (int nf = 0; nf < 4; ++nf){ acc[mf][nf][0]=0.f; acc[mf][nf][1]=0.f; acc[mf][nf][2]=0.f; acc[mf][nf][3]=0.f; }

  const u16t* bA[4]; const u16t* bB[4];
  #pragma unroll
  for (int nf = 0; nf < 4; ++nf){
    int n = n0 + nf*16 + lr;
    if (SPLIT){
      bA[nf] = xa + ((size_t)b*NPTS + n)*128 + kg*8;
      bB[nf] = xb + ((size_t)b*NPTS + n)*256 + kg*8;
    } else {
      bA[nf] = xa + ((size_t)b*NPTS + n)*CIN + kg*8;
    }
  }

  #pragma unroll
  for (int k0 = 0; k0 < KS; ++k0){
    s16x8 av[MF];
    #pragma unroll
    for (int mf = 0; mf < MF; ++mf)
      av[mf] = *reinterpret_cast<const s16x8*>(W + (size_t)(m0 + mf*16 + lr)*CIN + k0*32 + kg*8);
    s16x8 bv[4];
    #pragma unroll
    for (int nf = 0; nf < 4; ++nf){
      const u16t* p;
      if (SPLIT) p = (k0 < 4) ? (bA[nf] + k0*32) : (bB[nf] + (k0-4)*32);
      else       p = bA[nf] + k0*32;
      bv[nf] = *reinterpret_cast<const s16x8*>(p);
    }
    #pragma unroll
    for (int mf = 0; mf < MF; ++mf)
      #pragma unroll
      for (int nf = 0; nf < 4; ++nf)
        acc[mf][nf] = __builtin_amdgcn_mfma_f32_16x16x32_bf16(av[mf], bv[nf], acc[mf][nf], 0, 0, 0);
  }

  #pragma unroll
  for (int mf = 0; mf < MF; ++mf){
    int mb = m0 + mf*16 + kg*4;
    float4 bs = *reinterpret_cast<const float4*>(bias + mb);
    float s0=0.f,s1=0.f,s2=0.f,s3=0.f,q0=0.f,q1=0.f,q2=0.f,q3=0.f;
    #pragma unroll
    for (int nf = 0; nf < 4; ++nf){
      int n = n0 + nf*16 + lr;
      float v0 = acc[mf][nf][0] + bs.x;
      float v1 = acc[mf][nf][1] + bs.y;
      float v2 = acc[mf][nf][2] + bs.z;
      float v3 = acc[mf][nf][3] + bs.w;
      s0+=v0; q0+=v0*v0; s1+=v1; q1+=v1*v1;
      s2+=v2; q2+=v2*v2; s3+=v3; q3+=v3*v3;
      uint2 pv;
      pv.x = (u32t)f2b(v0) | ((u32t)f2b(v1) << 16);
      pv.y = (u32t)f2b(v2) | ((u32t)f2b(v3) << 16);
      *reinterpret_cast<uint2*>(y + ((size_t)b*NPTS + n)*OUT + mb) = pv;
    }
    // reduce across the 16 lanes (lr) sharing this channel quad; xor<16 stays in-group
    #pragma unroll
    for (int o = 1; o < 16; o <<= 1){
      s0 += __shfl_xor(s0, o); s1 += __shfl_xor(s1, o);
      s2 += __shfl_xor(s2, o); s3 += __shfl_xor(s3, o);
      q0 += __shfl_xor(q0, o); q1 += __shfl_xor(q1, o);
      q2 += __shfl_xor(q2, o); q3 += __shfl_xor(q3, o);
    }
    if (lr == 0){
      atomicAdd(&stats[(mb+0)*2], s0); atomicAdd(&stats[(mb+0)*2+1], q0);
      atomicAdd(&stats[(mb+1)*2], s1); atomicAdd(&stats[(mb+1)*2+1], q1);
      atomicAdd(&stats[(mb+2)*2], s2); atomicAdd(&stats[(mb+2)*2+1], q2);
      atomicAdd(&stats[(mb+3)*2], s3); atomicAdd(&stats[(mb+3)*2+1], q3);
    }
  }
}

// ---- gate: psi_pre[p] = psi_w . lrelu(bn(yg)+bn(yx)) + psi_b, + psi stats ----
__global__ __launch_bounds__(256) void gate_kernel(const u16t* __restrict__ yg, const u16t* __restrict__ yx,
                                                   const float* __restrict__ stg, const float* __restrict__ stx,
                                                   const float* __restrict__ wg_bn_g, const float* __restrict__ wg_bn_b,
                                                   const float* __restrict__ wx_bn_g, const float* __restrict__ wx_bn_b,
                                                   const float* __restrict__ psi_w, const float* __restrict__ psi_b,
                                                   float* __restrict__ psipre, float* __restrict__ stpsi){
  __shared__ float lag[64], lbg[64], lax[64], lbx[64], lpw[64];
  __shared__ float red[8];
  const int t = threadIdx.x;
  if (t < 64){
    float m  = stg[t*2] * (1.0f/CNTF);
    float vv = fmaxf(stg[t*2+1]*(1.0f/CNTF) - m*m, 0.0f);
    float iv = 1.0f/sqrtf(vv + BNEPS);
    float gm = wg_bn_g[t];
    lag[t] = gm*iv; lbg[t] = wg_bn_b[t] - m*gm*iv;
    m  = stx[t*2] * (1.0f/CNTF);
    vv = fmaxf(stx[t*2+1]*(1.0f/CNTF) - m*m, 0.0f);
    iv = 1.0f/sqrtf(vv + BNEPS);
    gm = wx_bn_g[t];
    lax[t] = gm*iv; lbx[t] = wx_bn_b[t] - m*gm*iv;
    lpw[t] = psi_w[t];
  }
  __syncthreads();
  const int p = blockIdx.x*256 + t;
  const u16t* rg = yg + (size_t)p*64;
  const u16t* rx = yx + (size_t)p*64;
  float acc = psi_b[0];
  #pragma unroll
  for (int u = 0; u < 8; ++u){
    uint4 qg = *reinterpret_cast<const uint4*>(rg + u*8);
    uint4 qx = *reinterpret_cast<const uint4*>(rx + u*8);
    const u32t* g4 = reinterpret_cast<const u32t*>(&qg);
    const u32t* x4 = reinterpret_cast<const u32t*>(&qx);
    #pragma unroll
    for (int e = 0; e < 4; ++e){
      int j = u*8 + e*2;
      float gv0 = fmaf(b2f((u16t)g4[e]),        lag[j],   lbg[j]);
      float xv0 = fmaf(b2f((u16t)x4[e]),        lax[j],   lbx[j]);
      float gv1 = fmaf(b2f((u16t)(g4[e]>>16)),  lag[j+1], lbg[j+1]);
      float xv1 = fmaf(b2f((u16t)(x4[e]>>16)),  lax[j+1], lbx[j+1]);
      acc = fmaf(lpw[j],   lrelu(gv0 + xv0), acc);
      acc = fmaf(lpw[j+1], lrelu(gv1 + xv1), acc);
    }
  }
  psipre[p] = acc;
  float s = acc, q = acc*acc;
  #pragma unroll
  for (int o = 32; o; o >>= 1){ s += __shfl_xor(s, o); q += __shfl_xor(q, o); }
  if ((t & 63) == 0){ red[(t>>6)*2] = s; red[(t>>6)*2+1] = q; }
  __syncthreads();
  if (t == 0){
    atomicAdd(&stpsi[0], red[0]+red[2]+red[4]+red[6]);
    atomicAdd(&stpsi[1], red[1]+red[3]+red[5]+red[7]);
  }
}

// ---- psi = sigmoid(bn(psi_pre)); scale p1t rows in place ----
__global__ __launch_bounds__(256) void scale_p1_kernel(u16t* __restrict__ p1t, const float* __restrict__ psipre,
                                                       const float* __restrict__ stpsi,
                                                       const float* __restrict__ psi_bn_g, const float* __restrict__ psi_bn_b){
  const int p = blockIdx.x*256 + threadIdx.x;
  float m  = stpsi[0]*(1.0f/CNTF);
  float vv = fmaxf(stpsi[1]*(1.0f/CNTF) - m*m, 0.0f);
  float iv = 1.0f/sqrtf(vv + BNEPS);
  float ap = psi_bn_g[0]*iv;
  float bp = psi_bn_b[0] - m*ap;
  float z  = fmaf(psipre[p], ap, bp);
  float psi = 1.0f/(1.0f + expf(-z));
  u16t* r = p1t + (size_t)p*128;
  #pragma unroll
  for (int u = 0; u < 16; ++u){
    uint4 q = *reinterpret_cast<uint4*>(r + u*8);
    u32t* a = reinterpret_cast<u32t*>(&q);
    #pragma unroll
    for (int j = 0; j < 4; ++j){
      float lo = b2f((u16t)a[j]) * psi;
      float hi = b2f((u16t)(a[j]>>16)) * psi;
      a[j] = (u32t)f2b(lo) | ((u32t)f2b(hi) << 16);
    }
    *reinterpret_cast<uint4*>(r + u*8) = q;
  }
}

// ---- bn1 + lrelu in place on h1 [P][256] bf16 ----
__global__ __launch_bounds__(256) void bnrelu256_kernel(u16t* __restrict__ x, const float* __restrict__ st,
                                                        const float* __restrict__ g, const float* __restrict__ bb){
  __shared__ float sa[256], sc[256];
  const int t = threadIdx.x;
  {
    float m  = st[t*2]*(1.0f/CNTF);
    float vv = fmaxf(st[t*2+1]*(1.0f/CNTF) - m*m, 0.0f);
    float iv = 1.0f/sqrtf(vv + BNEPS);
    float gm = g[t];
    sa[t] = gm*iv; sc[t] = bb[t] - m*gm*iv;
  }
  __syncthreads();
  size_t e4 = ((size_t)blockIdx.x*256 + t)*4;
  int c0 = (int)(e4 & 255);
  uint2 v = *reinterpret_cast<uint2*>(x + e4);
  float f0 = lrelu(fmaf(b2f((u16t)v.x),        sa[c0],   sc[c0]));
  float f1 = lrelu(fmaf(b2f((u16t)(v.x>>16)),  sa[c0+1], sc[c0+1]));
  float f2 = lrelu(fmaf(b2f((u16t)v.y),        sa[c0+2], sc[c0+2]));
  float f3 = lrelu(fmaf(b2f((u16t)(v.y>>16)),  sa[c0+3], sc[c0+3]));
  v.x = (u32t)f2b(f0) | ((u32t)f2b(f1) << 16);
  v.y = (u32t)f2b(f2) | ((u32t)f2b(f3) << 16);
  *reinterpret_cast<uint2*>(x + e4) = v;
}

// ---- final: out[b][m][n] f32 = lrelu(bn2(h2[b][n][m])) via LDS tile transpose ----
__global__ __launch_bounds__(256) void final_kernel(const u16t* __restrict__ h2, const float* __restrict__ st,
                                                    const float* __restrict__ g, const float* __restrict__ bb,
                                                    float* __restrict__ out){
  __shared__ float am[128], cm[128];
  __shared__ float tile[64][129];
  const int t = threadIdx.x;
  if (t < 128){
    float m  = st[t*2]*(1.0f/CNTF);
    float vv = fmaxf(st[t*2+1]*(1.0f/CNTF) - m*m, 0.0f);
    float iv = 1.0f/sqrtf(vv + BNEPS);
    float gm = g[t];
    am[t] = gm*iv; cm[t] = bb[t] - m*gm*iv;
  }
  __syncthreads();
  const int n0 = blockIdx.x * 64;
  const int b  = blockIdx.y;
  #pragma unroll
  for (int i = 0; i < 32; ++i){
    int idx = t + i*256;
    int mm = idx & 127, nn = idx >> 7;
    float v = fmaf(b2f(h2[((size_t)b*NPTS + n0 + nn)*128 + mm]), am[mm], cm[mm]);
    tile[nn][mm] = lrelu(v);
  }
  __syncthreads();
  #pragma unroll
  for (int i = 0; i < 32; ++i){
    int idx = t + i*256;
    int nn = idx & 63, mm = idx >> 6;
    out[((size_t)(b*128 + mm))*NPTS + n0 + nn] = tile[nn][mm];
  }
}

extern "C" void kernel_launch(void* const* d_in, const int* in_sizes, int n_in,
                              void* d_out, int out_size, void* d_ws, size_t ws_size,
                              hipStream_t stream){
  const float* xyz1    = (const float*)d_in[0];
  const float* xyz2    = (const float*)d_in[1];
  const float* points1 = (const float*)d_in[2];
  const float* points2 = (const float*)d_in[3];
  const float* conv1_w = (const float*)d_in[4];
  const float* conv1_b = (const float*)d_in[5];
  const float* bn1_g   = (const float*)d_in[6];
  const float* bn1_b   = (const float*)d_in[7];
  const float* conv2_w = (const float*)d_in[8];
  const float* conv2_b = (const float*)d_in[9];
  const float* bn2_g   = (const float*)d_in[10];
  const float* bn2_b   = (const float*)d_in[11];
  const float* wg_w    = (const float*)d_in[12];
  const float* wg_b    = (const float*)d_in[13];
  const float* wg_bn_g = (const float*)d_in[14];
  const float* wg_bn_b = (const float*)d_in[15];
  const float* wx_w    = (const float*)d_in[16];
  const float* wx_b    = (const float*)d_in[17];
  const float* wx_bn_g = (const float*)d_in[18];
  const float* wx_bn_b = (const float*)d_in[19];
  const float* psi_w   = (const float*)d_in[20];
  const float* psi_b   = (const float*)d_in[21];
  const float* psi_bn_g= (const float*)d_in[22];
  const float* psi_bn_b= (const float*)d_in[23];

  char* ws = (char*)d_ws;
  float* stats  = (float*)(ws + O_STATS);
  u16t*  wb     = (u16t*)(ws + O_WB);
  float* psipre = (float*)(ws + O_PSIPRE);
  u16t*  p2t    = (u16t*)(ws + O_P2T);
  u16t*  p1t    = (u16t*)(ws + O_P1T);
  u16t*  itp    = (u16t*)(ws + O_INT);
  u16t*  h1t    = (u16t*)(ws + O_H1);
  float* pd     = (float*)(ws + O_PD);
  int*   pi     = (int*)(ws + O_PI);
  int*   idx3   = (int*)(ws + O_IDX3);
  float* w3     = (float*)(ws + O_W3);
  u16t*  ygt    = (u16t*)(ws + O_YG);
  u16t*  yxt    = (u16t*)(ws + O_YX);
  u16t*  h2t    = (u16t*)(ws + O_H2);

  hipMemsetAsync(ws + O_STATS, 0, 8192, stream);

  knn_part_kernel<<<dim3(NPTS/256, NCH, Bq), 256, 0, stream>>>(xyz1, xyz2, pd, pi);
  knn_merge_kernel<<<(Bq*NPTS)/256, 256, 0, stream>>>(pd, pi, idx3, w3);
  tpose_kernel<256, SPTS><<<dim3(SPTS/64, 4, Bq), 256, 0, stream>>>(points2, p2t);
  interp_kernel<<<Bq*(NPTS/64), 256, 0, stream>>>(p2t, idx3, w3, itp);
  tpose_kernel<128, NPTS><<<dim3(NPTS/64, 2, Bq), 256, 0, stream>>>(points1, p1t);
  wcvt_kernel<<<(WTOTAL+255)/256, 256, 0, stream>>>(conv1_w, conv2_w, wg_w, wx_w, wb);

  mfma_conv_kernel<256, 64, false><<<Bq*(NPTS/64), 256, 0, stream>>>(itp, nullptr, wb+WOFF_WG, wg_b, ygt, stats+ST_WG);
  mfma_conv_kernel<128, 64, false><<<Bq*(NPTS/64), 256, 0, stream>>>(p1t, nullptr, wb+WOFF_WX, wx_b, yxt, stats+ST_WX);
  gate_kernel<<<256, 256, 0, stream>>>(ygt, yxt, stats+ST_WG, stats+ST_WX,
                                       wg_bn_g, wg_bn_b, wx_bn_g, wx_bn_b,
                                       psi_w, psi_b, psipre, stats+ST_PSI);
  scale_p1_kernel<<<256, 256, 0, stream>>>(p1t, psipre, stats+ST_PSI, psi_bn_g, psi_bn_b);

  mfma_conv_kernel<384, 256, true><<<Bq*(NPTS/64), 256, 0, stream>>>(p1t, itp, wb+WOFF_C1, conv1_b, h1t, stats+ST_BN1);
  bnrelu256_kernel<<<16384, 256, 0, stream>>>(h1t, stats+ST_BN1, bn1_g, bn1_b);

  mfma_conv_kernel<256, 128, false><<<Bq*(NPTS/64), 256, 0, stream>>>(h1t, nullptr, wb+WOFF_C2, conv2_b, h2t, stats+ST_BN2);
  final_kernel<<<dim3(NPTS/64, Bq), 256, 0, stream>>>(h2t, stats+ST_BN2, bn2_g, bn2_b, (float*)d_out);
}

// Round 7
// 328.292 us; speedup vs baseline: 3.3635x; 3.3635x over previous
//
#include <hip/hip_runtime.h>
#include <hip/hip_bf16.h>

#define Bq    4
#define NPTS  16384
#define SPTS  2048
#define NCH   8
#define SCH   (SPTS/NCH)   // 256
#define CNTF  65536.0f
#define BNEPS 1e-5f

typedef unsigned short u16t;
typedef unsigned int   u32t;
typedef __attribute__((ext_vector_type(8))) short s16x8;
typedef __attribute__((ext_vector_type(4))) float f32x4;

__device__ __forceinline__ float b2f(u16t u){
  union { u32t i; float f; } v; v.i = ((u32t)u) << 16; return v.f;
}
__device__ __forceinline__ u16t f2b(float f){
  __hip_bfloat16 h = __float2bfloat16(f);
  return *reinterpret_cast<u16t*>(&h);
}
__device__ __forceinline__ float lrelu(float x){ return x >= 0.0f ? x : 0.2f*x; }

// ---- stats f32 offsets: per-channel [sum,sumsq] pairs ----
#define ST_WG  0
#define ST_WX  128
#define ST_PSI 256
#define ST_BN1 272
#define ST_BN2 784

// ---- bf16 weight element offsets inside WB region ----
#define WOFF_C1 0
#define WOFF_C2 98304
#define WOFF_WG 131072
#define WOFF_WX 147456
#define WTOTAL  155648

// ---- ws byte offsets (time-disjoint aliasing; total ~84.6 MB) ----
#define O_STATS  0u
#define O_WB     8192u
#define O_PSIPRE 319488u
#define O_P2T    581632u        // 4 MB bf16 [B][S][256]; dead after interp
#define O_PART   O_P2T          // conv stats partials [1024][<=512] f32 = 2 MB, used after interp
#define O_P1T    4775936u       // 16.7 MB bf16 [B][N][128]; psi-scaled IN PLACE
#define O_INT    21553152u      // 33.5 MB bf16 [B][N][256] interp; h2t aliases later
#define O_H1     55107584u      // 33.5 MB bf16 [B][N][256] h1; bnrelu IN PLACE
// knn scratch lives inside the (not-yet-written) H1 region:
#define O_PD     O_H1                    // 6.29 MB f32 partial dists [B][N][NCH][3]
#define O_PI     (O_H1 + 6291456u)       // 6.29 MB i32 partial idx
#define O_IDX3   (O_H1 + 12582912u)      // 786 KB
#define O_W3     (O_H1 + 13369344u)      // 786 KB (all dead before ygt written)
#define O_YG     O_H1                    // ygt/yxt live steps 5-8, dead before h1 written
#define O_YX     (O_H1 + 8388608u)
#define O_H2     O_INT                   // h2 bf16, written after interp dead
// end = 55107584 + 33554432 = 88662016 B

// ---- 3-NN part 1: per-chunk top-3 over SCH s-points (full occupancy) ----
__global__ __launch_bounds__(256) void knn_part_kernel(const float* __restrict__ xyz1, const float* __restrict__ xyz2,
                                                       float* __restrict__ pd, int* __restrict__ pi){
  __shared__ float4 sp[SCH];
  const int b = blockIdx.z;
  const int c = blockIdx.y;
  const int t = threadIdx.x;
  {
    int s = c*SCH + t;
    float x = xyz2[(b*3+0)*SPTS+s];
    float y = xyz2[(b*3+1)*SPTS+s];
    float z = xyz2[(b*3+2)*SPTS+s];
    sp[t] = make_float4(x, y, z, x*x+y*y+z*z);
  }
  __syncthreads();
  const int n = blockIdx.x*256 + t;
  float px = xyz1[(b*3+0)*NPTS+n];
  float py = xyz1[(b*3+1)*NPTS+n];
  float pz = xyz1[(b*3+2)*NPTS+n];
  float s1 = px*px+py*py+pz*pz;
  float d0=3.4e38f, d1=3.4e38f, d2=3.4e38f;
  int   i0=0, i1=0, i2=0;
  for (int s=0; s<SCH; ++s){
    float4 q = sp[s];
    float dot = fmaf(pz, q.z, fmaf(py, q.y, px*q.x));
    float key = (s1 + q.w) - 2.0f*dot;   // same arithmetic as passing round-4 scan
    if (key < d2){
      int gi = c*SCH + s;
      if (key < d1){
        if (key < d0){ d2=d1; i2=i1; d1=d0; i1=i0; d0=key; i0=gi; }
        else         { d2=d1; i2=i1; d1=key; i1=gi; }
      } else         { d2=key; i2=gi; }
    }
  }
  size_t base = (((size_t)b*NPTS + n)*NCH + c)*3;
  pd[base]=d0; pd[base+1]=d1; pd[base+2]=d2;
  pi[base]=i0; pi[base+1]=i1; pi[base+2]=i2;
}

// ---- 3-NN part 2: merge NCH partial top-3 lists (chunk-order => stable ties) ----
__global__ __launch_bounds__(256) void knn_merge_kernel(const float* __restrict__ pd, const int* __restrict__ pi,
                                                        int* __restrict__ idx3, float* __restrict__ w3){
  const int p = blockIdx.x*256 + threadIdx.x;   // [0, B*N)
  const float* dp = pd + (size_t)p*NCH*3;
  const int*   ip = pi + (size_t)p*NCH*3;
  float d0=3.4e38f, d1=3.4e38f, d2=3.4e38f;
  int   i0=0, i1=0, i2=0;
  #pragma unroll
  for (int k=0; k<NCH*3; ++k){
    float key = dp[k]; int gi = ip[k];
    if (key < d2){
      if (key < d1){
        if (key < d0){ d2=d1; i2=i1; d1=d0; i1=i0; d0=key; i0=gi; }
        else         { d2=d1; i2=i1; d1=key; i1=gi; }
      } else         { d2=key; i2=gi; }
    }
  }
  float r0=1.0f/(d0+1e-8f), r1=1.0f/(d1+1e-8f), r2=1.0f/(d2+1e-8f);
  float rs = r0+r1+r2;
  size_t base = (size_t)p*3;
  idx3[base]=i0; idx3[base+1]=i1; idx3[base+2]=i2;
  w3[base]=r0/rs; w3[base+1]=r1/rs; w3[base+2]=r2/rs;
}

// ---- tiled transpose: src f32 [B][C][NN] -> dst bf16 [B][NN][C] ----
template<int C, int NN>
__global__ __launch_bounds__(256) void tpose_kernel(const float* __restrict__ src, u16t* __restrict__ dst){
  __shared__ float tile[64][65];
  const int n0 = blockIdx.x * 64;
  const int c0 = blockIdx.y * 64;
  const int b  = blockIdx.z;
  const int t  = threadIdx.x;
  #pragma unroll
  for (int i = 0; i < 16; ++i){
    int idx = t + i*256;
    int cc = idx >> 6, nn = idx & 63;
    tile[cc][nn] = src[((size_t)b*C + c0 + cc)*NN + n0 + nn];
  }
  __syncthreads();
  #pragma unroll
  for (int i = 0; i < 16; ++i){
    int idx = t + i*256;
    int nn = idx >> 6, cc = idx & 63;
    dst[((size_t)b*NN + n0 + nn)*C + c0 + cc] = f2b(tile[cc][nn]);
  }
}

// ---- weight convert f32 -> bf16 into WB ----
__global__ __launch_bounds__(256) void wcvt_kernel(const float* __restrict__ w1, const float* __restrict__ w2,
                                                   const float* __restrict__ wg, const float* __restrict__ wx,
                                                   u16t* __restrict__ wb){
  int i = blockIdx.x*256 + threadIdx.x;
  if (i >= WTOTAL) return;
  float v;
  if      (i < WOFF_C2) v = w1[i];
  else if (i < WOFF_WG) v = w2[i - WOFF_C2];
  else if (i < WOFF_WX) v = wg[i - WOFF_WG];
  else                  v = wx[i - WOFF_WX];
  wb[i] = f2b(v);
}

// ---- interp: point-major out [B][N][256] ----
__global__ __launch_bounds__(256) void interp_kernel(const u16t* __restrict__ p2t, const int* __restrict__ idx3,
                                                     const float* __restrict__ w3, u16t* __restrict__ it){
  const int bid = blockIdx.x;
  const int b = bid >> 8;
  const int n0 = (bid & 255) * 64;
  const int wv = threadIdx.x >> 6;
  const int lane = threadIdx.x & 63;
  const int n = n0 + lane;
  size_t pb = ((size_t)b*NPTS + n)*3;
  int i0 = idx3[pb], i1 = idx3[pb+1], i2 = idx3[pb+2];
  float w0 = w3[pb], w1 = w3[pb+1], w2 = w3[pb+2];
  const u16t* r0 = p2t + ((size_t)b*SPTS + i0)*256;
  const u16t* r1 = p2t + ((size_t)b*SPTS + i1)*256;
  const u16t* r2 = p2t + ((size_t)b*SPTS + i2)*256;
  u16t* orow = it + ((size_t)b*NPTS + n)*256;
  for (int c = wv*64; c < wv*64 + 64; c += 8){
    uint4 q0 = *reinterpret_cast<const uint4*>(r0 + c);
    uint4 q1 = *reinterpret_cast<const uint4*>(r1 + c);
    uint4 q2 = *reinterpret_cast<const uint4*>(r2 + c);
    const u32t* a0 = reinterpret_cast<const u32t*>(&q0);
    const u32t* a1 = reinterpret_cast<const u32t*>(&q1);
    const u32t* a2 = reinterpret_cast<const u32t*>(&q2);
    u32t ow[4];
    #pragma unroll
    for (int j = 0; j < 4; ++j){
      u32t u0 = a0[j], u1 = a1[j], u2 = a2[j];
      float lo = fmaf(w2, b2f((u16t)u2), fmaf(w1, b2f((u16t)u1), w0*b2f((u16t)u0)));
      float hi = fmaf(w2, b2f((u16t)(u2>>16)), fmaf(w1, b2f((u16t)(u1>>16)), w0*b2f((u16t)(u0>>16))));
      ow[j] = (u32t)f2b(lo) | ((u32t)f2b(hi) << 16);
    }
    *reinterpret_cast<uint4*>(orow + c) = make_uint4(ow[0], ow[1], ow[2], ow[3]);
  }
}

// ---- MFMA conv1x1 + per-block stats partials (NO atomics) ----
// y[B][N][OUT] = W[OUT][CIN] . x[B][N][CIN] + bias (raw, pre-BN)
// partial[bid][c*2 / c*2+1] = block-local sum/sumsq of f32 outputs
template<int CIN, int OUT, bool SPLIT>
__global__ __launch_bounds__(256, 1) void mfma_conv_kernel(const u16t* __restrict__ xa, const u16t* __restrict__ xb,
                                                           const u16t* __restrict__ W, const float* __restrict__ bias,
                                                           u16t* __restrict__ y, float* __restrict__ partial){
  constexpr int MW = OUT/4;      // per-wave M slice
  constexpr int MF = MW/16;      // m-fragments per wave
  constexpr int KS = CIN/32;     // k-steps
  const int bid = blockIdx.x;
  const int b = bid >> 8;
  const int n0 = (bid & 255) * 64;
  const int wv = threadIdx.x >> 6;
  const int lane = threadIdx.x & 63;
  const int lr = lane & 15;
  const int kg = lane >> 4;
  const int m0 = wv * MW;

  f32x4 acc[MF][4];
  #pragma unroll
  for (int mf = 0; mf < MF; ++mf)
    #pragma unroll
    for (int nf = 0; nf < 4; ++nf){ acc[mf][nf][0]=0.f; acc[mf][nf][1]=0.f; acc[mf][nf][2]=0.f; acc[mf][nf][3]=0.f; }

  const u16t* bA[4]; const u16t* bB[4];
  #pragma unroll
  for (int nf = 0; nf < 4; ++nf){
    int n = n0 + nf*16 + lr;
    if (SPLIT){
      bA[nf] = xa + ((size_t)b*NPTS + n)*128 + kg*8;
      bB[nf] = xb + ((size_t)b*NPTS + n)*256 + kg*8;
    } else {
      bA[nf] = xa + ((size_t)b*NPTS + n)*CIN + kg*8;
    }
  }

  #pragma unroll
  for (int k0 = 0; k0 < KS; ++k0){
    s16x8 av[MF];
    #pragma unroll
    for (int mf = 0; mf < MF; ++mf)
      av[mf] = *reinterpret_cast<const s16x8*>(W + (size_t)(m0 + mf*16 + lr)*CIN + k0*32 + kg*8);
    s16x8 bv[4];
    #pragma unroll
    for (int nf = 0; nf < 4; ++nf){
      const u16t* p;
      if (SPLIT) p = (k0 < 4) ? (bA[nf] + k0*32) : (bB[nf] + (k0-4)*32);
      else       p = bA[nf] + k0*32;
      bv[nf] = *reinterpret_cast<const s16x8*>(p);
    }
    #pragma unroll
    for (int mf = 0; mf < MF; ++mf)
      #pragma unroll
      for (int nf = 0; nf < 4; ++nf)
        acc[mf][nf] = __builtin_amdgcn_mfma_f32_16x16x32_bf16(av[mf], bv[nf], acc[mf][nf], 0, 0, 0);
  }

  #pragma unroll
  for (int mf = 0; mf < MF; ++mf){
    int mb = m0 + mf*16 + kg*4;
    float4 bs = *reinterpret_cast<const float4*>(bias + mb);
    float s0=0.f,s1=0.f,s2=0.f,s3=0.f,q0=0.f,q1=0.f,q2=0.f,q3=0.f;
    #pragma unroll
    for (int nf = 0; nf < 4; ++nf){
      int n = n0 + nf*16 + lr;
      float v0 = acc[mf][nf][0] + bs.x;
      float v1 = acc[mf][nf][1] + bs.y;
      float v2 = acc[mf][nf][2] + bs.z;
      float v3 = acc[mf][nf][3] + bs.w;
      s0+=v0; q0+=v0*v0; s1+=v1; q1+=v1*v1;
      s2+=v2; q2+=v2*v2; s3+=v3; q3+=v3*v3;
      uint2 pv;
      pv.x = (u32t)f2b(v0) | ((u32t)f2b(v1) << 16);
      pv.y = (u32t)f2b(v2) | ((u32t)f2b(v3) << 16);
      *reinterpret_cast<uint2*>(y + ((size_t)b*NPTS + n)*OUT + mb) = pv;
    }
    // reduce across the 16 lanes (lr) sharing this channel quad; xor<16 stays in-group
    #pragma unroll
    for (int o = 1; o < 16; o <<= 1){
      s0 += __shfl_xor(s0, o); s1 += __shfl_xor(s1, o);
      s2 += __shfl_xor(s2, o); s3 += __shfl_xor(s3, o);
      q0 += __shfl_xor(q0, o); q1 += __shfl_xor(q1, o);
      q2 += __shfl_xor(q2, o); q3 += __shfl_xor(q3, o);
    }
    if (lr == 0){
      float* pp = partial + (size_t)bid*(OUT*2) + mb*2;
      pp[0]=s0; pp[1]=q0; pp[2]=s1; pp[3]=q1;
      pp[4]=s2; pp[5]=q2; pp[6]=s3; pp[7]=q3;
    }
  }
}

// ---- reduce conv partials [1024][E] -> stats[E] (no atomics) ----
template<int E>
__global__ __launch_bounds__(256) void reduce_stats_kernel(const float* __restrict__ p, float* __restrict__ st){
  __shared__ float ls[8][32];
  const int t = threadIdx.x;
  const int kq = t >> 5, es = t & 31;
  const int e = blockIdx.x*32 + es;
  float s = 0.f;
  const float* pp = p + (size_t)kq*128*E + e;
  #pragma unroll 16
  for (int i = 0; i < 128; ++i) s += pp[(size_t)i*E];
  ls[kq][es] = s;
  __syncthreads();
  if (kq == 0){
    st[e] = ((ls[0][es]+ls[1][es])+(ls[2][es]+ls[3][es]))
          + ((ls[4][es]+ls[5][es])+(ls[6][es]+ls[7][es]));
  }
}

// ---- gate: psi_pre[p] = psi_w . lrelu(bn(yg)+bn(yx)) + psi_b, + psi stats ----
__global__ __launch_bounds__(256) void gate_kernel(const u16t* __restrict__ yg, const u16t* __restrict__ yx,
                                                   const float* __restrict__ stg, const float* __restrict__ stx,
                                                   const float* __restrict__ wg_bn_g, const float* __restrict__ wg_bn_b,
                                                   const float* __restrict__ wx_bn_g, const float* __restrict__ wx_bn_b,
                                                   const float* __restrict__ psi_w, const float* __restrict__ psi_b,
                                                   float* __restrict__ psipre, float* __restrict__ stpsi){
  __shared__ float lag[64], lbg[64], lax[64], lbx[64], lpw[64];
  __shared__ float red[8];
  const int t = threadIdx.x;
  if (t < 64){
    float m  = stg[t*2] * (1.0f/CNTF);
    float vv = fmaxf(stg[t*2+1]*(1.0f/CNTF) - m*m, 0.0f);
    float iv = 1.0f/sqrtf(vv + BNEPS);
    float gm = wg_bn_g[t];
    lag[t] = gm*iv; lbg[t] = wg_bn_b[t] - m*gm*iv;
    m  = stx[t*2] * (1.0f/CNTF);
    vv = fmaxf(stx[t*2+1]*(1.0f/CNTF) - m*m, 0.0f);
    iv = 1.0f/sqrtf(vv + BNEPS);
    gm = wx_bn_g[t];
    lax[t] = gm*iv; lbx[t] = wx_bn_b[t] - m*gm*iv;
    lpw[t] = psi_w[t];
  }
  __syncthreads();
  const int p = blockIdx.x*256 + t;
  const u16t* rg = yg + (size_t)p*64;
  const u16t* rx = yx + (size_t)p*64;
  float acc = psi_b[0];
  #pragma unroll
  for (int u = 0; u < 8; ++u){
    uint4 qg = *reinterpret_cast<const uint4*>(rg + u*8);
    uint4 qx = *reinterpret_cast<const uint4*>(rx + u*8);
    const u32t* g4 = reinterpret_cast<const u32t*>(&qg);
    const u32t* x4 = reinterpret_cast<const u32t*>(&qx);
    #pragma unroll
    for (int e = 0; e < 4; ++e){
      int j = u*8 + e*2;
      float gv0 = fmaf(b2f((u16t)g4[e]),        lag[j],   lbg[j]);
      float xv0 = fmaf(b2f((u16t)x4[e]),        lax[j],   lbx[j]);
      float gv1 = fmaf(b2f((u16t)(g4[e]>>16)),  lag[j+1], lbg[j+1]);
      float xv1 = fmaf(b2f((u16t)(x4[e]>>16)),  lax[j+1], lbx[j+1]);
      acc = fmaf(lpw[j],   lrelu(gv0 + xv0), acc);
      acc = fmaf(lpw[j+1], lrelu(gv1 + xv1), acc);
    }
  }
  psipre[p] = acc;
  float s = acc, q = acc*acc;
  #pragma unroll
  for (int o = 32; o; o >>= 1){ s += __shfl_xor(s, o); q += __shfl_xor(q, o); }
  if ((t & 63) == 0){ red[(t>>6)*2] = s; red[(t>>6)*2+1] = q; }
  __syncthreads();
  if (t == 0){
    atomicAdd(&stpsi[0], red[0]+red[2]+red[4]+red[6]);
    atomicAdd(&stpsi[1], red[1]+red[3]+red[5]+red[7]);
  }
}

// ---- psi = sigmoid(bn(psi_pre)); scale p1t rows in place ----
__global__ __launch_bounds__(256) void scale_p1_kernel(u16t* __restrict__ p1t, const float* __restrict__ psipre,
                                                       const float* __restrict__ stpsi,
                                                       const float* __restrict__ psi_bn_g, const float* __restrict__ psi_bn_b){
  const int p = blockIdx.x*256 + threadIdx.x;
  float m  = stpsi[0]*(1.0f/CNTF);
  float vv = fmaxf(stpsi[1]*(1.0f/CNTF) - m*m, 0.0f);
  float iv = 1.0f/sqrtf(vv + BNEPS);
  float ap = psi_bn_g[0]*iv;
  float bp = psi_bn_b[0] - m*ap;
  float z  = fmaf(psipre[p], ap, bp);
  float psi = 1.0f/(1.0f + expf(-z));
  u16t* r = p1t + (size_t)p*128;
  #pragma unroll
  for (int u = 0; u < 16; ++u){
    uint4 q = *reinterpret_cast<uint4*>(r + u*8);
    u32t* a = reinterpret_cast<u32t*>(&q);
    #pragma unroll
    for (int j = 0; j < 4; ++j){
      float lo = b2f((u16t)a[j]) * psi;
      float hi = b2f((u16t)(a[j]>>16)) * psi;
      a[j] = (u32t)f2b(lo) | ((u32t)f2b(hi) << 16);
    }
    *reinterpret_cast<uint4*>(r + u*8) = q;
  }
}

// ---- bn1 + lrelu in place on h1 [P][256] bf16 ----
__global__ __launch_bounds__(256) void bnrelu256_kernel(u16t* __restrict__ x, const float* __restrict__ st,
                                                        const float* __restrict__ g, const float* __restrict__ bb){
  __shared__ float sa[256], sc[256];
  const int t = threadIdx.x;
  {
    float m  = st[t*2]*(1.0f/CNTF);
    float vv = fmaxf(st[t*2+1]*(1.0f/CNTF) - m*m, 0.0f);
    float iv = 1.0f/sqrtf(vv + BNEPS);
    float gm = g[t];
    sa[t] = gm*iv; sc[t] = bb[t] - m*gm*iv;
  }
  __syncthreads();
  size_t e4 = ((size_t)blockIdx.x*256 + t)*4;
  int c0 = (int)(e4 & 255);
  uint2 v = *reinterpret_cast<uint2*>(x + e4);
  float f0 = lrelu(fmaf(b2f((u16t)v.x),        sa[c0],   sc[c0]));
  float f1 = lrelu(fmaf(b2f((u16t)(v.x>>16)),  sa[c0+1], sc[c0+1]));
  float f2 = lrelu(fmaf(b2f((u16t)v.y),        sa[c0+2], sc[c0+2]));
  float f3 = lrelu(fmaf(b2f((u16t)(v.y>>16)),  sa[c0+3], sc[c0+3]));
  v.x = (u32t)f2b(f0) | ((u32t)f2b(f1) << 16);
  v.y = (u32t)f2b(f2) | ((u32t)f2b(f3) << 16);
  *reinterpret_cast<uint2*>(x + e4) = v;
}

// ---- final: out[b][m][n] f32 = lrelu(bn2(h2[b][n][m])) via LDS tile transpose ----
__global__ __launch_bounds__(256) void final_kernel(const u16t* __restrict__ h2, const float* __restrict__ st,
                                                    const float* __restrict__ g, const float* __restrict__ bb,
                                                    float* __restrict__ out){
  __shared__ float am[128], cm[128];
  __shared__ float tile[64][129];
  const int t = threadIdx.x;
  if (t < 128){
    float m  = st[t*2]*(1.0f/CNTF);
    float vv = fmaxf(st[t*2+1]*(1.0f/CNTF) - m*m, 0.0f);
    float iv = 1.0f/sqrtf(vv + BNEPS);
    float gm = g[t];
    am[t] = gm*iv; cm[t] = bb[t] - m*gm*iv;
  }
  __syncthreads();
  const int n0 = blockIdx.x * 64;
  const int b  = blockIdx.y;
  #pragma unroll
  for (int i = 0; i < 32; ++i){
    int idx = t + i*256;
    int mm = idx & 127, nn = idx >> 7;
    float v = fmaf(b2f(h2[((size_t)b*NPTS + n0 + nn)*128 + mm]), am[mm], cm[mm]);
    tile[nn][mm] = lrelu(v);
  }
  __syncthreads();
  #pragma unroll
  for (int i = 0; i < 32; ++i){
    int idx = t + i*256;
    int nn = idx & 63, mm = idx >> 6;
    out[((size_t)(b*128 + mm))*NPTS + n0 + nn] = tile[nn][mm];
  }
}

extern "C" void kernel_launch(void* const* d_in, const int* in_sizes, int n_in,
                              void* d_out, int out_size, void* d_ws, size_t ws_size,
                              hipStream_t stream){
  const float* xyz1    = (const float*)d_in[0];
  const float* xyz2    = (const float*)d_in[1];
  const float* points1 = (const float*)d_in[2];
  const float* points2 = (const float*)d_in[3];
  const float* conv1_w = (const float*)d_in[4];
  const float* conv1_b = (const float*)d_in[5];
  const float* bn1_g   = (const float*)d_in[6];
  const float* bn1_b   = (const float*)d_in[7];
  const float* conv2_w = (const float*)d_in[8];
  const float* conv2_b = (const float*)d_in[9];
  const float* bn2_g   = (const float*)d_in[10];
  const float* bn2_b   = (const float*)d_in[11];
  const float* wg_w    = (const float*)d_in[12];
  const float* wg_b    = (const float*)d_in[13];
  const float* wg_bn_g = (const float*)d_in[14];
  const float* wg_bn_b = (const float*)d_in[15];
  const float* wx_w    = (const float*)d_in[16];
  const float* wx_b    = (const float*)d_in[17];
  const float* wx_bn_g = (const float*)d_in[18];
  const float* wx_bn_b = (const float*)d_in[19];
  const float* psi_w   = (const float*)d_in[20];
  const float* psi_b   = (const float*)d_in[21];
  const float* psi_bn_g= (const float*)d_in[22];
  const float* psi_bn_b= (const float*)d_in[23];

  char* ws = (char*)d_ws;
  float* stats  = (float*)(ws + O_STATS);
  u16t*  wb     = (u16t*)(ws + O_WB);
  float* psipre = (float*)(ws + O_PSIPRE);
  u16t*  p2t    = (u16t*)(ws + O_P2T);
  float* part   = (float*)(ws + O_PART);
  u16t*  p1t    = (u16t*)(ws + O_P1T);
  u16t*  itp    = (u16t*)(ws + O_INT);
  u16t*  h1t    = (u16t*)(ws + O_H1);
  float* pd     = (float*)(ws + O_PD);
  int*   pi     = (int*)(ws + O_PI);
  int*   idx3   = (int*)(ws + O_IDX3);
  float* w3     = (float*)(ws + O_W3);
  u16t*  ygt    = (u16t*)(ws + O_YG);
  u16t*  yxt    = (u16t*)(ws + O_YX);
  u16t*  h2t    = (u16t*)(ws + O_H2);

  hipMemsetAsync(ws + O_STATS, 0, 8192, stream);

  knn_part_kernel<<<dim3(NPTS/256, NCH, Bq), 256, 0, stream>>>(xyz1, xyz2, pd, pi);
  knn_merge_kernel<<<(Bq*NPTS)/256, 256, 0, stream>>>(pd, pi, idx3, w3);
  tpose_kernel<256, SPTS><<<dim3(SPTS/64, 4, Bq), 256, 0, stream>>>(points2, p2t);
  interp_kernel<<<Bq*(NPTS/64), 256, 0, stream>>>(p2t, idx3, w3, itp);
  tpose_kernel<128, NPTS><<<dim3(NPTS/64, 2, Bq), 256, 0, stream>>>(points1, p1t);
  wcvt_kernel<<<(WTOTAL+255)/256, 256, 0, stream>>>(conv1_w, conv2_w, wg_w, wx_w, wb);

  mfma_conv_kernel<256, 64, false><<<Bq*(NPTS/64), 256, 0, stream>>>(itp, nullptr, wb+WOFF_WG, wg_b, ygt, part);
  reduce_stats_kernel<128><<<4, 256, 0, stream>>>(part, stats+ST_WG);
  mfma_conv_kernel<128, 64, false><<<Bq*(NPTS/64), 256, 0, stream>>>(p1t, nullptr, wb+WOFF_WX, wx_b, yxt, part);
  reduce_stats_kernel<128><<<4, 256, 0, stream>>>(part, stats+ST_WX);
  gate_kernel<<<256, 256, 0, stream>>>(ygt, yxt, stats+ST_WG, stats+ST_WX,
                                       wg_bn_g, wg_bn_b, wx_bn_g, wx_bn_b,
                                       psi_w, psi_b, psipre, stats+ST_PSI);
  scale_p1_kernel<<<256, 256, 0, stream>>>(p1t, psipre, stats+ST_PSI, psi_bn_g, psi_bn_b);

  mfma_conv_kernel<384, 256, true><<<Bq*(NPTS/64), 256, 0, stream>>>(p1t, itp, wb+WOFF_C1, conv1_b, h1t, part);
  reduce_stats_kernel<512><<<16, 256, 0, stream>>>(part, stats+ST_BN1);
  bnrelu256_kernel<<<16384, 256, 0, stream>>>(h1t, stats+ST_BN1, bn1_g, bn1_b);

  mfma_conv_kernel<256, 128, false><<<Bq*(NPTS/64), 256, 0, stream>>>(h1t, nullptr, wb+WOFF_C2, conv2_b, h2t, part);
  reduce_stats_kernel<256><<<8, 256, 0, stream>>>(part, stats+ST_BN2);
  final_kernel<<<dim3(NPTS/64, Bq), 256, 0, stream>>>(h2t, stats+ST_BN2, bn2_g, bn2_b, (float*)d_out);
}

// Round 8
// 326.240 us; speedup vs baseline: 3.3846x; 1.0063x over previous
//
#include <hip/hip_runtime.h>
#include <hip/hip_bf16.h>

#define Bq    4
#define NPTS  16384
#define SPTS  2048
#define NCH   8
#define SCH   (SPTS/NCH)   // 256
#define CNTF  65536.0f
#define BNEPS 1e-5f

typedef unsigned short u16t;
typedef unsigned int   u32t;
typedef __attribute__((ext_vector_type(8))) short s16x8;
typedef __attribute__((ext_vector_type(4))) float f32x4;

__device__ __forceinline__ float b2f(u16t u){
  union { u32t i; float f; } v; v.i = ((u32t)u) << 16; return v.f;
}
__device__ __forceinline__ u16t f2b(float f){
  __hip_bfloat16 h = __float2bfloat16(f);
  return *reinterpret_cast<u16t*>(&h);
}
__device__ __forceinline__ float lrelu(float x){ return x >= 0.0f ? x : 0.2f*x; }

// ---- stats f32 offsets: per-channel [sum,sumsq] pairs ----
#define ST_WG  0
#define ST_WX  128
#define ST_PSI 256
#define ST_BN1 272
#define ST_BN2 784

// ---- bf16 weight element offsets inside WB region ----
#define WOFF_C1 0
#define WOFF_C2 98304
#define WOFF_WG 131072
#define WOFF_WX 147456
#define WTOTAL  155648

// ---- ws byte offsets (time-disjoint aliasing; total ~84.6 MB) ----
#define O_STATS  0u
#define O_WB     8192u
#define O_PSIPRE 319488u
#define O_P2T    581632u        // 4 MB bf16 [B][S][256]; dead after interp
#define O_PART   O_P2T          // conv stats partials [1024][<=512] f32 = 2 MB, used after interp
#define O_P1T    4775936u       // 16.7 MB bf16 [B][N][128]; psi-scaled IN PLACE
#define O_INT    21553152u      // 33.5 MB bf16 [B][N][256] interp; h2t aliases later
#define O_H1     55107584u      // 33.5 MB bf16 [B][N][256] h1; bnrelu IN PLACE
// knn scratch lives inside the (not-yet-written) H1 region:
#define O_PD     O_H1                    // 6.29 MB f32 partial dists [B][N][NCH][3]
#define O_PI     (O_H1 + 6291456u)       // 6.29 MB i32 partial idx
#define O_IDX3   (O_H1 + 12582912u)      // 786 KB
#define O_W3     (O_H1 + 13369344u)      // 786 KB (all dead before ygt written)
#define O_YG     O_H1                    // ygt/yxt live steps 5-8, dead before h1 written
#define O_YX     (O_H1 + 8388608u)
#define O_H2     O_INT                   // h2 bf16, written after interp dead
// end = 55107584 + 33554432 = 88662016 B

// ---- 3-NN part 1: per-chunk top-3 over SCH s-points (full occupancy) ----
__global__ __launch_bounds__(256) void knn_part_kernel(const float* __restrict__ xyz1, const float* __restrict__ xyz2,
                                                       float* __restrict__ pd, int* __restrict__ pi){
  __shared__ float4 sp[SCH];
  const int b = blockIdx.z;
  const int c = blockIdx.y;
  const int t = threadIdx.x;
  {
    int s = c*SCH + t;
    float x = xyz2[(b*3+0)*SPTS+s];
    float y = xyz2[(b*3+1)*SPTS+s];
    float z = xyz2[(b*3+2)*SPTS+s];
    sp[t] = make_float4(x, y, z, x*x+y*y+z*z);
  }
  __syncthreads();
  const int n = blockIdx.x*256 + t;
  float px = xyz1[(b*3+0)*NPTS+n];
  float py = xyz1[(b*3+1)*NPTS+n];
  float pz = xyz1[(b*3+2)*NPTS+n];
  float s1 = px*px+py*py+pz*pz;
  float d0=3.4e38f, d1=3.4e38f, d2=3.4e38f;
  int   i0=0, i1=0, i2=0;
  for (int s=0; s<SCH; ++s){
    float4 q = sp[s];
    float dot = fmaf(pz, q.z, fmaf(py, q.y, px*q.x));
    float key = (s1 + q.w) - 2.0f*dot;   // same arithmetic as passing round-4 scan
    if (key < d2){
      int gi = c*SCH + s;
      if (key < d1){
        if (key < d0){ d2=d1; i2=i1; d1=d0; i1=i0; d0=key; i0=gi; }
        else         { d2=d1; i2=i1; d1=key; i1=gi; }
      } else         { d2=key; i2=gi; }
    }
  }
  size_t base = (((size_t)b*NPTS + n)*NCH + c)*3;
  pd[base]=d0; pd[base+1]=d1; pd[base+2]=d2;
  pi[base]=i0; pi[base+1]=i1; pi[base+2]=i2;
}

// ---- 3-NN part 2: merge NCH partial top-3 lists (chunk-order => stable ties) ----
__global__ __launch_bounds__(256) void knn_merge_kernel(const float* __restrict__ pd, const int* __restrict__ pi,
                                                        int* __restrict__ idx3, float* __restrict__ w3){
  const int p = blockIdx.x*256 + threadIdx.x;   // [0, B*N)
  const float* dp = pd + (size_t)p*NCH*3;
  const int*   ip = pi + (size_t)p*NCH*3;
  float d0=3.4e38f, d1=3.4e38f, d2=3.4e38f;
  int   i0=0, i1=0, i2=0;
  #pragma unroll
  for (int k=0; k<NCH*3; ++k){
    float key = dp[k]; int gi = ip[k];
    if (key < d2){
      if (key < d1){
        if (key < d0){ d2=d1; i2=i1; d1=d0; i1=i0; d0=key; i0=gi; }
        else         { d2=d1; i2=i1; d1=key; i1=gi; }
      } else         { d2=key; i2=gi; }
    }
  }
  float r0=1.0f/(d0+1e-8f), r1=1.0f/(d1+1e-8f), r2=1.0f/(d2+1e-8f);
  float rs = r0+r1+r2;
  size_t base = (size_t)p*3;
  idx3[base]=i0; idx3[base+1]=i1; idx3[base+2]=i2;
  w3[base]=r0/rs; w3[base+1]=r1/rs; w3[base+2]=r2/rs;
}

// ---- tiled transpose: src f32 [B][C][NN] -> dst bf16 [B][NN][C] ----
template<int C, int NN>
__global__ __launch_bounds__(256) void tpose_kernel(const float* __restrict__ src, u16t* __restrict__ dst){
  __shared__ float tile[64][65];
  const int n0 = blockIdx.x * 64;
  const int c0 = blockIdx.y * 64;
  const int b  = blockIdx.z;
  const int t  = threadIdx.x;
  #pragma unroll
  for (int i = 0; i < 16; ++i){
    int idx = t + i*256;
    int cc = idx >> 6, nn = idx & 63;
    tile[cc][nn] = src[((size_t)b*C + c0 + cc)*NN + n0 + nn];
  }
  __syncthreads();
  #pragma unroll
  for (int i = 0; i < 16; ++i){
    int idx = t + i*256;
    int nn = idx >> 6, cc = idx & 63;
    dst[((size_t)b*NN + n0 + nn)*C + c0 + cc] = f2b(tile[cc][nn]);
  }
}

// ---- weight convert f32 -> bf16 into WB ----
__global__ __launch_bounds__(256) void wcvt_kernel(const float* __restrict__ w1, const float* __restrict__ w2,
                                                   const float* __restrict__ wg, const float* __restrict__ wx,
                                                   u16t* __restrict__ wb){
  int i = blockIdx.x*256 + threadIdx.x;
  if (i >= WTOTAL) return;
  float v;
  if      (i < WOFF_C2) v = w1[i];
  else if (i < WOFF_WG) v = w2[i - WOFF_C2];
  else if (i < WOFF_WX) v = wg[i - WOFF_WG];
  else                  v = wx[i - WOFF_WX];
  wb[i] = f2b(v);
}

// ---- interp: point-major out [B][N][256] ----
__global__ __launch_bounds__(256) void interp_kernel(const u16t* __restrict__ p2t, const int* __restrict__ idx3,
                                                     const float* __restrict__ w3, u16t* __restrict__ it){
  const int bid = blockIdx.x;
  const int b = bid >> 8;
  const int n0 = (bid & 255) * 64;
  const int wv = threadIdx.x >> 6;
  const int lane = threadIdx.x & 63;
  const int n = n0 + lane;
  size_t pb = ((size_t)b*NPTS + n)*3;
  int i0 = idx3[pb], i1 = idx3[pb+1], i2 = idx3[pb+2];
  float w0 = w3[pb], w1 = w3[pb+1], w2 = w3[pb+2];
  const u16t* r0 = p2t + ((size_t)b*SPTS + i0)*256;
  const u16t* r1 = p2t + ((size_t)b*SPTS + i1)*256;
  const u16t* r2 = p2t + ((size_t)b*SPTS + i2)*256;
  u16t* orow = it + ((size_t)b*NPTS + n)*256;
  for (int c = wv*64; c < wv*64 + 64; c += 8){
    uint4 q0 = *reinterpret_cast<const uint4*>(r0 + c);
    uint4 q1 = *reinterpret_cast<const uint4*>(r1 + c);
    uint4 q2 = *reinterpret_cast<const uint4*>(r2 + c);
    const u32t* a0 = reinterpret_cast<const u32t*>(&q0);
    const u32t* a1 = reinterpret_cast<const u32t*>(&q1);
    const u32t* a2 = reinterpret_cast<const u32t*>(&q2);
    u32t ow[4];
    #pragma unroll
    for (int j = 0; j < 4; ++j){
      u32t u0 = a0[j], u1 = a1[j], u2 = a2[j];
      float lo = fmaf(w2, b2f((u16t)u2), fmaf(w1, b2f((u16t)u1), w0*b2f((u16t)u0)));
      float hi = fmaf(w2, b2f((u16t)(u2>>16)), fmaf(w1, b2f((u16t)(u1>>16)), w0*b2f((u16t)(u0>>16))));
      ow[j] = (u32t)f2b(lo) | ((u32t)f2b(hi) << 16);
    }
    *reinterpret_cast<uint4*>(orow + c) = make_uint4(ow[0], ow[1], ow[2], ow[3]);
  }
}

// ---- MFMA conv1x1 + per-block stats partials (NO atomics) ----
// y[B][N][OUT] = W[OUT][CIN] . x[B][N][CIN] + bias (raw, pre-BN)
// partial[bid][c*2 / c*2+1] = block-local sum/sumsq of f32 outputs
// K-loop is register double-buffered: loads for k+1 issue BEFORE MFMAs of k.
template<int CIN, int OUT, bool SPLIT>
__global__ __launch_bounds__(256, 1) void mfma_conv_kernel(const u16t* __restrict__ xa, const u16t* __restrict__ xb,
                                                           const u16t* __restrict__ W, const float* __restrict__ bias,
                                                           u16t* __restrict__ y, float* __restrict__ partial){
  constexpr int MW = OUT/4;      // per-wave M slice
  constexpr int MF = MW/16;      // m-fragments per wave
  constexpr int KS = CIN/32;     // k-steps
  const int bid = blockIdx.x;
  const int b = bid >> 8;
  const int n0 = (bid & 255) * 64;
  const int wv = threadIdx.x >> 6;
  const int lane = threadIdx.x & 63;
  const int lr = lane & 15;
  const int kg = lane >> 4;
  const int m0 = wv * MW;

  f32x4 acc[MF][4];
  #pragma unroll
  for (int mf = 0; mf < MF; ++mf)
    #pragma unroll
    for (int nf = 0; nf < 4; ++nf){ acc[mf][nf][0]=0.f; acc[mf][nf][1]=0.f; acc[mf][nf][2]=0.f; acc[mf][nf][3]=0.f; }

  const u16t* bA[4]; const u16t* bB[4]; const u16t* wrow[MF];
  #pragma unroll
  for (int nf = 0; nf < 4; ++nf){
    int n = n0 + nf*16 + lr;
    if (SPLIT){
      bA[nf] = xa + ((size_t)b*NPTS + n)*128 + kg*8;
      bB[nf] = xb + ((size_t)b*NPTS + n)*256 + kg*8;
    } else {
      bA[nf] = xa + ((size_t)b*NPTS + n)*CIN + kg*8;
    }
  }
  #pragma unroll
  for (int mf = 0; mf < MF; ++mf)
    wrow[mf] = W + (size_t)(m0 + mf*16 + lr)*CIN + kg*8;

  // prologue: load k-step 0 into current buffers
  s16x8 avc[MF], bvc[4], avn[MF], bvn[4];
  #pragma unroll
  for (int mf = 0; mf < MF; ++mf)
    avc[mf] = *reinterpret_cast<const s16x8*>(wrow[mf]);
  #pragma unroll
  for (int nf = 0; nf < 4; ++nf)
    bvc[nf] = *reinterpret_cast<const s16x8*>(SPLIT ? bA[nf] : bA[nf]);

  #pragma unroll
  for (int k0 = 0; k0 < KS; ++k0){
    // prefetch k0+1 BEFORE consuming k0 (register double-buffer)
    if (k0 + 1 < KS){
      int k1 = k0 + 1;
      #pragma unroll
      for (int mf = 0; mf < MF; ++mf)
        avn[mf] = *reinterpret_cast<const s16x8*>(wrow[mf] + k1*32);
      #pragma unroll
      for (int nf = 0; nf < 4; ++nf){
        const u16t* p;
        if (SPLIT) p = (k1 < 4) ? (bA[nf] + k1*32) : (bB[nf] + (k1-4)*32);
        else       p = bA[nf] + k1*32;
        bvn[nf] = *reinterpret_cast<const s16x8*>(p);
      }
    }
    #pragma unroll
    for (int mf = 0; mf < MF; ++mf)
      #pragma unroll
      for (int nf = 0; nf < 4; ++nf)
        acc[mf][nf] = __builtin_amdgcn_mfma_f32_16x16x32_bf16(avc[mf], bvc[nf], acc[mf][nf], 0, 0, 0);
    #pragma unroll
    for (int mf = 0; mf < MF; ++mf) avc[mf] = avn[mf];
    #pragma unroll
    for (int nf = 0; nf < 4; ++nf) bvc[nf] = bvn[nf];
  }

  #pragma unroll
  for (int mf = 0; mf < MF; ++mf){
    int mb = m0 + mf*16 + kg*4;
    float4 bs = *reinterpret_cast<const float4*>(bias + mb);
    float s0=0.f,s1=0.f,s2=0.f,s3=0.f,q0=0.f,q1=0.f,q2=0.f,q3=0.f;
    #pragma unroll
    for (int nf = 0; nf < 4; ++nf){
      int n = n0 + nf*16 + lr;
      float v0 = acc[mf][nf][0] + bs.x;
      float v1 = acc[mf][nf][1] + bs.y;
      float v2 = acc[mf][nf][2] + bs.z;
      float v3 = acc[mf][nf][3] + bs.w;
      s0+=v0; q0+=v0*v0; s1+=v1; q1+=v1*v1;
      s2+=v2; q2+=v2*v2; s3+=v3; q3+=v3*v3;
      uint2 pv;
      pv.x = (u32t)f2b(v0) | ((u32t)f2b(v1) << 16);
      pv.y = (u32t)f2b(v2) | ((u32t)f2b(v3) << 16);
      *reinterpret_cast<uint2*>(y + ((size_t)b*NPTS + n)*OUT + mb) = pv;
    }
    // reduce across the 16 lanes (lr) sharing this channel quad; xor<16 stays in-group
    #pragma unroll
    for (int o = 1; o < 16; o <<= 1){
      s0 += __shfl_xor(s0, o); s1 += __shfl_xor(s1, o);
      s2 += __shfl_xor(s2, o); s3 += __shfl_xor(s3, o);
      q0 += __shfl_xor(q0, o); q1 += __shfl_xor(q1, o);
      q2 += __shfl_xor(q2, o); q3 += __shfl_xor(q3, o);
    }
    if (lr == 0){
      float* pp = partial + (size_t)bid*(OUT*2) + mb*2;
      pp[0]=s0; pp[1]=q0; pp[2]=s1; pp[3]=q1;
      pp[4]=s2; pp[5]=q2; pp[6]=s3; pp[7]=q3;
    }
  }
}

// ---- reduce conv partials [1024][E] -> stats[E] (no atomics) ----
template<int E>
__global__ __launch_bounds__(256) void reduce_stats_kernel(const float* __restrict__ p, float* __restrict__ st){
  __shared__ float ls[8][32];
  const int t = threadIdx.x;
  const int kq = t >> 5, es = t & 31;
  const int e = blockIdx.x*32 + es;
  float s = 0.f;
  const float* pp = p + (size_t)kq*128*E + e;
  #pragma unroll 16
  for (int i = 0; i < 128; ++i) s += pp[(size_t)i*E];
  ls[kq][es] = s;
  __syncthreads();
  if (kq == 0){
    st[e] = ((ls[0][es]+ls[1][es])+(ls[2][es]+ls[3][es]))
          + ((ls[4][es]+ls[5][es])+(ls[6][es]+ls[7][es]));
  }
}

// ---- gate: psi_pre[p] = psi_w . lrelu(bn(yg)+bn(yx)) + psi_b, + psi stats ----
__global__ __launch_bounds__(256) void gate_kernel(const u16t* __restrict__ yg, const u16t* __restrict__ yx,
                                                   const float* __restrict__ stg, const float* __restrict__ stx,
                                                   const float* __restrict__ wg_bn_g, const float* __restrict__ wg_bn_b,
                                                   const float* __restrict__ wx_bn_g, const float* __restrict__ wx_bn_b,
                                                   const float* __restrict__ psi_w, const float* __restrict__ psi_b,
                                                   float* __restrict__ psipre, float* __restrict__ stpsi){
  __shared__ float lag[64], lbg[64], lax[64], lbx[64], lpw[64];
  __shared__ float red[8];
  const int t = threadIdx.x;
  if (t < 64){
    float m  = stg[t*2] * (1.0f/CNTF);
    float vv = fmaxf(stg[t*2+1]*(1.0f/CNTF) - m*m, 0.0f);
    float iv = 1.0f/sqrtf(vv + BNEPS);
    float gm = wg_bn_g[t];
    lag[t] = gm*iv; lbg[t] = wg_bn_b[t] - m*gm*iv;
    m  = stx[t*2] * (1.0f/CNTF);
    vv = fmaxf(stx[t*2+1]*(1.0f/CNTF) - m*m, 0.0f);
    iv = 1.0f/sqrtf(vv + BNEPS);
    gm = wx_bn_g[t];
    lax[t] = gm*iv; lbx[t] = wx_bn_b[t] - m*gm*iv;
    lpw[t] = psi_w[t];
  }
  __syncthreads();
  const int p = blockIdx.x*256 + t;
  const u16t* rg = yg + (size_t)p*64;
  const u16t* rx = yx + (size_t)p*64;
  float acc = psi_b[0];
  #pragma unroll
  for (int u = 0; u < 8; ++u){
    uint4 qg = *reinterpret_cast<const uint4*>(rg + u*8);
    uint4 qx = *reinterpret_cast<const uint4*>(rx + u*8);
    const u32t* g4 = reinterpret_cast<const u32t*>(&qg);
    const u32t* x4 = reinterpret_cast<const u32t*>(&qx);
    #pragma unroll
    for (int e = 0; e < 4; ++e){
      int j = u*8 + e*2;
      float gv0 = fmaf(b2f((u16t)g4[e]),        lag[j],   lbg[j]);
      float xv0 = fmaf(b2f((u16t)x4[e]),        lax[j],   lbx[j]);
      float gv1 = fmaf(b2f((u16t)(g4[e]>>16)),  lag[j+1], lbg[j+1]);
      float xv1 = fmaf(b2f((u16t)(x4[e]>>16)),  lax[j+1], lbx[j+1]);
      acc = fmaf(lpw[j],   lrelu(gv0 + xv0), acc);
      acc = fmaf(lpw[j+1], lrelu(gv1 + xv1), acc);
    }
  }
  psipre[p] = acc;
  float s = acc, q = acc*acc;
  #pragma unroll
  for (int o = 32; o; o >>= 1){ s += __shfl_xor(s, o); q += __shfl_xor(q, o); }
  if ((t & 63) == 0){ red[(t>>6)*2] = s; red[(t>>6)*2+1] = q; }
  __syncthreads();
  if (t == 0){
    atomicAdd(&stpsi[0], red[0]+red[2]+red[4]+red[6]);
    atomicAdd(&stpsi[1], red[1]+red[3]+red[5]+red[7]);
  }
}

// ---- psi = sigmoid(bn(psi_pre)); scale p1t rows in place ----
__global__ __launch_bounds__(256) void scale_p1_kernel(u16t* __restrict__ p1t, const float* __restrict__ psipre,
                                                       const float* __restrict__ stpsi,
                                                       const float* __restrict__ psi_bn_g, const float* __restrict__ psi_bn_b){
  const int p = blockIdx.x*256 + threadIdx.x;
  float m  = stpsi[0]*(1.0f/CNTF);
  float vv = fmaxf(stpsi[1]*(1.0f/CNTF) - m*m, 0.0f);
  float iv = 1.0f/sqrtf(vv + BNEPS);
  float ap = psi_bn_g[0]*iv;
  float bp = psi_bn_b[0] - m*ap;
  float z  = fmaf(psipre[p], ap, bp);
  float psi = 1.0f/(1.0f + expf(-z));
  u16t* r = p1t + (size_t)p*128;
  #pragma unroll
  for (int u = 0; u < 16; ++u){
    uint4 q = *reinterpret_cast<uint4*>(r + u*8);
    u32t* a = reinterpret_cast<u32t*>(&q);
    #pragma unroll
    for (int j = 0; j < 4; ++j){
      float lo = b2f((u16t)a[j]) * psi;
      float hi = b2f((u16t)(a[j]>>16)) * psi;
      a[j] = (u32t)f2b(lo) | ((u32t)f2b(hi) << 16);
    }
    *reinterpret_cast<uint4*>(r + u*8) = q;
  }
}

// ---- bn1 + lrelu in place on h1 [P][256] bf16 ----
__global__ __launch_bounds__(256) void bnrelu256_kernel(u16t* __restrict__ x, const float* __restrict__ st,
                                                        const float* __restrict__ g, const float* __restrict__ bb){
  __shared__ float sa[256], sc[256];
  const int t = threadIdx.x;
  {
    float m  = st[t*2]*(1.0f/CNTF);
    float vv = fmaxf(st[t*2+1]*(1.0f/CNTF) - m*m, 0.0f);
    float iv = 1.0f/sqrtf(vv + BNEPS);
    float gm = g[t];
    sa[t] = gm*iv; sc[t] = bb[t] - m*gm*iv;
  }
  __syncthreads();
  size_t e4 = ((size_t)blockIdx.x*256 + t)*4;
  int c0 = (int)(e4 & 255);
  uint2 v = *reinterpret_cast<uint2*>(x + e4);
  float f0 = lrelu(fmaf(b2f((u16t)v.x),        sa[c0],   sc[c0]));
  float f1 = lrelu(fmaf(b2f((u16t)(v.x>>16)),  sa[c0+1], sc[c0+1]));
  float f2 = lrelu(fmaf(b2f((u16t)v.y),        sa[c0+2], sc[c0+2]));
  float f3 = lrelu(fmaf(b2f((u16t)(v.y>>16)),  sa[c0+3], sc[c0+3]));
  v.x = (u32t)f2b(f0) | ((u32t)f2b(f1) << 16);
  v.y = (u32t)f2b(f2) | ((u32t)f2b(f3) << 16);
  *reinterpret_cast<uint2*>(x + e4) = v;
}

// ---- final: out[b][m][n] f32 = lrelu(bn2(h2[b][n][m])) via LDS tile transpose ----
__global__ __launch_bounds__(256) void final_kernel(const u16t* __restrict__ h2, const float* __restrict__ st,
                                                    const float* __restrict__ g, const float* __restrict__ bb,
                                                    float* __restrict__ out){
  __shared__ float am[128], cm[128];
  __shared__ float tile[64][129];
  const int t = threadIdx.x;
  if (t < 128){
    float m  = st[t*2]*(1.0f/CNTF);
    float vv = fmaxf(st[t*2+1]*(1.0f/CNTF) - m*m, 0.0f);
    float iv = 1.0f/sqrtf(vv + BNEPS);
    float gm = g[t];
    am[t] = gm*iv; cm[t] = bb[t] - m*gm*iv;
  }
  __syncthreads();
  const int n0 = blockIdx.x * 64;
  const int b  = blockIdx.y;
  #pragma unroll
  for (int i = 0; i < 32; ++i){
    int idx = t + i*256;
    int mm = idx & 127, nn = idx >> 7;
    float v = fmaf(b2f(h2[((size_t)b*NPTS + n0 + nn)*128 + mm]), am[mm], cm[mm]);
    tile[nn][mm] = lrelu(v);
  }
  __syncthreads();
  #pragma unroll
  for (int i = 0; i < 32; ++i){
    int idx = t + i*256;
    int nn = idx & 63, mm = idx >> 6;
    out[((size_t)(b*128 + mm))*NPTS + n0 + nn] = tile[nn][mm];
  }
}

extern "C" void kernel_launch(void* const* d_in, const int* in_sizes, int n_in,
                              void* d_out, int out_size, void* d_ws, size_t ws_size,
                              hipStream_t stream){
  const float* xyz1    = (const float*)d_in[0];
  const float* xyz2    = (const float*)d_in[1];
  const float* points1 = (const float*)d_in[2];
  const float* points2 = (const float*)d_in[3];
  const float* conv1_w = (const float*)d_in[4];
  const float* conv1_b = (const float*)d_in[5];
  const float* bn1_g   = (const float*)d_in[6];
  const float* bn1_b   = (const float*)d_in[7];
  const float* conv2_w = (const float*)d_in[8];
  const float* conv2_b = (const float*)d_in[9];
  const float* bn2_g   = (const float*)d_in[10];
  const float* bn2_b   = (const float*)d_in[11];
  const float* wg_w    = (const float*)d_in[12];
  const float* wg_b    = (const float*)d_in[13];
  const float* wg_bn_g = (const float*)d_in[14];
  const float* wg_bn_b = (const float*)d_in[15];
  const float* wx_w    = (const float*)d_in[16];
  const float* wx_b    = (const float*)d_in[17];
  const float* wx_bn_g = (const float*)d_in[18];
  const float* wx_bn_b = (const float*)d_in[19];
  const float* psi_w   = (const float*)d_in[20];
  const float* psi_b   = (const float*)d_in[21];
  const float* psi_bn_g= (const float*)d_in[22];
  const float* psi_bn_b= (const float*)d_in[23];

  char* ws = (char*)d_ws;
  float* stats  = (float*)(ws + O_STATS);
  u16t*  wb     = (u16t*)(ws + O_WB);
  float* psipre = (float*)(ws + O_PSIPRE);
  u16t*  p2t    = (u16t*)(ws + O_P2T);
  float* part   = (float*)(ws + O_PART);
  u16t*  p1t    = (u16t*)(ws + O_P1T);
  u16t*  itp    = (u16t*)(ws + O_INT);
  u16t*  h1t    = (u16t*)(ws + O_H1);
  float* pd     = (float*)(ws + O_PD);
  int*   pi     = (int*)(ws + O_PI);
  int*   idx3   = (int*)(ws + O_IDX3);
  float* w3     = (float*)(ws + O_W3);
  u16t*  ygt    = (u16t*)(ws + O_YG);
  u16t*  yxt    = (u16t*)(ws + O_YX);
  u16t*  h2t    = (u16t*)(ws + O_H2);

  hipMemsetAsync(ws + O_STATS, 0, 8192, stream);

  knn_part_kernel<<<dim3(NPTS/256, NCH, Bq), 256, 0, stream>>>(xyz1, xyz2, pd, pi);
  knn_merge_kernel<<<(Bq*NPTS)/256, 256, 0, stream>>>(pd, pi, idx3, w3);
  tpose_kernel<256, SPTS><<<dim3(SPTS/64, 4, Bq), 256, 0, stream>>>(points2, p2t);
  interp_kernel<<<Bq*(NPTS/64), 256, 0, stream>>>(p2t, idx3, w3, itp);
  tpose_kernel<128, NPTS><<<dim3(NPTS/64, 2, Bq), 256, 0, stream>>>(points1, p1t);
  wcvt_kernel<<<(WTOTAL+255)/256, 256, 0, stream>>>(conv1_w, conv2_w, wg_w, wx_w, wb);

  mfma_conv_kernel<256, 64, false><<<Bq*(NPTS/64), 256, 0, stream>>>(itp, nullptr, wb+WOFF_WG, wg_b, ygt, part);
  reduce_stats_kernel<128><<<4, 256, 0, stream>>>(part, stats+ST_WG);
  mfma_conv_kernel<128, 64, false><<<Bq*(NPTS/64), 256, 0, stream>>>(p1t, nullptr, wb+WOFF_WX, wx_b, yxt, part);
  reduce_stats_kernel<128><<<4, 256, 0, stream>>>(part, stats+ST_WX);
  gate_kernel<<<256, 256, 0, stream>>>(ygt, yxt, stats+ST_WG, stats+ST_WX,
                                       wg_bn_g, wg_bn_b, wx_bn_g, wx_bn_b,
                                       psi_w, psi_b, psipre, stats+ST_PSI);
  scale_p1_kernel<<<256, 256, 0, stream>>>(p1t, psipre, stats+ST_PSI, psi_bn_g, psi_bn_b);

  mfma_conv_kernel<384, 256, true><<<Bq*(NPTS/64), 256, 0, stream>>>(p1t, itp, wb+WOFF_C1, conv1_b, h1t, part);
  reduce_stats_kernel<512><<<16, 256, 0, stream>>>(part, stats+ST_BN1);
  bnrelu256_kernel<<<16384, 256, 0, stream>>>(h1t, stats+ST_BN1, bn1_g, bn1_b);

  mfma_conv_kernel<256, 128, false><<<Bq*(NPTS/64), 256, 0, stream>>>(h1t, nullptr, wb+WOFF_C2, conv2_b, h2t, part);
  reduce_stats_kernel<256><<<8, 256, 0, stream>>>(part, stats+ST_BN2);
  final_kernel<<<dim3(NPTS/64, Bq), 256, 0, stream>>>(h2t, stats+ST_BN2, bn2_g, bn2_b, (float*)d_out);
}

// Round 9
// 285.760 us; speedup vs baseline: 3.8641x; 1.1417x over previous
//
#include <hip/hip_runtime.h>
#include <hip/hip_bf16.h>

#define Bq    4
#define NPTS  16384
#define SPTS  2048
#define NCH   8
#define SCH   (SPTS/NCH)   // 256
#define CNTF  65536.0f
#define BNEPS 1e-5f

typedef unsigned short u16t;
typedef unsigned int   u32t;
typedef __attribute__((ext_vector_type(8))) short s16x8;
typedef __attribute__((ext_vector_type(4))) float f32x4;

#define AS1(p) ((const __attribute__((address_space(1))) void*)(p))
#define AS3(p) ((__attribute__((address_space(3))) void*)(p))

__device__ __forceinline__ float b2f(u16t u){
  union { u32t i; float f; } v; v.i = ((u32t)u) << 16; return v.f;
}
__device__ __forceinline__ u16t f2b(float f){
  __hip_bfloat16 h = __float2bfloat16(f);
  return *reinterpret_cast<u16t*>(&h);
}
__device__ __forceinline__ float lrelu(float x){ return x >= 0.0f ? x : 0.2f*x; }

// ---- stats f32 offsets: per-channel [sum,sumsq] pairs ----
#define ST_WG  0
#define ST_WX  128
#define ST_PSI 256
#define ST_BN1 272
#define ST_BN2 784

// ---- bf16 weight element offsets inside WB region ----
#define WOFF_C1 0
#define WOFF_C2 98304
#define WOFF_WG 131072
#define WOFF_WX 147456
#define WTOTAL  155648

// ---- ws byte offsets (time-disjoint aliasing; total ~84.6 MB) ----
#define O_STATS  0u
#define O_WB     8192u
#define O_PSIPRE 319488u
#define O_P2T    581632u        // 4 MB bf16 [B][S][256]; dead after interp
#define O_PART   O_P2T          // conv stats partials [1024][<=512] f32 = 2 MB, used after interp
#define O_P1T    4775936u       // 16.7 MB bf16 [B][N][128]; psi-scaled IN PLACE
#define O_INT    21553152u      // 33.5 MB bf16 [B][N][256] interp; h2t aliases later
#define O_H1     55107584u      // 33.5 MB bf16 [B][N][256] h1; bnrelu IN PLACE
// knn scratch lives inside the (not-yet-written) H1 region:
#define O_PD     O_H1                    // 6.29 MB f32 partial dists [B][N][NCH][3]
#define O_PI     (O_H1 + 6291456u)       // 6.29 MB i32 partial idx
#define O_IDX3   (O_H1 + 12582912u)      // 786 KB
#define O_W3     (O_H1 + 13369344u)      // 786 KB (all dead before ygt written)
#define O_YG     O_H1                    // ygt/yxt live steps 5-8, dead before h1 written
#define O_YX     (O_H1 + 8388608u)
#define O_H2     O_INT                   // h2 bf16, written after interp dead
// end = 55107584 + 33554432 = 88662016 B

// ---- 3-NN part 1: per-chunk top-3 over SCH s-points (full occupancy) ----
__global__ __launch_bounds__(256) void knn_part_kernel(const float* __restrict__ xyz1, const float* __restrict__ xyz2,
                                                       float* __restrict__ pd, int* __restrict__ pi){
  __shared__ float4 sp[SCH];
  const int b = blockIdx.z;
  const int c = blockIdx.y;
  const int t = threadIdx.x;
  {
    int s = c*SCH + t;
    float x = xyz2[(b*3+0)*SPTS+s];
    float y = xyz2[(b*3+1)*SPTS+s];
    float z = xyz2[(b*3+2)*SPTS+s];
    sp[t] = make_float4(x, y, z, x*x+y*y+z*z);
  }
  __syncthreads();
  const int n = blockIdx.x*256 + t;
  float px = xyz1[(b*3+0)*NPTS+n];
  float py = xyz1[(b*3+1)*NPTS+n];
  float pz = xyz1[(b*3+2)*NPTS+n];
  float s1 = px*px+py*py+pz*pz;
  float d0=3.4e38f, d1=3.4e38f, d2=3.4e38f;
  int   i0=0, i1=0, i2=0;
  for (int s=0; s<SCH; ++s){
    float4 q = sp[s];
    float dot = fmaf(pz, q.z, fmaf(py, q.y, px*q.x));
    float key = (s1 + q.w) - 2.0f*dot;   // same arithmetic as passing round-4 scan
    if (key < d2){
      int gi = c*SCH + s;
      if (key < d1){
        if (key < d0){ d2=d1; i2=i1; d1=d0; i1=i0; d0=key; i0=gi; }
        else         { d2=d1; i2=i1; d1=key; i1=gi; }
      } else         { d2=key; i2=gi; }
    }
  }
  size_t base = (((size_t)b*NPTS + n)*NCH + c)*3;
  pd[base]=d0; pd[base+1]=d1; pd[base+2]=d2;
  pi[base]=i0; pi[base+1]=i1; pi[base+2]=i2;
}

// ---- 3-NN part 2: merge NCH partial top-3 lists (chunk-order => stable ties) ----
__global__ __launch_bounds__(256) void knn_merge_kernel(const float* __restrict__ pd, const int* __restrict__ pi,
                                                        int* __restrict__ idx3, float* __restrict__ w3){
  const int p = blockIdx.x*256 + threadIdx.x;   // [0, B*N)
  const float* dp = pd + (size_t)p*NCH*3;
  const int*   ip = pi + (size_t)p*NCH*3;
  float d0=3.4e38f, d1=3.4e38f, d2=3.4e38f;
  int   i0=0, i1=0, i2=0;
  #pragma unroll
  for (int k=0; k<NCH*3; ++k){
    float key = dp[k]; int gi = ip[k];
    if (key < d2){
      if (key < d1){
        if (key < d0){ d2=d1; i2=i1; d1=d0; i1=i0; d0=key; i0=gi; }
        else         { d2=d1; i2=i1; d1=key; i1=gi; }
      } else         { d2=key; i2=gi; }
    }
  }
  float r0=1.0f/(d0+1e-8f), r1=1.0f/(d1+1e-8f), r2=1.0f/(d2+1e-8f);
  float rs = r0+r1+r2;
  size_t base = (size_t)p*3;
  idx3[base]=i0; idx3[base+1]=i1; idx3[base+2]=i2;
  w3[base]=r0/rs; w3[base+1]=r1/rs; w3[base+2]=r2/rs;
}

// ---- tiled transpose: src f32 [B][C][NN] -> dst bf16 [B][NN][C] ----
template<int C, int NN>
__global__ __launch_bounds__(256) void tpose_kernel(const float* __restrict__ src, u16t* __restrict__ dst){
  __shared__ float tile[64][65];
  const int n0 = blockIdx.x * 64;
  const int c0 = blockIdx.y * 64;
  const int b  = blockIdx.z;
  const int t  = threadIdx.x;
  #pragma unroll
  for (int i = 0; i < 16; ++i){
    int idx = t + i*256;
    int cc = idx >> 6, nn = idx & 63;
    tile[cc][nn] = src[((size_t)b*C + c0 + cc)*NN + n0 + nn];
  }
  __syncthreads();
  #pragma unroll
  for (int i = 0; i < 16; ++i){
    int idx = t + i*256;
    int nn = idx >> 6, cc = idx & 63;
    dst[((size_t)b*NN + n0 + nn)*C + c0 + cc] = f2b(tile[cc][nn]);
  }
}

// ---- weight convert f32 -> bf16 into WB ----
__global__ __launch_bounds__(256) void wcvt_kernel(const float* __restrict__ w1, const float* __restrict__ w2,
                                                   const float* __restrict__ wg, const float* __restrict__ wx,
                                                   u16t* __restrict__ wb){
  int i = blockIdx.x*256 + threadIdx.x;
  if (i >= WTOTAL) return;
  float v;
  if      (i < WOFF_C2) v = w1[i];
  else if (i < WOFF_WG) v = w2[i - WOFF_C2];
  else if (i < WOFF_WX) v = wg[i - WOFF_WG];
  else                  v = wx[i - WOFF_WX];
  wb[i] = f2b(v);
}

// ---- interp: point-major out [B][N][256] ----
__global__ __launch_bounds__(256) void interp_kernel(const u16t* __restrict__ p2t, const int* __restrict__ idx3,
                                                     const float* __restrict__ w3, u16t* __restrict__ it){
  const int bid = blockIdx.x;
  const int b = bid >> 8;
  const int n0 = (bid & 255) * 64;
  const int wv = threadIdx.x >> 6;
  const int lane = threadIdx.x & 63;
  const int n = n0 + lane;
  size_t pb = ((size_t)b*NPTS + n)*3;
  int i0 = idx3[pb], i1 = idx3[pb+1], i2 = idx3[pb+2];
  float w0 = w3[pb], w1 = w3[pb+1], w2 = w3[pb+2];
  const u16t* r0 = p2t + ((size_t)b*SPTS + i0)*256;
  const u16t* r1 = p2t + ((size_t)b*SPTS + i1)*256;
  const u16t* r2 = p2t + ((size_t)b*SPTS + i2)*256;
  u16t* orow = it + ((size_t)b*NPTS + n)*256;
  for (int c = wv*64; c < wv*64 + 64; c += 8){
    uint4 q0 = *reinterpret_cast<const uint4*>(r0 + c);
    uint4 q1 = *reinterpret_cast<const uint4*>(r1 + c);
    uint4 q2 = *reinterpret_cast<const uint4*>(r2 + c);
    const u32t* a0 = reinterpret_cast<const u32t*>(&q0);
    const u32t* a1 = reinterpret_cast<const u32t*>(&q1);
    const u32t* a2 = reinterpret_cast<const u32t*>(&q2);
    u32t ow[4];
    #pragma unroll
    for (int j = 0; j < 4; ++j){
      u32t u0 = a0[j], u1 = a1[j], u2 = a2[j];
      float lo = fmaf(w2, b2f((u16t)u2), fmaf(w1, b2f((u16t)u1), w0*b2f((u16t)u0)));
      float hi = fmaf(w2, b2f((u16t)(u2>>16)), fmaf(w1, b2f((u16t)(u1>>16)), w0*b2f((u16t)(u0>>16))));
      ow[j] = (u32t)f2b(lo) | ((u32t)f2b(hi) << 16);
    }
    *reinterpret_cast<uint4*>(orow + c) = make_uint4(ow[0], ow[1], ow[2], ow[3]);
  }
}

// ---- MFMA conv1x1, LDS-staged activations (global_load_lds w16, dbuf, XOR-swizzled) ----
// y[B][N][OUT] = W[OUT][CIN] . x[B][N][CIN] + bias (raw, pre-BN)
// LDS tile: [64 pts][64 ch] bf16 per chunk (128 B/row). Swizzle: 16B slot s stores
// global slot s^(row&7) (pre-swizzled source); ds_read applies the same XOR. (T2/G4, rule #21)
template<int CIN, int OUT, bool SPLIT>
__global__ __launch_bounds__(256, 1) void mfma_conv_kernel(const u16t* __restrict__ xa, const u16t* __restrict__ xb,
                                                           const u16t* __restrict__ W, const float* __restrict__ bias,
                                                           u16t* __restrict__ y, float* __restrict__ partial){
  constexpr int MW = OUT/4;      // per-wave M slice
  constexpr int MF = MW/16;      // m-fragments per wave
  constexpr int NC = CIN/64;     // 64-channel k-chunks
  __shared__ u16t sbuf[2][64*64];   // 16 KB double buffer
  const int bid = blockIdx.x;
  const int b = bid >> 8;
  const int n0 = (bid & 255) * 64;
  const int wv = threadIdx.x >> 6;
  const int lane = threadIdx.x & 63;
  const int lr = lane & 15;
  const int kg = lane >> 4;
  const int m0 = wv * MW;

  f32x4 acc[MF][4];
  #pragma unroll
  for (int mf = 0; mf < MF; ++mf)
    #pragma unroll
    for (int nf = 0; nf < 4; ++nf){ acc[mf][nf][0]=0.f; acc[mf][nf][1]=0.f; acc[mf][nf][2]=0.f; acc[mf][nf][3]=0.f; }

  const u16t* wrow[MF];
  #pragma unroll
  for (int mf = 0; mf < MF; ++mf)
    wrow[mf] = W + (size_t)(m0 + mf*16 + lr)*CIN + kg*8;

  // staging geometry: instr i covers rows wv*16+i*8+(lane>>3), slot (lane&7),
  // reading the swizzled global slot (lane&7)^((lane>>3)&7).
  const int prow0 = wv*16 + (lane>>3);                 // +8 for i=1 (row&7 unchanged)
  const int gslot = (lane & 7) ^ ((lane >> 3) & 7);    // pre-swizzled source slot
  // per-chunk ds_read element offsets (swizzled), slot' = (ks*4+kg)^(lr&7)
  int rdoff[2][4];
  #pragma unroll
  for (int ks = 0; ks < 2; ++ks)
    #pragma unroll
    for (int nf = 0; nf < 4; ++nf)
      rdoff[ks][nf] = (nf*16 + lr)*64 + (((ks*4 + kg) ^ (lr & 7)) << 3);

  // stage chunk c into buffer buf (2 x 1KB global_load_lds per wave)
  auto stage = [&](int c, int buf){
    #pragma unroll
    for (int i = 0; i < 2; ++i){
      int p = prow0 + i*8;
      const u16t* g;
      if (SPLIT){
        if (c < 2) g = xa + ((size_t)b*NPTS + n0 + p)*128 + c*64     + gslot*8;
        else       g = xb + ((size_t)b*NPTS + n0 + p)*256 + (c-2)*64 + gslot*8;
      } else {
        g = xa + ((size_t)b*NPTS + n0 + p)*CIN + c*64 + gslot*8;
      }
      u16t* l = &sbuf[buf][(wv*16 + i*8)*64];   // wave-uniform base; HW adds lane*16B
      __builtin_amdgcn_global_load_lds(AS1(g), AS3(l), 16, 0, 0);
    }
  };

  stage(0, 0);
  __syncthreads();
  #pragma unroll
  for (int c = 0; c < NC; ++c){
    if (c + 1 < NC) stage(c+1, (c+1)&1);
    #pragma unroll
    for (int ks = 0; ks < 2; ++ks){
      const int k0 = c*2 + ks;
      s16x8 av[MF];
      #pragma unroll
      for (int mf = 0; mf < MF; ++mf)
        av[mf] = *reinterpret_cast<const s16x8*>(wrow[mf] + k0*32);
      s16x8 bv[4];
      #pragma unroll
      for (int nf = 0; nf < 4; ++nf)
        bv[nf] = *reinterpret_cast<const s16x8*>(&sbuf[c&1][rdoff[ks][nf]]);
      #pragma unroll
      for (int mf = 0; mf < MF; ++mf)
        #pragma unroll
        for (int nf = 0; nf < 4; ++nf)
          acc[mf][nf] = __builtin_amdgcn_mfma_f32_16x16x32_bf16(av[mf], bv[nf], acc[mf][nf], 0, 0, 0);
    }
    __syncthreads();   // drains stage(c+1) vmcnt + syncs readers of buf[c&1]
  }

  #pragma unroll
  for (int mf = 0; mf < MF; ++mf){
    int mb = m0 + mf*16 + kg*4;
    float4 bs = *reinterpret_cast<const float4*>(bias + mb);
    float s0=0.f,s1=0.f,s2=0.f,s3=0.f,q0=0.f,q1=0.f,q2=0.f,q3=0.f;
    #pragma unroll
    for (int nf = 0; nf < 4; ++nf){
      int n = n0 + nf*16 + lr;
      float v0 = acc[mf][nf][0] + bs.x;
      float v1 = acc[mf][nf][1] + bs.y;
      float v2 = acc[mf][nf][2] + bs.z;
      float v3 = acc[mf][nf][3] + bs.w;
      s0+=v0; q0+=v0*v0; s1+=v1; q1+=v1*v1;
      s2+=v2; q2+=v2*v2; s3+=v3; q3+=v3*v3;
      uint2 pv;
      pv.x = (u32t)f2b(v0) | ((u32t)f2b(v1) << 16);
      pv.y = (u32t)f2b(v2) | ((u32t)f2b(v3) << 16);
      *reinterpret_cast<uint2*>(y + ((size_t)b*NPTS + n)*OUT + mb) = pv;
    }
    // reduce across the 16 lanes (lr) sharing this channel quad; xor<16 stays in-group
    #pragma unroll
    for (int o = 1; o < 16; o <<= 1){
      s0 += __shfl_xor(s0, o); s1 += __shfl_xor(s1, o);
      s2 += __shfl_xor(s2, o); s3 += __shfl_xor(s3, o);
      q0 += __shfl_xor(q0, o); q1 += __shfl_xor(q1, o);
      q2 += __shfl_xor(q2, o); q3 += __shfl_xor(q3, o);
    }
    if (lr == 0){
      float* pp = partial + (size_t)bid*(OUT*2) + mb*2;
      pp[0]=s0; pp[1]=q0; pp[2]=s1; pp[3]=q1;
      pp[4]=s2; pp[5]=q2; pp[6]=s3; pp[7]=q3;
    }
  }
}

// ---- reduce conv partials [1024][E] -> stats[E] (no atomics) ----
template<int E>
__global__ __launch_bounds__(256) void reduce_stats_kernel(const float* __restrict__ p, float* __restrict__ st){
  __shared__ float ls[8][32];
  const int t = threadIdx.x;
  const int kq = t >> 5, es = t & 31;
  const int e = blockIdx.x*32 + es;
  float s = 0.f;
  const float* pp = p + (size_t)kq*128*E + e;
  #pragma unroll 16
  for (int i = 0; i < 128; ++i) s += pp[(size_t)i*E];
  ls[kq][es] = s;
  __syncthreads();
  if (kq == 0){
    st[e] = ((ls[0][es]+ls[1][es])+(ls[2][es]+ls[3][es]))
          + ((ls[4][es]+ls[5][es])+(ls[6][es]+ls[7][es]));
  }
}

// ---- gate: psi_pre[p] = psi_w . lrelu(bn(yg)+bn(yx)) + psi_b, + psi stats ----
__global__ __launch_bounds__(256) void gate_kernel(const u16t* __restrict__ yg, const u16t* __restrict__ yx,
                                                   const float* __restrict__ stg, const float* __restrict__ stx,
                                                   const float* __restrict__ wg_bn_g, const float* __restrict__ wg_bn_b,
                                                   const float* __restrict__ wx_bn_g, const float* __restrict__ wx_bn_b,
                                                   const float* __restrict__ psi_w, const float* __restrict__ psi_b,
                                                   float* __restrict__ psipre, float* __restrict__ stpsi){
  __shared__ float lag[64], lbg[64], lax[64], lbx[64], lpw[64];
  __shared__ float red[8];
  const int t = threadIdx.x;
  if (t < 64){
    float m  = stg[t*2] * (1.0f/CNTF);
    float vv = fmaxf(stg[t*2+1]*(1.0f/CNTF) - m*m, 0.0f);
    float iv = 1.0f/sqrtf(vv + BNEPS);
    float gm = wg_bn_g[t];
    lag[t] = gm*iv; lbg[t] = wg_bn_b[t] - m*gm*iv;
    m  = stx[t*2] * (1.0f/CNTF);
    vv = fmaxf(stx[t*2+1]*(1.0f/CNTF) - m*m, 0.0f);
    iv = 1.0f/sqrtf(vv + BNEPS);
    gm = wx_bn_g[t];
    lax[t] = gm*iv; lbx[t] = wx_bn_b[t] - m*gm*iv;
    lpw[t] = psi_w[t];
  }
  __syncthreads();
  const int p = blockIdx.x*256 + t;
  const u16t* rg = yg + (size_t)p*64;
  const u16t* rx = yx + (size_t)p*64;
  float acc = psi_b[0];
  #pragma unroll
  for (int u = 0; u < 8; ++u){
    uint4 qg = *reinterpret_cast<const uint4*>(rg + u*8);
    uint4 qx = *reinterpret_cast<const uint4*>(rx + u*8);
    const u32t* g4 = reinterpret_cast<const u32t*>(&qg);
    const u32t* x4 = reinterpret_cast<const u32t*>(&qx);
    #pragma unroll
    for (int e = 0; e < 4; ++e){
      int j = u*8 + e*2;
      float gv0 = fmaf(b2f((u16t)g4[e]),        lag[j],   lbg[j]);
      float xv0 = fmaf(b2f((u16t)x4[e]),        lax[j],   lbx[j]);
      float gv1 = fmaf(b2f((u16t)(g4[e]>>16)),  lag[j+1], lbg[j+1]);
      float xv1 = fmaf(b2f((u16t)(x4[e]>>16)),  lax[j+1], lbx[j+1]);
      acc = fmaf(lpw[j],   lrelu(gv0 + xv0), acc);
      acc = fmaf(lpw[j+1], lrelu(gv1 + xv1), acc);
    }
  }
  psipre[p] = acc;
  float s = acc, q = acc*acc;
  #pragma unroll
  for (int o = 32; o; o >>= 1){ s += __shfl_xor(s, o); q += __shfl_xor(q, o); }
  if ((t & 63) == 0){ red[(t>>6)*2] = s; red[(t>>6)*2+1] = q; }
  __syncthreads();
  if (t == 0){
    atomicAdd(&stpsi[0], red[0]+red[2]+red[4]+red[6]);
    atomicAdd(&stpsi[1], red[1]+red[3]+red[5]+red[7]);
  }
}

// ---- psi = sigmoid(bn(psi_pre)); scale p1t rows in place ----
__global__ __launch_bounds__(256) void scale_p1_kernel(u16t* __restrict__ p1t, const float* __restrict__ psipre,
                                                       const float* __restrict__ stpsi,
                                                       const float* __restrict__ psi_bn_g, const float* __restrict__ psi_bn_b){
  const int p = blockIdx.x*256 + threadIdx.x;
  float m  = stpsi[0]*(1.0f/CNTF);
  float vv = fmaxf(stpsi[1]*(1.0f/CNTF) - m*m, 0.0f);
  float iv = 1.0f/sqrtf(vv + BNEPS);
  float ap = psi_bn_g[0]*iv;
  float bp = psi_bn_b[0] - m*ap;
  float z  = fmaf(psipre[p], ap, bp);
  float psi = 1.0f/(1.0f + expf(-z));
  u16t* r = p1t + (size_t)p*128;
  #pragma unroll
  for (int u = 0; u < 16; ++u){
    uint4 q = *reinterpret_cast<uint4*>(r + u*8);
    u32t* a = reinterpret_cast<u32t*>(&q);
    #pragma unroll
    for (int j = 0; j < 4; ++j){
      float lo = b2f((u16t)a[j]) * psi;
      float hi = b2f((u16t)(a[j]>>16)) * psi;
      a[j] = (u32t)f2b(lo) | ((u32t)f2b(hi) << 16);
    }
    *reinterpret_cast<uint4*>(r + u*8) = q;
  }
}

// ---- bn1 + lrelu in place on h1 [P][256] bf16 ----
__global__ __launch_bounds__(256) void bnrelu256_kernel(u16t* __restrict__ x, const float* __restrict__ st,
                                                        const float* __restrict__ g, const float* __restrict__ bb){
  __shared__ float sa[256], sc[256];
  const int t = threadIdx.x;
  {
    float m  = st[t*2]*(1.0f/CNTF);
    float vv = fmaxf(st[t*2+1]*(1.0f/CNTF) - m*m, 0.0f);
    float iv = 1.0f/sqrtf(vv + BNEPS);
    float gm = g[t];
    sa[t] = gm*iv; sc[t] = bb[t] - m*gm*iv;
  }
  __syncthreads();
  size_t e4 = ((size_t)blockIdx.x*256 + t)*4;
  int c0 = (int)(e4 & 255);
  uint2 v = *reinterpret_cast<uint2*>(x + e4);
  float f0 = lrelu(fmaf(b2f((u16t)v.x),        sa[c0],   sc[c0]));
  float f1 = lrelu(fmaf(b2f((u16t)(v.x>>16)),  sa[c0+1], sc[c0+1]));
  float f2 = lrelu(fmaf(b2f((u16t)v.y),        sa[c0+2], sc[c0+2]));
  float f3 = lrelu(fmaf(b2f((u16t)(v.y>>16)),  sa[c0+3], sc[c0+3]));
  v.x = (u32t)f2b(f0) | ((u32t)f2b(f1) << 16);
  v.y = (u32t)f2b(f2) | ((u32t)f2b(f3) << 16);
  *reinterpret_cast<uint2*>(x + e4) = v;
}

// ---- final: out[b][m][n] f32 = lrelu(bn2(h2[b][n][m])) via LDS tile transpose ----
__global__ __launch_bounds__(256) void final_kernel(const u16t* __restrict__ h2, const float* __restrict__ st,
                                                    const float* __restrict__ g, const float* __restrict__ bb,
                                                    float* __restrict__ out){
  __shared__ float am[128], cm[128];
  __shared__ float tile[64][129];
  const int t = threadIdx.x;
  if (t < 128){
    float m  = st[t*2]*(1.0f/CNTF);
    float vv = fmaxf(st[t*2+1]*(1.0f/CNTF) - m*m, 0.0f);
    float iv = 1.0f/sqrtf(vv + BNEPS);
    float gm = g[t];
    am[t] = gm*iv; cm[t] = bb[t] - m*gm*iv;
  }
  __syncthreads();
  const int n0 = blockIdx.x * 64;
  const int b  = blockIdx.y;
  #pragma unroll
  for (int i = 0; i < 32; ++i){
    int idx = t + i*256;
    int mm = idx & 127, nn = idx >> 7;
    float v = fmaf(b2f(h2[((size_t)b*NPTS + n0 + nn)*128 + mm]), am[mm], cm[mm]);
    tile[nn][mm] = lrelu(v);
  }
  __syncthreads();
  #pragma unroll
  for (int i = 0; i < 32; ++i){
    int idx = t + i*256;
    int nn = idx & 63, mm = idx >> 6;
    out[((size_t)(b*128 + mm))*NPTS + n0 + nn] = tile[nn][mm];
  }
}

extern "C" void kernel_launch(void* const* d_in, const int* in_sizes, int n_in,
                              void* d_out, int out_size, void* d_ws, size_t ws_size,
                              hipStream_t stream){
  const float* xyz1    = (const float*)d_in[0];
  const float* xyz2    = (const float*)d_in[1];
  const float* points1 = (const float*)d_in[2];
  const float* points2 = (const float*)d_in[3];
  const float* conv1_w = (const float*)d_in[4];
  const float* conv1_b = (const float*)d_in[5];
  const float* bn1_g   = (const float*)d_in[6];
  const float* bn1_b   = (const float*)d_in[7];
  const float* conv2_w = (const float*)d_in[8];
  const float* conv2_b = (const float*)d_in[9];
  const float* bn2_g   = (const float*)d_in[10];
  const float* bn2_b   = (const float*)d_in[11];
  const float* wg_w    = (const float*)d_in[12];
  const float* wg_b    = (const float*)d_in[13];
  const float* wg_bn_g = (const float*)d_in[14];
  const float* wg_bn_b = (const float*)d_in[15];
  const float* wx_w    = (const float*)d_in[16];
  const float* wx_b    = (const float*)d_in[17];
  const float* wx_bn_g = (const float*)d_in[18];
  const float* wx_bn_b = (const float*)d_in[19];
  const float* psi_w   = (const float*)d_in[20];
  const float* psi_b   = (const float*)d_in[21];
  const float* psi_bn_g= (const float*)d_in[22];
  const float* psi_bn_b= (const float*)d_in[23];

  char* ws = (char*)d_ws;
  float* stats  = (float*)(ws + O_STATS);
  u16t*  wb     = (u16t*)(ws + O_WB);
  float* psipre = (float*)(ws + O_PSIPRE);
  u16t*  p2t    = (u16t*)(ws + O_P2T);
  float* part   = (float*)(ws + O_PART);
  u16t*  p1t    = (u16t*)(ws + O_P1T);
  u16t*  itp    = (u16t*)(ws + O_INT);
  u16t*  h1t    = (u16t*)(ws + O_H1);
  float* pd     = (float*)(ws + O_PD);
  int*   pi     = (int*)(ws + O_PI);
  int*   idx3   = (int*)(ws + O_IDX3);
  float* w3     = (float*)(ws + O_W3);
  u16t*  ygt    = (u16t*)(ws + O_YG);
  u16t*  yxt    = (u16t*)(ws + O_YX);
  u16t*  h2t    = (u16t*)(ws + O_H2);

  hipMemsetAsync(ws + O_STATS, 0, 8192, stream);

  knn_part_kernel<<<dim3(NPTS/256, NCH, Bq), 256, 0, stream>>>(xyz1, xyz2, pd, pi);
  knn_merge_kernel<<<(Bq*NPTS)/256, 256, 0, stream>>>(pd, pi, idx3, w3);
  tpose_kernel<256, SPTS><<<dim3(SPTS/64, 4, Bq), 256, 0, stream>>>(points2, p2t);
  interp_kernel<<<Bq*(NPTS/64), 256, 0, stream>>>(p2t, idx3, w3, itp);
  tpose_kernel<128, NPTS><<<dim3(NPTS/64, 2, Bq), 256, 0, stream>>>(points1, p1t);
  wcvt_kernel<<<(WTOTAL+255)/256, 256, 0, stream>>>(conv1_w, conv2_w, wg_w, wx_w, wb);

  mfma_conv_kernel<256, 64, false><<<Bq*(NPTS/64), 256, 0, stream>>>(itp, nullptr, wb+WOFF_WG, wg_b, ygt, part);
  reduce_stats_kernel<128><<<4, 256, 0, stream>>>(part, stats+ST_WG);
  mfma_conv_kernel<128, 64, false><<<Bq*(NPTS/64), 256, 0, stream>>>(p1t, nullptr, wb+WOFF_WX, wx_b, yxt, part);
  reduce_stats_kernel<128><<<4, 256, 0, stream>>>(part, stats+ST_WX);
  gate_kernel<<<256, 256, 0, stream>>>(ygt, yxt, stats+ST_WG, stats+ST_WX,
                                       wg_bn_g, wg_bn_b, wx_bn_g, wx_bn_b,
                                       psi_w, psi_b, psipre, stats+ST_PSI);
  scale_p1_kernel<<<256, 256, 0, stream>>>(p1t, psipre, stats+ST_PSI, psi_bn_g, psi_bn_b);

  mfma_conv_kernel<384, 256, true><<<Bq*(NPTS/64), 256, 0, stream>>>(p1t, itp, wb+WOFF_C1, conv1_b, h1t, part);
  reduce_stats_kernel<512><<<16, 256, 0, stream>>>(part, stats+ST_BN1);
  bnrelu256_kernel<<<16384, 256, 0, stream>>>(h1t, stats+ST_BN1, bn1_g, bn1_b);

  mfma_conv_kernel<256, 128, false><<<Bq*(NPTS/64), 256, 0, stream>>>(h1t, nullptr, wb+WOFF_C2, conv2_b, h2t, part);
  reduce_stats_kernel<256><<<8, 256, 0, stream>>>(part, stats+ST_BN2);
  final_kernel<<<dim3(NPTS/64, Bq), 256, 0, stream>>>(h2t, stats+ST_BN2, bn2_g, bn2_b, (float*)d_out);
}

// Round 10
// 241.009 us; speedup vs baseline: 4.5816x; 1.1857x over previous
//
#include <hip/hip_runtime.h>
#include <hip/hip_bf16.h>

#define Bq    4
#define NPTS  16384
#define SPTS  2048
#define NCH   8
#define SCH   (SPTS/NCH)   // 256
#define CNTF  65536.0f
#define BNEPS 1e-5f

typedef unsigned short u16t;
typedef unsigned int   u32t;
typedef __attribute__((ext_vector_type(8))) short s16x8;
typedef __attribute__((ext_vector_type(4))) float f32x4;

#define AS1(p) ((const __attribute__((address_space(1))) void*)(p))
#define AS3(p) ((__attribute__((address_space(3))) void*)(p))

__device__ __forceinline__ float b2f(u16t u){
  union { u32t i; float f; } v; v.i = ((u32t)u) << 16; return v.f;
}
__device__ __forceinline__ u16t f2b(float f){
  __hip_bfloat16 h = __float2bfloat16(f);
  return *reinterpret_cast<u16t*>(&h);
}
__device__ __forceinline__ float lrelu(float x){ return x >= 0.0f ? x : 0.2f*x; }

// ---- stats f32 offsets: per-channel [sum,sumsq] pairs ----
#define ST_WG  0
#define ST_WX  128
#define ST_PSI 256
#define ST_BN1 272
#define ST_BN2 784

// ---- bf16 weight element offsets inside WB region ----
#define WOFF_C1 0
#define WOFF_C2 98304
#define WOFF_WG 131072
#define WOFF_WX 147456
#define WTOTAL  155648

// ---- ws byte offsets (time-disjoint aliasing; total ~84.6 MB) ----
#define O_STATS  0u
#define O_WB     8192u
#define O_PSIPRE 319488u
#define O_P2T    581632u        // 4 MB bf16 [B][S][256]; dead after interp
#define O_PART   O_P2T          // conv stats partials [1024][<=512] f32 = 2 MB, used after interp
#define O_P1T    4775936u       // 16.7 MB bf16 [B][N][128]; psi-scaled IN PLACE
#define O_INT    21553152u      // 33.5 MB bf16 [B][N][256] interp; h2t aliases later
#define O_H1     55107584u      // 33.5 MB bf16 [B][N][256] h1; bnrelu IN PLACE
// knn scratch lives inside the (not-yet-written) H1 region:
#define O_PD     O_H1                    // 6.29 MB f32 partial dists [B][N][NCH][3]
#define O_PI     (O_H1 + 6291456u)       // 6.29 MB i32 partial idx
#define O_IDX3   (O_H1 + 12582912u)      // 786 KB
#define O_W3     (O_H1 + 13369344u)      // 786 KB (all dead before ygt written)
#define O_YG     O_H1                    // ygt/yxt live steps 5-8, dead before h1 written
#define O_YX     (O_H1 + 8388608u)
#define O_H2     O_INT                   // h2 bf16, written after interp dead
// end = 55107584 + 33554432 = 88662016 B

// ---- 3-NN part 1: per-chunk top-3 over SCH s-points (full occupancy) ----
__global__ __launch_bounds__(256) void knn_part_kernel(const float* __restrict__ xyz1, const float* __restrict__ xyz2,
                                                       float* __restrict__ pd, int* __restrict__ pi){
  __shared__ float4 sp[SCH];
  const int b = blockIdx.z;
  const int c = blockIdx.y;
  const int t = threadIdx.x;
  {
    int s = c*SCH + t;
    float x = xyz2[(b*3+0)*SPTS+s];
    float y = xyz2[(b*3+1)*SPTS+s];
    float z = xyz2[(b*3+2)*SPTS+s];
    sp[t] = make_float4(x, y, z, x*x+y*y+z*z);
  }
  __syncthreads();
  const int n = blockIdx.x*256 + t;
  float px = xyz1[(b*3+0)*NPTS+n];
  float py = xyz1[(b*3+1)*NPTS+n];
  float pz = xyz1[(b*3+2)*NPTS+n];
  float s1 = px*px+py*py+pz*pz;
  float d0=3.4e38f, d1=3.4e38f, d2=3.4e38f;
  int   i0=0, i1=0, i2=0;
  for (int s=0; s<SCH; ++s){
    float4 q = sp[s];
    float dot = fmaf(pz, q.z, fmaf(py, q.y, px*q.x));
    float key = (s1 + q.w) - 2.0f*dot;   // same arithmetic as passing round-4 scan
    if (key < d2){
      int gi = c*SCH + s;
      if (key < d1){
        if (key < d0){ d2=d1; i2=i1; d1=d0; i1=i0; d0=key; i0=gi; }
        else         { d2=d1; i2=i1; d1=key; i1=gi; }
      } else         { d2=key; i2=gi; }
    }
  }
  size_t base = (((size_t)b*NPTS + n)*NCH + c)*3;
  pd[base]=d0; pd[base+1]=d1; pd[base+2]=d2;
  pi[base]=i0; pi[base+1]=i1; pi[base+2]=i2;
}

// ---- 3-NN part 2: merge NCH partial top-3 lists (chunk-order => stable ties) ----
__global__ __launch_bounds__(256) void knn_merge_kernel(const float* __restrict__ pd, const int* __restrict__ pi,
                                                        int* __restrict__ idx3, float* __restrict__ w3){
  const int p = blockIdx.x*256 + threadIdx.x;   // [0, B*N)
  const float* dp = pd + (size_t)p*NCH*3;
  const int*   ip = pi + (size_t)p*NCH*3;
  float d0=3.4e38f, d1=3.4e38f, d2=3.4e38f;
  int   i0=0, i1=0, i2=0;
  #pragma unroll
  for (int k=0; k<NCH*3; ++k){
    float key = dp[k]; int gi = ip[k];
    if (key < d2){
      if (key < d1){
        if (key < d0){ d2=d1; i2=i1; d1=d0; i1=i0; d0=key; i0=gi; }
        else         { d2=d1; i2=i1; d1=key; i1=gi; }
      } else         { d2=key; i2=gi; }
    }
  }
  float r0=1.0f/(d0+1e-8f), r1=1.0f/(d1+1e-8f), r2=1.0f/(d2+1e-8f);
  float rs = r0+r1+r2;
  size_t base = (size_t)p*3;
  idx3[base]=i0; idx3[base+1]=i1; idx3[base+2]=i2;
  w3[base]=r0/rs; w3[base+1]=r1/rs; w3[base+2]=r2/rs;
}

// ---- tiled transpose: src f32 [B][C][NN] -> dst bf16 [B][NN][C] ----
template<int C, int NN>
__global__ __launch_bounds__(256) void tpose_kernel(const float* __restrict__ src, u16t* __restrict__ dst){
  __shared__ float tile[64][65];
  const int n0 = blockIdx.x * 64;
  const int c0 = blockIdx.y * 64;
  const int b  = blockIdx.z;
  const int t  = threadIdx.x;
  #pragma unroll
  for (int i = 0; i < 16; ++i){
    int idx = t + i*256;
    int cc = idx >> 6, nn = idx & 63;
    tile[cc][nn] = src[((size_t)b*C + c0 + cc)*NN + n0 + nn];
  }
  __syncthreads();
  #pragma unroll
  for (int i = 0; i < 16; ++i){
    int idx = t + i*256;
    int nn = idx >> 6, cc = idx & 63;
    dst[((size_t)b*NN + n0 + nn)*C + c0 + cc] = f2b(tile[cc][nn]);
  }
}

// ---- weight convert f32 -> bf16 into WB ----
__global__ __launch_bounds__(256) void wcvt_kernel(const float* __restrict__ w1, const float* __restrict__ w2,
                                                   const float* __restrict__ wg, const float* __restrict__ wx,
                                                   u16t* __restrict__ wb){
  int i = blockIdx.x*256 + threadIdx.x;
  if (i >= WTOTAL) return;
  float v;
  if      (i < WOFF_C2) v = w1[i];
  else if (i < WOFF_WG) v = w2[i - WOFF_C2];
  else if (i < WOFF_WX) v = wg[i - WOFF_WG];
  else                  v = wx[i - WOFF_WX];
  wb[i] = f2b(v);
}

// ---- interp: half-wave (32 lanes) per point; coalesced 512B row reads/writes ----
__global__ __launch_bounds__(256) void interp_kernel(const u16t* __restrict__ p2t, const int* __restrict__ idx3,
                                                     const float* __restrict__ w3, u16t* __restrict__ it){
  const int t = threadIdx.x;
  const int pid = blockIdx.x*8 + (t >> 5);   // global point in [0, B*N)
  const int l = t & 31;                      // lane-in-half: channels l*8..l*8+8
  const int b = pid >> 14;                   // NPTS = 16384
  size_t pb = (size_t)pid*3;
  int i0 = idx3[pb], i1 = idx3[pb+1], i2 = idx3[pb+2];
  float w0 = w3[pb], w1 = w3[pb+1], w2 = w3[pb+2];
  const u16t* r0 = p2t + ((size_t)b*SPTS + i0)*256 + l*8;
  const u16t* r1 = p2t + ((size_t)b*SPTS + i1)*256 + l*8;
  const u16t* r2 = p2t + ((size_t)b*SPTS + i2)*256 + l*8;
  uint4 q0 = *reinterpret_cast<const uint4*>(r0);
  uint4 q1 = *reinterpret_cast<const uint4*>(r1);
  uint4 q2 = *reinterpret_cast<const uint4*>(r2);
  const u32t* a0 = reinterpret_cast<const u32t*>(&q0);
  const u32t* a1 = reinterpret_cast<const u32t*>(&q1);
  const u32t* a2 = reinterpret_cast<const u32t*>(&q2);
  u32t ow[4];
  #pragma unroll
  for (int j = 0; j < 4; ++j){
    u32t u0 = a0[j], u1 = a1[j], u2 = a2[j];
    float lo = fmaf(w2, b2f((u16t)u2), fmaf(w1, b2f((u16t)u1), w0*b2f((u16t)u0)));
    float hi = fmaf(w2, b2f((u16t)(u2>>16)), fmaf(w1, b2f((u16t)(u1>>16)), w0*b2f((u16t)(u0>>16))));
    ow[j] = (u32t)f2b(lo) | ((u32t)f2b(hi) << 16);
  }
  *reinterpret_cast<uint4*>(it + (size_t)pid*256 + l*8) = make_uint4(ow[0], ow[1], ow[2], ow[3]);
}

// ---- MFMA conv1x1, LDS-staged activations (global_load_lds w16, dbuf, XOR-swizzled) ----
// y[B][N][OUT] = W[OUT][CIN] . x[B][N][CIN] + bias (raw, pre-BN)
// LDS tile: [64 pts][64 ch] bf16 per chunk (128 B/row). Swizzle: 16B slot s stores
// global slot s^(row&7) (pre-swizzled source); ds_read applies the same XOR. (T2/G4, rule #21)
template<int CIN, int OUT, bool SPLIT>
__global__ __launch_bounds__(256, 1) void mfma_conv_kernel(const u16t* __restrict__ xa, const u16t* __restrict__ xb,
                                                           const u16t* __restrict__ W, const float* __restrict__ bias,
                                                           u16t* __restrict__ y, float* __restrict__ partial){
  constexpr int MW = OUT/4;      // per-wave M slice
  constexpr int MF = MW/16;      // m-fragments per wave
  constexpr int NC = CIN/64;     // 64-channel k-chunks
  __shared__ u16t sbuf[2][64*64];   // 16 KB double buffer
  const int bid = blockIdx.x;
  const int b = bid >> 8;
  const int n0 = (bid & 255) * 64;
  const int wv = threadIdx.x >> 6;
  const int lane = threadIdx.x & 63;
  const int lr = lane & 15;
  const int kg = lane >> 4;
  const int m0 = wv * MW;

  f32x4 acc[MF][4];
  #pragma unroll
  for (int mf = 0; mf < MF; ++mf)
    #pragma unroll
    for (int nf = 0; nf < 4; ++nf){ acc[mf][nf][0]=0.f; acc[mf][nf][1]=0.f; acc[mf][nf][2]=0.f; acc[mf][nf][3]=0.f; }

  const u16t* wrow[MF];
  #pragma unroll
  for (int mf = 0; mf < MF; ++mf)
    wrow[mf] = W + (size_t)(m0 + mf*16 + lr)*CIN + kg*8;

  const int prow0 = wv*16 + (lane>>3);                 // +8 for i=1 (row&7 unchanged)
  const int gslot = (lane & 7) ^ ((lane >> 3) & 7);    // pre-swizzled source slot
  int rdoff[2][4];
  #pragma unroll
  for (int ks = 0; ks < 2; ++ks)
    #pragma unroll
    for (int nf = 0; nf < 4; ++nf)
      rdoff[ks][nf] = (nf*16 + lr)*64 + (((ks*4 + kg) ^ (lr & 7)) << 3);

  auto stage = [&](int c, int buf){
    #pragma unroll
    for (int i = 0; i < 2; ++i){
      int p = prow0 + i*8;
      const u16t* g;
      if (SPLIT){
        if (c < 2) g = xa + ((size_t)b*NPTS + n0 + p)*128 + c*64     + gslot*8;
        else       g = xb + ((size_t)b*NPTS + n0 + p)*256 + (c-2)*64 + gslot*8;
      } else {
        g = xa + ((size_t)b*NPTS + n0 + p)*CIN + c*64 + gslot*8;
      }
      u16t* l = &sbuf[buf][(wv*16 + i*8)*64];   // wave-uniform base; HW adds lane*16B
      __builtin_amdgcn_global_load_lds(AS1(g), AS3(l), 16, 0, 0);
    }
  };

  stage(0, 0);
  __syncthreads();
  #pragma unroll
  for (int c = 0; c < NC; ++c){
    if (c + 1 < NC) stage(c+1, (c+1)&1);
    #pragma unroll
    for (int ks = 0; ks < 2; ++ks){
      const int k0 = c*2 + ks;
      s16x8 av[MF];
      #pragma unroll
      for (int mf = 0; mf < MF; ++mf)
        av[mf] = *reinterpret_cast<const s16x8*>(wrow[mf] + k0*32);
      s16x8 bv[4];
      #pragma unroll
      for (int nf = 0; nf < 4; ++nf)
        bv[nf] = *reinterpret_cast<const s16x8*>(&sbuf[c&1][rdoff[ks][nf]]);
      #pragma unroll
      for (int mf = 0; mf < MF; ++mf)
        #pragma unroll
        for (int nf = 0; nf < 4; ++nf)
          acc[mf][nf] = __builtin_amdgcn_mfma_f32_16x16x32_bf16(av[mf], bv[nf], acc[mf][nf], 0, 0, 0);
    }
    __syncthreads();   // drains stage(c+1) vmcnt + syncs readers of buf[c&1]
  }

  #pragma unroll
  for (int mf = 0; mf < MF; ++mf){
    int mb = m0 + mf*16 + kg*4;
    float4 bs = *reinterpret_cast<const float4*>(bias + mb);
    float s0=0.f,s1=0.f,s2=0.f,s3=0.f,q0=0.f,q1=0.f,q2=0.f,q3=0.f;
    #pragma unroll
    for (int nf = 0; nf < 4; ++nf){
      int n = n0 + nf*16 + lr;
      float v0 = acc[mf][nf][0] + bs.x;
      float v1 = acc[mf][nf][1] + bs.y;
      float v2 = acc[mf][nf][2] + bs.z;
      float v3 = acc[mf][nf][3] + bs.w;
      s0+=v0; q0+=v0*v0; s1+=v1; q1+=v1*v1;
      s2+=v2; q2+=v2*v2; s3+=v3; q3+=v3*v3;
      uint2 pv;
      pv.x = (u32t)f2b(v0) | ((u32t)f2b(v1) << 16);
      pv.y = (u32t)f2b(v2) | ((u32t)f2b(v3) << 16);
      *reinterpret_cast<uint2*>(y + ((size_t)b*NPTS + n)*OUT + mb) = pv;
    }
    #pragma unroll
    for (int o = 1; o < 16; o <<= 1){
      s0 += __shfl_xor(s0, o); s1 += __shfl_xor(s1, o);
      s2 += __shfl_xor(s2, o); s3 += __shfl_xor(s3, o);
      q0 += __shfl_xor(q0, o); q1 += __shfl_xor(q1, o);
      q2 += __shfl_xor(q2, o); q3 += __shfl_xor(q3, o);
    }
    if (lr == 0){
      float* pp = partial + (size_t)bid*(OUT*2) + mb*2;
      pp[0]=s0; pp[1]=q0; pp[2]=s1; pp[3]=q1;
      pp[4]=s2; pp[5]=q2; pp[6]=s3; pp[7]=q3;
    }
  }
}

// ---- reduce conv partials [1024][E] -> stats[E] (no atomics) ----
template<int E>
__global__ __launch_bounds__(256) void reduce_stats_kernel(const float* __restrict__ p, float* __restrict__ st){
  __shared__ float ls[8][32];
  const int t = threadIdx.x;
  const int kq = t >> 5, es = t & 31;
  const int e = blockIdx.x*32 + es;
  float s = 0.f;
  const float* pp = p + (size_t)kq*128*E + e;
  #pragma unroll 16
  for (int i = 0; i < 128; ++i) s += pp[(size_t)i*E];
  ls[kq][es] = s;
  __syncthreads();
  if (kq == 0){
    st[e] = ((ls[0][es]+ls[1][es])+(ls[2][es]+ls[3][es]))
          + ((ls[4][es]+ls[5][es])+(ls[6][es]+ls[7][es]));
  }
}

// ---- gate: psi_pre[p] = psi_w . lrelu(bn(yg)+bn(yx)) + psi_b, + psi stats ----
__global__ __launch_bounds__(256) void gate_kernel(const u16t* __restrict__ yg, const u16t* __restrict__ yx,
                                                   const float* __restrict__ stg, const float* __restrict__ stx,
                                                   const float* __restrict__ wg_bn_g, const float* __restrict__ wg_bn_b,
                                                   const float* __restrict__ wx_bn_g, const float* __restrict__ wx_bn_b,
                                                   const float* __restrict__ psi_w, const float* __restrict__ psi_b,
                                                   float* __restrict__ psipre, float* __restrict__ stpsi){
  __shared__ float lag[64], lbg[64], lax[64], lbx[64], lpw[64];
  __shared__ float red[8];
  const int t = threadIdx.x;
  if (t < 64){
    float m  = stg[t*2] * (1.0f/CNTF);
    float vv = fmaxf(stg[t*2+1]*(1.0f/CNTF) - m*m, 0.0f);
    float iv = 1.0f/sqrtf(vv + BNEPS);
    float gm = wg_bn_g[t];
    lag[t] = gm*iv; lbg[t] = wg_bn_b[t] - m*gm*iv;
    m  = stx[t*2] * (1.0f/CNTF);
    vv = fmaxf(stx[t*2+1]*(1.0f/CNTF) - m*m, 0.0f);
    iv = 1.0f/sqrtf(vv + BNEPS);
    gm = wx_bn_g[t];
    lax[t] = gm*iv; lbx[t] = wx_bn_b[t] - m*gm*iv;
    lpw[t] = psi_w[t];
  }
  __syncthreads();
  const int p = blockIdx.x*256 + t;
  const u16t* rg = yg + (size_t)p*64;
  const u16t* rx = yx + (size_t)p*64;
  float acc = psi_b[0];
  #pragma unroll
  for (int u = 0; u < 8; ++u){
    uint4 qg = *reinterpret_cast<const uint4*>(rg + u*8);
    uint4 qx = *reinterpret_cast<const uint4*>(rx + u*8);
    const u32t* g4 = reinterpret_cast<const u32t*>(&qg);
    const u32t* x4 = reinterpret_cast<const u32t*>(&qx);
    #pragma unroll
    for (int e = 0; e < 4; ++e){
      int j = u*8 + e*2;
      float gv0 = fmaf(b2f((u16t)g4[e]),        lag[j],   lbg[j]);
      float xv0 = fmaf(b2f((u16t)x4[e]),        lax[j],   lbx[j]);
      float gv1 = fmaf(b2f((u16t)(g4[e]>>16)),  lag[j+1], lbg[j+1]);
      float xv1 = fmaf(b2f((u16t)(x4[e]>>16)),  lax[j+1], lbx[j+1]);
      acc = fmaf(lpw[j],   lrelu(gv0 + xv0), acc);
      acc = fmaf(lpw[j+1], lrelu(gv1 + xv1), acc);
    }
  }
  psipre[p] = acc;
  float s = acc, q = acc*acc;
  #pragma unroll
  for (int o = 32; o; o >>= 1){ s += __shfl_xor(s, o); q += __shfl_xor(q, o); }
  if ((t & 63) == 0){ red[(t>>6)*2] = s; red[(t>>6)*2+1] = q; }
  __syncthreads();
  if (t == 0){
    atomicAdd(&stpsi[0], red[0]+red[2]+red[4]+red[6]);
    atomicAdd(&stpsi[1], red[1]+red[3]+red[5]+red[7]);
  }
}

// ---- psi = sigmoid(bn(psi_pre)); scale p1t rows in place ----
__global__ __launch_bounds__(256) void scale_p1_kernel(u16t* __restrict__ p1t, const float* __restrict__ psipre,
                                                       const float* __restrict__ stpsi,
                                                       const float* __restrict__ psi_bn_g, const float* __restrict__ psi_bn_b){
  const int p = blockIdx.x*256 + threadIdx.x;
  float m  = stpsi[0]*(1.0f/CNTF);
  float vv = fmaxf(stpsi[1]*(1.0f/CNTF) - m*m, 0.0f);
  float iv = 1.0f/sqrtf(vv + BNEPS);
  float ap = psi_bn_g[0]*iv;
  float bp = psi_bn_b[0] - m*ap;
  float z  = fmaf(psipre[p], ap, bp);
  float psi = 1.0f/(1.0f + expf(-z));
  u16t* r = p1t + (size_t)p*128;
  #pragma unroll
  for (int u = 0; u < 16; ++u){
    uint4 q = *reinterpret_cast<uint4*>(r + u*8);
    u32t* a = reinterpret_cast<u32t*>(&q);
    #pragma unroll
    for (int j = 0; j < 4; ++j){
      float lo = b2f((u16t)a[j]) * psi;
      float hi = b2f((u16t)(a[j]>>16)) * psi;
      a[j] = (u32t)f2b(lo) | ((u32t)f2b(hi) << 16);
    }
    *reinterpret_cast<uint4*>(r + u*8) = q;
  }
}

// ---- bn1 + lrelu in place on h1 [P][256] bf16 ----
__global__ __launch_bounds__(256) void bnrelu256_kernel(u16t* __restrict__ x, const float* __restrict__ st,
                                                        const float* __restrict__ g, const float* __restrict__ bb){
  __shared__ float sa[256], sc[256];
  const int t = threadIdx.x;
  {
    float m  = st[t*2]*(1.0f/CNTF);
    float vv = fmaxf(st[t*2+1]*(1.0f/CNTF) - m*m, 0.0f);
    float iv = 1.0f/sqrtf(vv + BNEPS);
    float gm = g[t];
    sa[t] = gm*iv; sc[t] = bb[t] - m*gm*iv;
  }
  __syncthreads();
  size_t e4 = ((size_t)blockIdx.x*256 + t)*4;
  int c0 = (int)(e4 & 255);
  uint2 v = *reinterpret_cast<uint2*>(x + e4);
  float f0 = lrelu(fmaf(b2f((u16t)v.x),        sa[c0],   sc[c0]));
  float f1 = lrelu(fmaf(b2f((u16t)(v.x>>16)),  sa[c0+1], sc[c0+1]));
  float f2 = lrelu(fmaf(b2f((u16t)v.y),        sa[c0+2], sc[c0+2]));
  float f3 = lrelu(fmaf(b2f((u16t)(v.y>>16)),  sa[c0+3], sc[c0+3]));
  v.x = (u32t)f2b(f0) | ((u32t)f2b(f1) << 16);
  v.y = (u32t)f2b(f2) | ((u32t)f2b(f3) << 16);
  *reinterpret_cast<uint2*>(x + e4) = v;
}

// ---- final: out[b][m][n] f32 = lrelu(bn2(h2[b][n][m])) via LDS tile transpose ----
__global__ __launch_bounds__(256) void final_kernel(const u16t* __restrict__ h2, const float* __restrict__ st,
                                                    const float* __restrict__ g, const float* __restrict__ bb,
                                                    float* __restrict__ out){
  __shared__ float am[128], cm[128];
  __shared__ float tile[64][129];
  const int t = threadIdx.x;
  if (t < 128){
    float m  = st[t*2]*(1.0f/CNTF);
    float vv = fmaxf(st[t*2+1]*(1.0f/CNTF) - m*m, 0.0f);
    float iv = 1.0f/sqrtf(vv + BNEPS);
    float gm = g[t];
    am[t] = gm*iv; cm[t] = bb[t] - m*gm*iv;
  }
  __syncthreads();
  const int n0 = blockIdx.x * 64;
  const int b  = blockIdx.y;
  #pragma unroll
  for (int i = 0; i < 32; ++i){
    int idx = t + i*256;
    int mm = idx & 127, nn = idx >> 7;
    float v = fmaf(b2f(h2[((size_t)b*NPTS + n0 + nn)*128 + mm]), am[mm], cm[mm]);
    tile[nn][mm] = lrelu(v);
  }
  __syncthreads();
  #pragma unroll
  for (int i = 0; i < 32; ++i){
    int idx = t + i*256;
    int nn = idx & 63, mm = idx >> 6;
    out[((size_t)(b*128 + mm))*NPTS + n0 + nn] = tile[nn][mm];
  }
}

extern "C" void kernel_launch(void* const* d_in, const int* in_sizes, int n_in,
                              void* d_out, int out_size, void* d_ws, size_t ws_size,
                              hipStream_t stream){
  const float* xyz1    = (const float*)d_in[0];
  const float* xyz2    = (const float*)d_in[1];
  const float* points1 = (const float*)d_in[2];
  const float* points2 = (const float*)d_in[3];
  const float* conv1_w = (const float*)d_in[4];
  const float* conv1_b = (const float*)d_in[5];
  const float* bn1_g   = (const float*)d_in[6];
  const float* bn1_b   = (const float*)d_in[7];
  const float* conv2_w = (const float*)d_in[8];
  const float* conv2_b = (const float*)d_in[9];
  const float* bn2_g   = (const float*)d_in[10];
  const float* bn2_b   = (const float*)d_in[11];
  const float* wg_w    = (const float*)d_in[12];
  const float* wg_b    = (const float*)d_in[13];
  const float* wg_bn_g = (const float*)d_in[14];
  const float* wg_bn_b = (const float*)d_in[15];
  const float* wx_w    = (const float*)d_in[16];
  const float* wx_b    = (const float*)d_in[17];
  const float* wx_bn_g = (const float*)d_in[18];
  const float* wx_bn_b = (const float*)d_in[19];
  const float* psi_w   = (const float*)d_in[20];
  const float* psi_b   = (const float*)d_in[21];
  const float* psi_bn_g= (const float*)d_in[22];
  const float* psi_bn_b= (const float*)d_in[23];

  char* ws = (char*)d_ws;
  float* stats  = (float*)(ws + O_STATS);
  u16t*  wb     = (u16t*)(ws + O_WB);
  float* psipre = (float*)(ws + O_PSIPRE);
  u16t*  p2t    = (u16t*)(ws + O_P2T);
  float* part   = (float*)(ws + O_PART);
  u16t*  p1t    = (u16t*)(ws + O_P1T);
  u16t*  itp    = (u16t*)(ws + O_INT);
  u16t*  h1t    = (u16t*)(ws + O_H1);
  float* pd     = (float*)(ws + O_PD);
  int*   pi     = (int*)(ws + O_PI);
  int*   idx3   = (int*)(ws + O_IDX3);
  float* w3     = (float*)(ws + O_W3);
  u16t*  ygt    = (u16t*)(ws + O_YG);
  u16t*  yxt    = (u16t*)(ws + O_YX);
  u16t*  h2t    = (u16t*)(ws + O_H2);

  hipMemsetAsync(ws + O_STATS, 0, 8192, stream);

  knn_part_kernel<<<dim3(NPTS/256, NCH, Bq), 256, 0, stream>>>(xyz1, xyz2, pd, pi);
  knn_merge_kernel<<<(Bq*NPTS)/256, 256, 0, stream>>>(pd, pi, idx3, w3);
  tpose_kernel<256, SPTS><<<dim3(SPTS/64, 4, Bq), 256, 0, stream>>>(points2, p2t);
  interp_kernel<<<(Bq*NPTS)/8, 256, 0, stream>>>(p2t, idx3, w3, itp);
  tpose_kernel<128, NPTS><<<dim3(NPTS/64, 2, Bq), 256, 0, stream>>>(points1, p1t);
  wcvt_kernel<<<(WTOTAL+255)/256, 256, 0, stream>>>(conv1_w, conv2_w, wg_w, wx_w, wb);

  mfma_conv_kernel<256, 64, false><<<Bq*(NPTS/64), 256, 0, stream>>>(itp, nullptr, wb+WOFF_WG, wg_b, ygt, part);
  reduce_stats_kernel<128><<<4, 256, 0, stream>>>(part, stats+ST_WG);
  mfma_conv_kernel<128, 64, false><<<Bq*(NPTS/64), 256, 0, stream>>>(p1t, nullptr, wb+WOFF_WX, wx_b, yxt, part);
  reduce_stats_kernel<128><<<4, 256, 0, stream>>>(part, stats+ST_WX);
  gate_kernel<<<256, 256, 0, stream>>>(ygt, yxt, stats+ST_WG, stats+ST_WX,
                                       wg_bn_g, wg_bn_b, wx_bn_g, wx_bn_b,
                                       psi_w, psi_b, psipre, stats+ST_PSI);
  scale_p1_kernel<<<256, 256, 0, stream>>>(p1t, psipre, stats+ST_PSI, psi_bn_g, psi_bn_b);

  mfma_conv_kernel<384, 256, true><<<Bq*(NPTS/64), 256, 0, stream>>>(p1t, itp, wb+WOFF_C1, conv1_b, h1t, part);
  reduce_stats_kernel<512><<<16, 256, 0, stream>>>(part, stats+ST_BN1);
  bnrelu256_kernel<<<16384, 256, 0, stream>>>(h1t, stats+ST_BN1, bn1_g, bn1_b);

  mfma_conv_kernel<256, 128, false><<<Bq*(NPTS/64), 256, 0, stream>>>(h1t, nullptr, wb+WOFF_C2, conv2_b, h2t, part);
  reduce_stats_kernel<256><<<8, 256, 0, stream>>>(part, stats+ST_BN2);
  final_kernel<<<dim3(NPTS/64, Bq), 256, 0, stream>>>(h2t, stats+ST_BN2, bn2_g, bn2_b, (float*)d_out);
}

// Round 11
// 226.338 us; speedup vs baseline: 4.8786x; 1.0648x over previous
//
#include <hip/hip_runtime.h>
#include <hip/hip_bf16.h>

#define Bq    4
#define NPTS  16384
#define SPTS  2048
#define NCH   8
#define SCH   (SPTS/NCH)   // 256
#define CNTF  65536.0f
#define BNEPS 1e-5f

typedef unsigned short u16t;
typedef unsigned int   u32t;
typedef __attribute__((ext_vector_type(8))) short s16x8;
typedef __attribute__((ext_vector_type(4))) float f32x4;

#define AS1(p) ((const __attribute__((address_space(1))) void*)(p))
#define AS3(p) ((__attribute__((address_space(3))) void*)(p))

__device__ __forceinline__ float b2f(u16t u){
  union { u32t i; float f; } v; v.i = ((u32t)u) << 16; return v.f;
}
__device__ __forceinline__ u16t f2b(float f){
  __hip_bfloat16 h = __float2bfloat16(f);
  return *reinterpret_cast<u16t*>(&h);
}
__device__ __forceinline__ float lrelu(float x){ return x >= 0.0f ? x : 0.2f*x; }

// ---- stats f32 offsets: per-channel [sum,sumsq] pairs ----
#define ST_WG  0
#define ST_WX  128
#define ST_PSI 256
#define ST_BN1 272
#define ST_BN2 784

// ---- bf16 weight element offsets inside WB region ----
#define WOFF_C1 0
#define WOFF_C2 98304
#define WOFF_WG 131072
#define WOFF_WX 147456
#define WTOTAL  155648

// ---- ws byte offsets (time-disjoint aliasing; total ~84.6 MB) ----
#define O_STATS  0u
#define O_WB     8192u
#define O_PSIPRE 319488u        // 262144 B; first 128 KB doubles as packed-xyz2 sp (dead before gate writes psipre)
#define O_SP     O_PSIPRE
#define O_P2T    581632u        // 4 MB bf16 [B][S][256]; dead after interp
#define O_PART   O_P2T          // conv stats partials [1024][<=512] f32 = 2 MB, used after interp
#define O_P1T    4775936u       // 16.7 MB bf16 [B][N][128] (read-only now; psi folded into conv1)
#define O_INT    21553152u      // 33.5 MB bf16 [B][N][256] interp; h2t aliases later
#define O_H1     55107584u      // 33.5 MB bf16 [B][N][256] h1; bnrelu IN PLACE
// knn scratch lives inside the (not-yet-written) H1 region:
#define O_PD     O_H1                    // 6.29 MB f32 partial dists [B][N][NCH][3]
#define O_PI     (O_H1 + 6291456u)       // 6.29 MB i32 partial idx
#define O_IDX3   (O_H1 + 12582912u)      // 786 KB
#define O_W3     (O_H1 + 13369344u)      // 786 KB (all dead before ygt written)
#define O_YG     O_H1                    // ygt/yxt live steps 5-8, dead before h1 written
#define O_YX     (O_H1 + 8388608u)
#define O_H2     O_INT                   // h2 bf16, written after interp dead
// end = 55107584 + 33554432 = 88662016 B

// ---- pack xyz2 -> sp[B][S] = (x,y,z,|s|^2) for wave-uniform scalar loads ----
__global__ __launch_bounds__(256) void knn_prep_kernel(const float* __restrict__ xyz2, float4* __restrict__ sp){
  int i = blockIdx.x*256 + threadIdx.x;   // [0, B*S)
  int b = i >> 11, s = i & (SPTS-1);
  float x = xyz2[(b*3+0)*SPTS+s];
  float y = xyz2[(b*3+1)*SPTS+s];
  float z = xyz2[(b*3+2)*SPTS+s];
  sp[i] = make_float4(x, y, z, x*x+y*y+z*z);
}

// ---- 3-NN part 1: per-chunk top-3; branchless sorted-triple insert, scalar candidate loads ----
__global__ __launch_bounds__(256) void knn_part_kernel(const float* __restrict__ xyz1, const float4* __restrict__ sp,
                                                       float* __restrict__ pd, int* __restrict__ pi){
  const int b = blockIdx.z;
  const int c = blockIdx.y;
  const int n = blockIdx.x*256 + threadIdx.x;
  const float4* cp = sp + (size_t)b*SPTS + c*SCH;   // wave-uniform base
  float px = xyz1[(b*3+0)*NPTS+n];
  float py = xyz1[(b*3+1)*NPTS+n];
  float pz = xyz1[(b*3+2)*NPTS+n];
  float s1 = px*px+py*py+pz*pz;
  float d0=3.4e38f, d1=3.4e38f, d2=3.4e38f;
  int   i0=0, i1=0, i2=0;
  const int cbase = c*SCH;
  #pragma unroll 8
  for (int s=0; s<SCH; ++s){
    float4 q = cp[s];                               // uniform addr -> s_load (scalar pipe)
    float dot = fmaf(pz, q.z, fmaf(py, q.y, px*q.x));
    float key = (s1 + q.w) - 2.0f*dot;              // bitwise == reference (2*dot exact)
    int gi = cbase + s;
    // branchless insert into sorted (d0<=d1<=d2); exact equiv of strict-< chain
    bool c0 = key < d0, c1 = key < d1, c2 = key < d2;
    int ni2 = c1 ? i1 : (c2 ? gi : i2);
    int ni1 = c0 ? i0 : (c1 ? gi : i1);
    i0 = c0 ? gi : i0;
    float nd2 = fminf(d2, fmaxf(d1, key));
    d1 = __builtin_amdgcn_fmed3f(d0, d1, key);
    d0 = fminf(d0, key);
    d2 = nd2; i1 = ni1; i2 = ni2;
  }
  size_t base = (((size_t)b*NPTS + n)*NCH + c)*3;
  pd[base]=d0; pd[base+1]=d1; pd[base+2]=d2;
  pi[base]=i0; pi[base+1]=i1; pi[base+2]=i2;
}

// ---- 3-NN part 2: merge NCH partial top-3 lists (chunk-order => stable ties) ----
__global__ __launch_bounds__(256) void knn_merge_kernel(const float* __restrict__ pd, const int* __restrict__ pi,
                                                        int* __restrict__ idx3, float* __restrict__ w3){
  const int p = blockIdx.x*256 + threadIdx.x;   // [0, B*N)
  const float* dp = pd + (size_t)p*NCH*3;
  const int*   ip = pi + (size_t)p*NCH*3;
  float d0=3.4e38f, d1=3.4e38f, d2=3.4e38f;
  int   i0=0, i1=0, i2=0;
  #pragma unroll
  for (int k=0; k<NCH*3; ++k){
    float key = dp[k]; int gi = ip[k];
    bool c0 = key < d0, c1 = key < d1, c2 = key < d2;
    int ni2 = c1 ? i1 : (c2 ? gi : i2);
    int ni1 = c0 ? i0 : (c1 ? gi : i1);
    i0 = c0 ? gi : i0;
    float nd2 = fminf(d2, fmaxf(d1, key));
    d1 = __builtin_amdgcn_fmed3f(d0, d1, key);
    d0 = fminf(d0, key);
    d2 = nd2; i1 = ni1; i2 = ni2;
  }
  float r0=1.0f/(d0+1e-8f), r1=1.0f/(d1+1e-8f), r2=1.0f/(d2+1e-8f);
  float rs = r0+r1+r2;
  size_t base = (size_t)p*3;
  idx3[base]=i0; idx3[base+1]=i1; idx3[base+2]=i2;
  w3[base]=r0/rs; w3[base+1]=r1/rs; w3[base+2]=r2/rs;
}

// ---- tiled transpose: src f32 [B][C][NN] -> dst bf16 [B][NN][C] ----
template<int C, int NN>
__global__ __launch_bounds__(256) void tpose_kernel(const float* __restrict__ src, u16t* __restrict__ dst){
  __shared__ float tile[64][65];
  const int n0 = blockIdx.x * 64;
  const int c0 = blockIdx.y * 64;
  const int b  = blockIdx.z;
  const int t  = threadIdx.x;
  #pragma unroll
  for (int i = 0; i < 16; ++i){
    int idx = t + i*256;
    int cc = idx >> 6, nn = idx & 63;
    tile[cc][nn] = src[((size_t)b*C + c0 + cc)*NN + n0 + nn];
  }
  __syncthreads();
  #pragma unroll
  for (int i = 0; i < 16; ++i){
    int idx = t + i*256;
    int nn = idx >> 6, cc = idx & 63;
    dst[((size_t)b*NN + n0 + nn)*C + c0 + cc] = f2b(tile[cc][nn]);
  }
}

// ---- weight convert f32 -> bf16 into WB ----
__global__ __launch_bounds__(256) void wcvt_kernel(const float* __restrict__ w1, const float* __restrict__ w2,
                                                   const float* __restrict__ wg, const float* __restrict__ wx,
                                                   u16t* __restrict__ wb){
  int i = blockIdx.x*256 + threadIdx.x;
  if (i >= WTOTAL) return;
  float v;
  if      (i < WOFF_C2) v = w1[i];
  else if (i < WOFF_WG) v = w2[i - WOFF_C2];
  else if (i < WOFF_WX) v = wg[i - WOFF_WG];
  else                  v = wx[i - WOFF_WX];
  wb[i] = f2b(v);
}

// ---- interp: half-wave (32 lanes) per point; coalesced 512B row reads/writes ----
__global__ __launch_bounds__(256) void interp_kernel(const u16t* __restrict__ p2t, const int* __restrict__ idx3,
                                                     const float* __restrict__ w3, u16t* __restrict__ it){
  const int t = threadIdx.x;
  const int pid = blockIdx.x*8 + (t >> 5);   // global point in [0, B*N)
  const int l = t & 31;                      // lane-in-half: channels l*8..l*8+8
  const int b = pid >> 14;                   // NPTS = 16384
  size_t pb = (size_t)pid*3;
  int i0 = idx3[pb], i1 = idx3[pb+1], i2 = idx3[pb+2];
  float w0 = w3[pb], w1 = w3[pb+1], w2 = w3[pb+2];
  const u16t* r0 = p2t + ((size_t)b*SPTS + i0)*256 + l*8;
  const u16t* r1 = p2t + ((size_t)b*SPTS + i1)*256 + l*8;
  const u16t* r2 = p2t + ((size_t)b*SPTS + i2)*256 + l*8;
  uint4 q0 = *reinterpret_cast<const uint4*>(r0);
  uint4 q1 = *reinterpret_cast<const uint4*>(r1);
  uint4 q2 = *reinterpret_cast<const uint4*>(r2);
  const u32t* a0 = reinterpret_cast<const u32t*>(&q0);
  const u32t* a1 = reinterpret_cast<const u32t*>(&q1);
  const u32t* a2 = reinterpret_cast<const u32t*>(&q2);
  u32t ow[4];
  #pragma unroll
  for (int j = 0; j < 4; ++j){
    u32t u0 = a0[j], u1 = a1[j], u2 = a2[j];
    float lo = fmaf(w2, b2f((u16t)u2), fmaf(w1, b2f((u16t)u1), w0*b2f((u16t)u0)));
    float hi = fmaf(w2, b2f((u16t)(u2>>16)), fmaf(w1, b2f((u16t)(u1>>16)), w0*b2f((u16t)(u0>>16))));
    ow[j] = (u32t)f2b(lo) | ((u32t)f2b(hi) << 16);
  }
  *reinterpret_cast<uint4*>(it + (size_t)pid*256 + l*8) = make_uint4(ow[0], ow[1], ow[2], ow[3]);
}

// ---- MFMA conv1x1, LDS-staged activations (global_load_lds w16, dbuf, XOR-swizzled) ----
// y[B][N][OUT] = W[OUT][CIN] . x[B][N][CIN] + bias (raw, pre-BN)
// SPLIT (conv1): x = [p1*psi ; interp] with psi folded into the accumulator after the
// p1 k-chunks: acc = psi[n]*(W1.p1) + W2.interp  (exact linear identity).
template<int CIN, int OUT, bool SPLIT>
__global__ __launch_bounds__(256, 1) void mfma_conv_kernel(const u16t* __restrict__ xa, const u16t* __restrict__ xb,
                                                           const u16t* __restrict__ W, const float* __restrict__ bias,
                                                           u16t* __restrict__ y, float* __restrict__ partial,
                                                           const float* __restrict__ psipre, const float* __restrict__ stpsi,
                                                           const float* __restrict__ pbn_g, const float* __restrict__ pbn_b){
  constexpr int MW = OUT/4;      // per-wave M slice
  constexpr int MF = MW/16;      // m-fragments per wave
  constexpr int NC = CIN/64;     // 64-channel k-chunks
  __shared__ u16t sbuf[2][64*64];   // 16 KB double buffer
  const int bid = blockIdx.x;
  const int b = bid >> 8;
  const int n0 = (bid & 255) * 64;
  const int wv = threadIdx.x >> 6;
  const int lane = threadIdx.x & 63;
  const int lr = lane & 15;
  const int kg = lane >> 4;
  const int m0 = wv * MW;

  float psiv[4];
  if (SPLIT){
    float m  = stpsi[0]*(1.0f/CNTF);
    float vv = fmaxf(stpsi[1]*(1.0f/CNTF) - m*m, 0.0f);
    float iv = 1.0f/sqrtf(vv + BNEPS);
    float ap = pbn_g[0]*iv;
    float bp = pbn_b[0] - m*ap;
    #pragma unroll
    for (int nf = 0; nf < 4; ++nf){
      float z = fmaf(psipre[b*NPTS + n0 + nf*16 + lr], ap, bp);
      psiv[nf] = 1.0f/(1.0f + expf(-z));
    }
  }

  f32x4 acc[MF][4];
  #pragma unroll
  for (int mf = 0; mf < MF; ++mf)
    #pragma unroll
    for (int nf = 0; nf < 4; ++nf){ acc[mf][nf][0]=0.f; acc[mf][nf][1]=0.f; acc[mf][nf][2]=0.f; acc[mf][nf][3]=0.f; }

  const u16t* wrow[MF];
  #pragma unroll
  for (int mf = 0; mf < MF; ++mf)
    wrow[mf] = W + (size_t)(m0 + mf*16 + lr)*CIN + kg*8;

  const int prow0 = wv*16 + (lane>>3);                 // +8 for i=1 (row&7 unchanged)
  const int gslot = (lane & 7) ^ ((lane >> 3) & 7);    // pre-swizzled source slot
  int rdoff[2][4];
  #pragma unroll
  for (int ks = 0; ks < 2; ++ks)
    #pragma unroll
    for (int nf = 0; nf < 4; ++nf)
      rdoff[ks][nf] = (nf*16 + lr)*64 + (((ks*4 + kg) ^ (lr & 7)) << 3);

  auto stage = [&](int c, int buf){
    #pragma unroll
    for (int i = 0; i < 2; ++i){
      int p = prow0 + i*8;
      const u16t* g;
      if (SPLIT){
        if (c < 2) g = xa + ((size_t)b*NPTS + n0 + p)*128 + c*64     + gslot*8;
        else       g = xb + ((size_t)b*NPTS + n0 + p)*256 + (c-2)*64 + gslot*8;
      } else {
        g = xa + ((size_t)b*NPTS + n0 + p)*CIN + c*64 + gslot*8;
      }
      u16t* l = &sbuf[buf][(wv*16 + i*8)*64];   // wave-uniform base; HW adds lane*16B
      __builtin_amdgcn_global_load_lds(AS1(g), AS3(l), 16, 0, 0);
    }
  };

  stage(0, 0);
  __syncthreads();
  #pragma unroll
  for (int c = 0; c < NC; ++c){
    if (c + 1 < NC) stage(c+1, (c+1)&1);
    #pragma unroll
    for (int ks = 0; ks < 2; ++ks){
      const int k0 = c*2 + ks;
      s16x8 av[MF];
      #pragma unroll
      for (int mf = 0; mf < MF; ++mf)
        av[mf] = *reinterpret_cast<const s16x8*>(wrow[mf] + k0*32);
      s16x8 bv[4];
      #pragma unroll
      for (int nf = 0; nf < 4; ++nf)
        bv[nf] = *reinterpret_cast<const s16x8*>(&sbuf[c&1][rdoff[ks][nf]]);
      #pragma unroll
      for (int mf = 0; mf < MF; ++mf)
        #pragma unroll
        for (int nf = 0; nf < 4; ++nf)
          acc[mf][nf] = __builtin_amdgcn_mfma_f32_16x16x32_bf16(av[mf], bv[nf], acc[mf][nf], 0, 0, 0);
    }
    if (SPLIT && c == 1){
      // p1 k-chunks (0..127) done: scale partial acc by per-column psi
      #pragma unroll
      for (int mf = 0; mf < MF; ++mf)
        #pragma unroll
        for (int nf = 0; nf < 4; ++nf){
          acc[mf][nf][0] *= psiv[nf]; acc[mf][nf][1] *= psiv[nf];
          acc[mf][nf][2] *= psiv[nf]; acc[mf][nf][3] *= psiv[nf];
        }
    }
    __syncthreads();   // drains stage(c+1) vmcnt + syncs readers of buf[c&1]
  }

  #pragma unroll
  for (int mf = 0; mf < MF; ++mf){
    int mb = m0 + mf*16 + kg*4;
    float4 bs = *reinterpret_cast<const float4*>(bias + mb);
    float s0=0.f,s1=0.f,s2=0.f,s3=0.f,q0=0.f,q1=0.f,q2=0.f,q3=0.f;
    #pragma unroll
    for (int nf = 0; nf < 4; ++nf){
      int n = n0 + nf*16 + lr;
      float v0 = acc[mf][nf][0] + bs.x;
      float v1 = acc[mf][nf][1] + bs.y;
      float v2 = acc[mf][nf][2] + bs.z;
      float v3 = acc[mf][nf][3] + bs.w;
      s0+=v0; q0+=v0*v0; s1+=v1; q1+=v1*v1;
      s2+=v2; q2+=v2*v2; s3+=v3; q3+=v3*v3;
      uint2 pv;
      pv.x = (u32t)f2b(v0) | ((u32t)f2b(v1) << 16);
      pv.y = (u32t)f2b(v2) | ((u32t)f2b(v3) << 16);
      *reinterpret_cast<uint2*>(y + ((size_t)b*NPTS + n)*OUT + mb) = pv;
    }
    #pragma unroll
    for (int o = 1; o < 16; o <<= 1){
      s0 += __shfl_xor(s0, o); s1 += __shfl_xor(s1, o);
      s2 += __shfl_xor(s2, o); s3 += __shfl_xor(s3, o);
      q0 += __shfl_xor(q0, o); q1 += __shfl_xor(q1, o);
      q2 += __shfl_xor(q2, o); q3 += __shfl_xor(q3, o);
    }
    if (lr == 0){
      float* pp = partial + (size_t)bid*(OUT*2) + mb*2;
      pp[0]=s0; pp[1]=q0; pp[2]=s1; pp[3]=q1;
      pp[4]=s2; pp[5]=q2; pp[6]=s3; pp[7]=q3;
    }
  }
}

// ---- reduce conv partials [1024][E] -> stats[E] (no atomics) ----
template<int E>
__global__ __launch_bounds__(256) void reduce_stats_kernel(const float* __restrict__ p, float* __restrict__ st){
  __shared__ float ls[8][32];
  const int t = threadIdx.x;
  const int kq = t >> 5, es = t & 31;
  const int e = blockIdx.x*32 + es;
  float s = 0.f;
  const float* pp = p + (size_t)kq*128*E + e;
  #pragma unroll 16
  for (int i = 0; i < 128; ++i) s += pp[(size_t)i*E];
  ls[kq][es] = s;
  __syncthreads();
  if (kq == 0){
    st[e] = ((ls[0][es]+ls[1][es])+(ls[2][es]+ls[3][es]))
          + ((ls[4][es]+ls[5][es])+(ls[6][es]+ls[7][es]));
  }
}

// ---- gate: psi_pre[p] = psi_w . lrelu(bn(yg)+bn(yx)) + psi_b, + psi stats ----
__global__ __launch_bounds__(256) void gate_kernel(const u16t* __restrict__ yg, const u16t* __restrict__ yx,
                                                   const float* __restrict__ stg, const float* __restrict__ stx,
                                                   const float* __restrict__ wg_bn_g, const float* __restrict__ wg_bn_b,
                                                   const float* __restrict__ wx_bn_g, const float* __restrict__ wx_bn_b,
                                                   const float* __restrict__ psi_w, const float* __restrict__ psi_b,
                                                   float* __restrict__ psipre, float* __restrict__ stpsi){
  __shared__ float lag[64], lbg[64], lax[64], lbx[64], lpw[64];
  __shared__ float red[8];
  const int t = threadIdx.x;
  if (t < 64){
    float m  = stg[t*2] * (1.0f/CNTF);
    float vv = fmaxf(stg[t*2+1]*(1.0f/CNTF) - m*m, 0.0f);
    float iv = 1.0f/sqrtf(vv + BNEPS);
    float gm = wg_bn_g[t];
    lag[t] = gm*iv; lbg[t] = wg_bn_b[t] - m*gm*iv;
    m  = stx[t*2] * (1.0f/CNTF);
    vv = fmaxf(stx[t*2+1]*(1.0f/CNTF) - m*m, 0.0f);
    iv = 1.0f/sqrtf(vv + BNEPS);
    gm = wx_bn_g[t];
    lax[t] = gm*iv; lbx[t] = wx_bn_b[t] - m*gm*iv;
    lpw[t] = psi_w[t];
  }
  __syncthreads();
  const int p = blockIdx.x*256 + t;
  const u16t* rg = yg + (size_t)p*64;
  const u16t* rx = yx + (size_t)p*64;
  float acc = psi_b[0];
  #pragma unroll
  for (int u = 0; u < 8; ++u){
    uint4 qg = *reinterpret_cast<const uint4*>(rg + u*8);
    uint4 qx = *reinterpret_cast<const uint4*>(rx + u*8);
    const u32t* g4 = reinterpret_cast<const u32t*>(&qg);
    const u32t* x4 = reinterpret_cast<const u32t*>(&qx);
    #pragma unroll
    for (int e = 0; e < 4; ++e){
      int j = u*8 + e*2;
      float gv0 = fmaf(b2f((u16t)g4[e]),        lag[j],   lbg[j]);
      float xv0 = fmaf(b2f((u16t)x4[e]),        lax[j],   lbx[j]);
      float gv1 = fmaf(b2f((u16t)(g4[e]>>16)),  lag[j+1], lbg[j+1]);
      float xv1 = fmaf(b2f((u16t)(x4[e]>>16)),  lax[j+1], lbx[j+1]);
      acc = fmaf(lpw[j],   lrelu(gv0 + xv0), acc);
      acc = fmaf(lpw[j+1], lrelu(gv1 + xv1), acc);
    }
  }
  psipre[p] = acc;
  float s = acc, q = acc*acc;
  #pragma unroll
  for (int o = 32; o; o >>= 1){ s += __shfl_xor(s, o); q += __shfl_xor(q, o); }
  if ((t & 63) == 0){ red[(t>>6)*2] = s; red[(t>>6)*2+1] = q; }
  __syncthreads();
  if (t == 0){
    atomicAdd(&stpsi[0], red[0]+red[2]+red[4]+red[6]);
    atomicAdd(&stpsi[1], red[1]+red[3]+red[5]+red[7]);
  }
}

// ---- bn1 + lrelu in place on h1 [P][256] bf16 ----
__global__ __launch_bounds__(256) void bnrelu256_kernel(u16t* __restrict__ x, const float* __restrict__ st,
                                                        const float* __restrict__ g, const float* __restrict__ bb){
  __shared__ float sa[256], sc[256];
  const int t = threadIdx.x;
  {
    float m  = st[t*2]*(1.0f/CNTF);
    float vv = fmaxf(st[t*2+1]*(1.0f/CNTF) - m*m, 0.0f);
    float iv = 1.0f/sqrtf(vv + BNEPS);
    float gm = g[t];
    sa[t] = gm*iv; sc[t] = bb[t] - m*gm*iv;
  }
  __syncthreads();
  size_t e4 = ((size_t)blockIdx.x*256 + t)*4;
  int c0 = (int)(e4 & 255);
  uint2 v = *reinterpret_cast<uint2*>(x + e4);
  float f0 = lrelu(fmaf(b2f((u16t)v.x),        sa[c0],   sc[c0]));
  float f1 = lrelu(fmaf(b2f((u16t)(v.x>>16)),  sa[c0+1], sc[c0+1]));
  float f2 = lrelu(fmaf(b2f((u16t)v.y),        sa[c0+2], sc[c0+2]));
  float f3 = lrelu(fmaf(b2f((u16t)(v.y>>16)),  sa[c0+3], sc[c0+3]));
  v.x = (u32t)f2b(f0) | ((u32t)f2b(f1) << 16);
  v.y = (u32t)f2b(f2) | ((u32t)f2b(f3) << 16);
  *reinterpret_cast<uint2*>(x + e4) = v;
}

// ---- final: out[b][m][n] f32 = lrelu(bn2(h2[b][n][m])) via LDS tile transpose ----
__global__ __launch_bounds__(256) void final_kernel(const u16t* __restrict__ h2, const float* __restrict__ st,
                                                    const float* __restrict__ g, const float* __restrict__ bb,
                                                    float* __restrict__ out){
  __shared__ float am[128], cm[128];
  __shared__ float tile[64][129];
  const int t = threadIdx.x;
  if (t < 128){
    float m  = st[t*2]*(1.0f/CNTF);
    float vv = fmaxf(st[t*2+1]*(1.0f/CNTF) - m*m, 0.0f);
    float iv = 1.0f/sqrtf(vv + BNEPS);
    float gm = g[t];
    am[t] = gm*iv; cm[t] = bb[t] - m*gm*iv;
  }
  __syncthreads();
  const int n0 = blockIdx.x * 64;
  const int b  = blockIdx.y;
  #pragma unroll
  for (int i = 0; i < 32; ++i){
    int idx = t + i*256;
    int mm = idx & 127, nn = idx >> 7;
    float v = fmaf(b2f(h2[((size_t)b*NPTS + n0 + nn)*128 + mm]), am[mm], cm[mm]);
    tile[nn][mm] = lrelu(v);
  }
  __syncthreads();
  #pragma unroll
  for (int i = 0; i < 32; ++i){
    int idx = t + i*256;
    int nn = idx & 63, mm = idx >> 6;
    out[((size_t)(b*128 + mm))*NPTS + n0 + nn] = tile[nn][mm];
  }
}

extern "C" void kernel_launch(void* const* d_in, const int* in_sizes, int n_in,
                              void* d_out, int out_size, void* d_ws, size_t ws_size,
                              hipStream_t stream){
  const float* xyz1    = (const float*)d_in[0];
  const float* xyz2    = (const float*)d_in[1];
  const float* points1 = (const float*)d_in[2];
  const float* points2 = (const float*)d_in[3];
  const float* conv1_w = (const float*)d_in[4];
  const float* conv1_b = (const float*)d_in[5];
  const float* bn1_g   = (const float*)d_in[6];
  const float* bn1_b   = (const float*)d_in[7];
  const float* conv2_w = (const float*)d_in[8];
  const float* conv2_b = (const float*)d_in[9];
  const float* bn2_g   = (const float*)d_in[10];
  const float* bn2_b   = (const float*)d_in[11];
  const float* wg_w    = (const float*)d_in[12];
  const float* wg_b    = (const float*)d_in[13];
  const float* wg_bn_g = (const float*)d_in[14];
  const float* wg_bn_b = (const float*)d_in[15];
  const float* wx_w    = (const float*)d_in[16];
  const float* wx_b    = (const float*)d_in[17];
  const float* wx_bn_g = (const float*)d_in[18];
  const float* wx_bn_b = (const float*)d_in[19];
  const float* psi_w   = (const float*)d_in[20];
  const float* psi_b   = (const float*)d_in[21];
  const float* psi_bn_g= (const float*)d_in[22];
  const float* psi_bn_b= (const float*)d_in[23];

  char* ws = (char*)d_ws;
  float* stats  = (float*)(ws + O_STATS);
  u16t*  wb     = (u16t*)(ws + O_WB);
  float* psipre = (float*)(ws + O_PSIPRE);
  float4* sp    = (float4*)(ws + O_SP);
  u16t*  p2t    = (u16t*)(ws + O_P2T);
  float* part   = (float*)(ws + O_PART);
  u16t*  p1t    = (u16t*)(ws + O_P1T);
  u16t*  itp    = (u16t*)(ws + O_INT);
  u16t*  h1t    = (u16t*)(ws + O_H1);
  float* pd     = (float*)(ws + O_PD);
  int*   pi     = (int*)(ws + O_PI);
  int*   idx3   = (int*)(ws + O_IDX3);
  float* w3     = (float*)(ws + O_W3);
  u16t*  ygt    = (u16t*)(ws + O_YG);
  u16t*  yxt    = (u16t*)(ws + O_YX);
  u16t*  h2t    = (u16t*)(ws + O_H2);

  hipMemsetAsync(ws + O_STATS, 0, 8192, stream);

  knn_prep_kernel<<<(Bq*SPTS)/256, 256, 0, stream>>>(xyz2, sp);
  knn_part_kernel<<<dim3(NPTS/256, NCH, Bq), 256, 0, stream>>>(xyz1, sp, pd, pi);
  knn_merge_kernel<<<(Bq*NPTS)/256, 256, 0, stream>>>(pd, pi, idx3, w3);
  tpose_kernel<256, SPTS><<<dim3(SPTS/64, 4, Bq), 256, 0, stream>>>(points2, p2t);
  interp_kernel<<<(Bq*NPTS)/8, 256, 0, stream>>>(p2t, idx3, w3, itp);
  tpose_kernel<128, NPTS><<<dim3(NPTS/64, 2, Bq), 256, 0, stream>>>(points1, p1t);
  wcvt_kernel<<<(WTOTAL+255)/256, 256, 0, stream>>>(conv1_w, conv2_w, wg_w, wx_w, wb);

  mfma_conv_kernel<256, 64, false><<<Bq*(NPTS/64), 256, 0, stream>>>(itp, nullptr, wb+WOFF_WG, wg_b, ygt, part,
                                                                     nullptr, nullptr, nullptr, nullptr);
  reduce_stats_kernel<128><<<4, 256, 0, stream>>>(part, stats+ST_WG);
  mfma_conv_kernel<128, 64, false><<<Bq*(NPTS/64), 256, 0, stream>>>(p1t, nullptr, wb+WOFF_WX, wx_b, yxt, part,
                                                                     nullptr, nullptr, nullptr, nullptr);
  reduce_stats_kernel<128><<<4, 256, 0, stream>>>(part, stats+ST_WX);
  gate_kernel<<<256, 256, 0, stream>>>(ygt, yxt, stats+ST_WG, stats+ST_WX,
                                       wg_bn_g, wg_bn_b, wx_bn_g, wx_bn_b,
                                       psi_w, psi_b, psipre, stats+ST_PSI);

  mfma_conv_kernel<384, 256, true><<<Bq*(NPTS/64), 256, 0, stream>>>(p1t, itp, wb+WOFF_C1, conv1_b, h1t, part,
                                                                     psipre, stats+ST_PSI, psi_bn_g, psi_bn_b);
  reduce_stats_kernel<512><<<16, 256, 0, stream>>>(part, stats+ST_BN1);
  bnrelu256_kernel<<<16384, 256, 0, stream>>>(h1t, stats+ST_BN1, bn1_g, bn1_b);

  mfma_conv_kernel<256, 128, false><<<Bq*(NPTS/64), 256, 0, stream>>>(h1t, nullptr, wb+WOFF_C2, conv2_b, h2t, part,
                                                                      nullptr, nullptr, nullptr, nullptr);
  reduce_stats_kernel<256><<<8, 256, 0, stream>>>(part, stats+ST_BN2);
  final_kernel<<<dim3(NPTS/64, Bq), 256, 0, stream>>>(h2t, stats+ST_BN2, bn2_g, bn2_b, (float*)d_out);
}

// Round 12
// 224.162 us; speedup vs baseline: 4.9259x; 1.0097x over previous
//
#include <hip/hip_runtime.h>
#include <hip/hip_bf16.h>

#define Bq    4
#define NPTS  16384
#define SPTS  2048
#define NCH   8
#define SCH   (SPTS/NCH)   // 256
#define CNTF  65536.0f
#define BNEPS 1e-5f

typedef unsigned short u16t;
typedef unsigned int   u32t;
typedef __attribute__((ext_vector_type(8))) short s16x8;
typedef __attribute__((ext_vector_type(4))) float f32x4;

#define AS1(p) ((const __attribute__((address_space(1))) void*)(p))
#define AS3(p) ((__attribute__((address_space(3))) void*)(p))

__device__ __forceinline__ float b2f(u16t u){
  union { u32t i; float f; } v; v.i = ((u32t)u) << 16; return v.f;
}
__device__ __forceinline__ u16t f2b(float f){
  __hip_bfloat16 h = __float2bfloat16(f);
  return *reinterpret_cast<u16t*>(&h);
}
__device__ __forceinline__ float lrelu(float x){ return x >= 0.0f ? x : 0.2f*x; }

// ---- stats f32 offsets: per-channel [sum,sumsq] pairs ----
#define ST_WG  0
#define ST_WX  128
#define ST_PSI 256
#define ST_BN1 272
#define ST_BN2 784

// ---- bf16 weight element offsets inside WB region ----
#define WOFF_C1 0
#define WOFF_C2 98304
#define WOFF_WG 131072
#define WOFF_WX 147456
#define WTOTAL  155648

// ---- ws byte offsets (time-disjoint aliasing; total ~84.6 MB) ----
#define O_STATS  0u
#define O_WB     8192u
#define O_PSIPRE 319488u        // 262144 B; first 128 KB doubles as packed-xyz2 sp (dead before gate writes psipre)
#define O_SP     O_PSIPRE
#define O_P2T    581632u        // 4 MB bf16 [B][S][256]; dead after interp
#define O_PART   O_P2T          // conv stats partials [1024][<=512] f32 = 2 MB, used after interp
#define O_P1T    4775936u       // 16.7 MB bf16 [B][N][128] (read-only; psi folded into conv1)
#define O_INT    21553152u      // 33.5 MB bf16 [B][N][256] interp; h2t aliases later
#define O_H1     55107584u      // 33.5 MB bf16 [B][N][256] h1; bnrelu IN PLACE
// knn scratch lives inside the (not-yet-written) H1 region:
#define O_PD     O_H1                    // 6.29 MB f32 partial dists [B][N][NCH][3]
#define O_PI     (O_H1 + 6291456u)       // 6.29 MB i32 partial idx
#define O_IDX3   (O_H1 + 12582912u)      // 786 KB
#define O_W3     (O_H1 + 13369344u)      // 786 KB (all dead before ygt written)
#define O_YG     O_H1                    // ygt/yxt live steps 5-8, dead before h1 written
#define O_YX     (O_H1 + 8388608u)
#define O_H2     O_INT                   // h2 bf16, written after interp dead
// end = 55107584 + 33554432 = 88662016 B

// ---- pack xyz2 -> sp[B][S] = (x,y,z,|s|^2) for wave-uniform scalar loads ----
__global__ __launch_bounds__(256) void knn_prep_kernel(const float* __restrict__ xyz2, float4* __restrict__ sp){
  int i = blockIdx.x*256 + threadIdx.x;   // [0, B*S)
  int b = i >> 11, s = i & (SPTS-1);
  float x = xyz2[(b*3+0)*SPTS+s];
  float y = xyz2[(b*3+1)*SPTS+s];
  float z = xyz2[(b*3+2)*SPTS+s];
  sp[i] = make_float4(x, y, z, x*x+y*y+z*z);
}

// ---- 3-NN part 1: per-chunk top-3; branchless sorted-triple insert, scalar candidate loads ----
__global__ __launch_bounds__(256) void knn_part_kernel(const float* __restrict__ xyz1, const float4* __restrict__ sp,
                                                       float* __restrict__ pd, int* __restrict__ pi){
  const int b = blockIdx.z;
  const int c = blockIdx.y;
  const int n = blockIdx.x*256 + threadIdx.x;
  const float4* cp = sp + (size_t)b*SPTS + c*SCH;   // wave-uniform base
  float px = xyz1[(b*3+0)*NPTS+n];
  float py = xyz1[(b*3+1)*NPTS+n];
  float pz = xyz1[(b*3+2)*NPTS+n];
  float s1 = px*px+py*py+pz*pz;
  float d0=3.4e38f, d1=3.4e38f, d2=3.4e38f;
  int   i0=0, i1=0, i2=0;
  const int cbase = c*SCH;
  #pragma unroll 8
  for (int s=0; s<SCH; ++s){
    float4 q = cp[s];                               // uniform addr -> scalar pipe
    float dot = fmaf(pz, q.z, fmaf(py, q.y, px*q.x));
    float key = (s1 + q.w) - 2.0f*dot;              // bitwise == reference (2*dot exact)
    int gi = cbase + s;
    bool c0 = key < d0, c1 = key < d1, c2 = key < d2;
    int ni2 = c1 ? i1 : (c2 ? gi : i2);
    int ni1 = c0 ? i0 : (c1 ? gi : i1);
    i0 = c0 ? gi : i0;
    float nd2 = fminf(d2, fmaxf(d1, key));
    d1 = __builtin_amdgcn_fmed3f(d0, d1, key);
    d0 = fminf(d0, key);
    d2 = nd2; i1 = ni1; i2 = ni2;
  }
  size_t base = (((size_t)b*NPTS + n)*NCH + c)*3;
  pd[base]=d0; pd[base+1]=d1; pd[base+2]=d2;
  pi[base]=i0; pi[base+1]=i1; pi[base+2]=i2;
}

// ---- 3-NN part 2: merge NCH partial top-3 lists (chunk-order => stable ties) ----
__global__ __launch_bounds__(256) void knn_merge_kernel(const float* __restrict__ pd, const int* __restrict__ pi,
                                                        int* __restrict__ idx3, float* __restrict__ w3){
  const int p = blockIdx.x*256 + threadIdx.x;   // [0, B*N)
  const float* dp = pd + (size_t)p*NCH*3;
  const int*   ip = pi + (size_t)p*NCH*3;
  float d0=3.4e38f, d1=3.4e38f, d2=3.4e38f;
  int   i0=0, i1=0, i2=0;
  #pragma unroll
  for (int k=0; k<NCH*3; ++k){
    float key = dp[k]; int gi = ip[k];
    bool c0 = key < d0, c1 = key < d1, c2 = key < d2;
    int ni2 = c1 ? i1 : (c2 ? gi : i2);
    int ni1 = c0 ? i0 : (c1 ? gi : i1);
    i0 = c0 ? gi : i0;
    float nd2 = fminf(d2, fmaxf(d1, key));
    d1 = __builtin_amdgcn_fmed3f(d0, d1, key);
    d0 = fminf(d0, key);
    d2 = nd2; i1 = ni1; i2 = ni2;
  }
  float r0=1.0f/(d0+1e-8f), r1=1.0f/(d1+1e-8f), r2=1.0f/(d2+1e-8f);
  float rs = r0+r1+r2;
  size_t base = (size_t)p*3;
  idx3[base]=i0; idx3[base+1]=i1; idx3[base+2]=i2;
  w3[base]=r0/rs; w3[base+1]=r1/rs; w3[base+2]=r2/rs;
}

// ---- tiled transpose: src f32 [B][C][NN] -> dst bf16 [B][NN][C] ----
template<int C, int NN>
__global__ __launch_bounds__(256) void tpose_kernel(const float* __restrict__ src, u16t* __restrict__ dst){
  __shared__ float tile[64][65];
  const int n0 = blockIdx.x * 64;
  const int c0 = blockIdx.y * 64;
  const int b  = blockIdx.z;
  const int t  = threadIdx.x;
  #pragma unroll
  for (int i = 0; i < 16; ++i){
    int idx = t + i*256;
    int cc = idx >> 6, nn = idx & 63;
    tile[cc][nn] = src[((size_t)b*C + c0 + cc)*NN + n0 + nn];
  }
  __syncthreads();
  #pragma unroll
  for (int i = 0; i < 16; ++i){
    int idx = t + i*256;
    int nn = idx >> 6, cc = idx & 63;
    dst[((size_t)b*NN + n0 + nn)*C + c0 + cc] = f2b(tile[cc][nn]);
  }
}

// ---- weight convert f32 -> bf16 into WB ----
__global__ __launch_bounds__(256) void wcvt_kernel(const float* __restrict__ w1, const float* __restrict__ w2,
                                                   const float* __restrict__ wg, const float* __restrict__ wx,
                                                   u16t* __restrict__ wb){
  int i = blockIdx.x*256 + threadIdx.x;
  if (i >= WTOTAL) return;
  float v;
  if      (i < WOFF_C2) v = w1[i];
  else if (i < WOFF_WG) v = w2[i - WOFF_C2];
  else if (i < WOFF_WX) v = wg[i - WOFF_WG];
  else                  v = wx[i - WOFF_WX];
  wb[i] = f2b(v);
}

// ---- interp: half-wave (32 lanes) per point; coalesced 512B row reads/writes ----
__global__ __launch_bounds__(256) void interp_kernel(const u16t* __restrict__ p2t, const int* __restrict__ idx3,
                                                     const float* __restrict__ w3, u16t* __restrict__ it){
  const int t = threadIdx.x;
  const int pid = blockIdx.x*8 + (t >> 5);   // global point in [0, B*N)
  const int l = t & 31;                      // lane-in-half: channels l*8..l*8+8
  const int b = pid >> 14;                   // NPTS = 16384
  size_t pb = (size_t)pid*3;
  int i0 = idx3[pb], i1 = idx3[pb+1], i2 = idx3[pb+2];
  float w0 = w3[pb], w1 = w3[pb+1], w2 = w3[pb+2];
  const u16t* r0 = p2t + ((size_t)b*SPTS + i0)*256 + l*8;
  const u16t* r1 = p2t + ((size_t)b*SPTS + i1)*256 + l*8;
  const u16t* r2 = p2t + ((size_t)b*SPTS + i2)*256 + l*8;
  uint4 q0 = *reinterpret_cast<const uint4*>(r0);
  uint4 q1 = *reinterpret_cast<const uint4*>(r1);
  uint4 q2 = *reinterpret_cast<const uint4*>(r2);
  const u32t* a0 = reinterpret_cast<const u32t*>(&q0);
  const u32t* a1 = reinterpret_cast<const u32t*>(&q1);
  const u32t* a2 = reinterpret_cast<const u32t*>(&q2);
  u32t ow[4];
  #pragma unroll
  for (int j = 0; j < 4; ++j){
    u32t u0 = a0[j], u1 = a1[j], u2 = a2[j];
    float lo = fmaf(w2, b2f((u16t)u2), fmaf(w1, b2f((u16t)u1), w0*b2f((u16t)u0)));
    float hi = fmaf(w2, b2f((u16t)(u2>>16)), fmaf(w1, b2f((u16t)(u1>>16)), w0*b2f((u16t)(u0>>16))));
    ow[j] = (u32t)f2b(lo) | ((u32t)f2b(hi) << 16);
  }
  *reinterpret_cast<uint4*>(it + (size_t)pid*256 + l*8) = make_uint4(ow[0], ow[1], ow[2], ow[3]);
}

// ---- MFMA conv1x1, LDS-staged activations + LDS-staged C-tile (coalesced row stores) ----
// y[B][N][OUT] = W[OUT][CIN] . x[B][N][CIN] + bias (raw, pre-BN)
// SPLIT (conv1): acc = psi[n]*(W1.p1) + W2.interp (exact linear identity).
// C-tile [64][OUT+8] in LDS (pad kills write bank conflicts); full-row uint4 stores
// eliminate the partial-line write-allocate RMW (was 48MB WRITE for 33.5MB output).
template<int CIN, int OUT, bool SPLIT>
__global__ __launch_bounds__(256, 1) void mfma_conv_kernel(const u16t* __restrict__ xa, const u16t* __restrict__ xb,
                                                           const u16t* __restrict__ W, const float* __restrict__ bias,
                                                           u16t* __restrict__ y, float* __restrict__ partial,
                                                           const float* __restrict__ psipre, const float* __restrict__ stpsi,
                                                           const float* __restrict__ pbn_g, const float* __restrict__ pbn_b){
  constexpr int MW = OUT/4;      // per-wave M slice
  constexpr int MF = MW/16;      // m-fragments per wave
  constexpr int NC = CIN/64;     // 64-channel k-chunks
  constexpr int CSTR = OUT + 8;  // padded ctile row stride (elems)
  constexpr int LDSZ = (CSTR*64 > 8192) ? CSTR*64 : 8192;
  __shared__ u16t lds[LDSZ];     // staging dbuf (2x4096) unions with ctile (time-disjoint)
  u16t* sbuf0 = lds;
  u16t* sbuf1 = lds + 4096;
  const int bid = blockIdx.x;
  const int b = bid >> 8;
  const int n0 = (bid & 255) * 64;
  const int wv = threadIdx.x >> 6;
  const int lane = threadIdx.x & 63;
  const int lr = lane & 15;
  const int kg = lane >> 4;
  const int m0 = wv * MW;
  const int t = threadIdx.x;

  float psiv[4];
  if (SPLIT){
    float m  = stpsi[0]*(1.0f/CNTF);
    float vv = fmaxf(stpsi[1]*(1.0f/CNTF) - m*m, 0.0f);
    float iv = 1.0f/sqrtf(vv + BNEPS);
    float ap = pbn_g[0]*iv;
    float bp = pbn_b[0] - m*ap;
    #pragma unroll
    for (int nf = 0; nf < 4; ++nf){
      float z = fmaf(psipre[b*NPTS + n0 + nf*16 + lr], ap, bp);
      psiv[nf] = 1.0f/(1.0f + expf(-z));
    }
  }

  f32x4 acc[MF][4];
  #pragma unroll
  for (int mf = 0; mf < MF; ++mf)
    #pragma unroll
    for (int nf = 0; nf < 4; ++nf){ acc[mf][nf][0]=0.f; acc[mf][nf][1]=0.f; acc[mf][nf][2]=0.f; acc[mf][nf][3]=0.f; }

  const u16t* wrow[MF];
  #pragma unroll
  for (int mf = 0; mf < MF; ++mf)
    wrow[mf] = W + (size_t)(m0 + mf*16 + lr)*CIN + kg*8;

  const int prow0 = wv*16 + (lane>>3);                 // +8 for i=1 (row&7 unchanged)
  const int gslot = (lane & 7) ^ ((lane >> 3) & 7);    // pre-swizzled source slot
  int rdoff[2][4];
  #pragma unroll
  for (int ks = 0; ks < 2; ++ks)
    #pragma unroll
    for (int nf = 0; nf < 4; ++nf)
      rdoff[ks][nf] = (nf*16 + lr)*64 + (((ks*4 + kg) ^ (lr & 7)) << 3);

  auto stage = [&](int c, int buf){
    #pragma unroll
    for (int i = 0; i < 2; ++i){
      int p = prow0 + i*8;
      const u16t* g;
      if (SPLIT){
        if (c < 2) g = xa + ((size_t)b*NPTS + n0 + p)*128 + c*64     + gslot*8;
        else       g = xb + ((size_t)b*NPTS + n0 + p)*256 + (c-2)*64 + gslot*8;
      } else {
        g = xa + ((size_t)b*NPTS + n0 + p)*CIN + c*64 + gslot*8;
      }
      u16t* l = (buf ? sbuf1 : sbuf0) + (wv*16 + i*8)*64;   // wave-uniform base; HW adds lane*16B
      __builtin_amdgcn_global_load_lds(AS1(g), AS3(l), 16, 0, 0);
    }
  };

  stage(0, 0);
  __syncthreads();
  #pragma unroll
  for (int c = 0; c < NC; ++c){
    if (c + 1 < NC) stage(c+1, (c+1)&1);
    #pragma unroll
    for (int ks = 0; ks < 2; ++ks){
      const int k0 = c*2 + ks;
      s16x8 av[MF];
      #pragma unroll
      for (int mf = 0; mf < MF; ++mf)
        av[mf] = *reinterpret_cast<const s16x8*>(wrow[mf] + k0*32);
      s16x8 bv[4];
      #pragma unroll
      for (int nf = 0; nf < 4; ++nf)
        bv[nf] = *reinterpret_cast<const s16x8*>(((c&1) ? sbuf1 : sbuf0) + rdoff[ks][nf]);
      #pragma unroll
      for (int mf = 0; mf < MF; ++mf)
        #pragma unroll
        for (int nf = 0; nf < 4; ++nf)
          acc[mf][nf] = __builtin_amdgcn_mfma_f32_16x16x32_bf16(av[mf], bv[nf], acc[mf][nf], 0, 0, 0);
    }
    if (SPLIT && c == 1){
      #pragma unroll
      for (int mf = 0; mf < MF; ++mf)
        #pragma unroll
        for (int nf = 0; nf < 4; ++nf){
          acc[mf][nf][0] *= psiv[nf]; acc[mf][nf][1] *= psiv[nf];
          acc[mf][nf][2] *= psiv[nf]; acc[mf][nf][3] *= psiv[nf];
        }
    }
    __syncthreads();   // drains stage(c+1) vmcnt + syncs readers; after last iter, sbuf is dead
  }

  // epilogue: bias + stats + C-tile into LDS (sbuf region is dead past the final barrier)
  #pragma unroll
  for (int mf = 0; mf < MF; ++mf){
    int mb = m0 + mf*16 + kg*4;
    float4 bs = *reinterpret_cast<const float4*>(bias + mb);
    float s0=0.f,s1=0.f,s2=0.f,s3=0.f,q0=0.f,q1=0.f,q2=0.f,q3=0.f;
    #pragma unroll
    for (int nf = 0; nf < 4; ++nf){
      int row = nf*16 + lr;
      float v0 = acc[mf][nf][0] + bs.x;
      float v1 = acc[mf][nf][1] + bs.y;
      float v2 = acc[mf][nf][2] + bs.z;
      float v3 = acc[mf][nf][3] + bs.w;
      s0+=v0; q0+=v0*v0; s1+=v1; q1+=v1*v1;
      s2+=v2; q2+=v2*v2; s3+=v3; q3+=v3*v3;
      uint2 pv;
      pv.x = (u32t)f2b(v0) | ((u32t)f2b(v1) << 16);
      pv.y = (u32t)f2b(v2) | ((u32t)f2b(v3) << 16);
      *reinterpret_cast<uint2*>(&lds[row*CSTR + mb]) = pv;
    }
    #pragma unroll
    for (int o = 1; o < 16; o <<= 1){
      s0 += __shfl_xor(s0, o); s1 += __shfl_xor(s1, o);
      s2 += __shfl_xor(s2, o); s3 += __shfl_xor(s3, o);
      q0 += __shfl_xor(q0, o); q1 += __shfl_xor(q1, o);
      q2 += __shfl_xor(q2, o); q3 += __shfl_xor(q3, o);
    }
    if (lr == 0){
      float* pp = partial + (size_t)bid*(OUT*2) + mb*2;
      pp[0]=s0; pp[1]=q0; pp[2]=s1; pp[3]=q1;
      pp[4]=s2; pp[5]=q2; pp[6]=s3; pp[7]=q3;
    }
  }
  __syncthreads();
  // cooperative full-row stores: 16B/lane, contiguous 128B lines, no RMW
  constexpr int CH8 = OUT/8;              // 16B chunks per row
  #pragma unroll
  for (int i = 0; i < (64*CH8)/256; ++i){
    int idx = t + i*256;
    int row = idx / CH8, c8 = idx % CH8;  // CH8 is a power of 2
    uint4 v = *reinterpret_cast<const uint4*>(&lds[row*CSTR + c8*8]);
    *reinterpret_cast<uint4*>(y + ((size_t)b*NPTS + n0 + row)*OUT + c8*8) = v;
  }
}

// ---- reduce conv partials [1024][E] -> stats[E] (no atomics) ----
template<int E>
__global__ __launch_bounds__(256) void reduce_stats_kernel(const float* __restrict__ p, float* __restrict__ st){
  __shared__ float ls[8][32];
  const int t = threadIdx.x;
  const int kq = t >> 5, es = t & 31;
  const int e = blockIdx.x*32 + es;
  float s = 0.f;
  const float* pp = p + (size_t)kq*128*E + e;
  #pragma unroll 16
  for (int i = 0; i < 128; ++i) s += pp[(size_t)i*E];
  ls[kq][es] = s;
  __syncthreads();
  if (kq == 0){
    st[e] = ((ls[0][es]+ls[1][es])+(ls[2][es]+ls[3][es]))
          + ((ls[4][es]+ls[5][es])+(ls[6][es]+ls[7][es]));
  }
}

// ---- gate: psi_pre[p] = psi_w . lrelu(bn(yg)+bn(yx)) + psi_b, + psi stats ----
__global__ __launch_bounds__(256) void gate_kernel(const u16t* __restrict__ yg, const u16t* __restrict__ yx,
                                                   const float* __restrict__ stg, const float* __restrict__ stx,
                                                   const float* __restrict__ wg_bn_g, const float* __restrict__ wg_bn_b,
                                                   const float* __restrict__ wx_bn_g, const float* __restrict__ wx_bn_b,
                                                   const float* __restrict__ psi_w, const float* __restrict__ psi_b,
                                                   float* __restrict__ psipre, float* __restrict__ stpsi){
  __shared__ float lag[64], lbg[64], lax[64], lbx[64], lpw[64];
  __shared__ float red[8];
  const int t = threadIdx.x;
  if (t < 64){
    float m  = stg[t*2] * (1.0f/CNTF);
    float vv = fmaxf(stg[t*2+1]*(1.0f/CNTF) - m*m, 0.0f);
    float iv = 1.0f/sqrtf(vv + BNEPS);
    float gm = wg_bn_g[t];
    lag[t] = gm*iv; lbg[t] = wg_bn_b[t] - m*gm*iv;
    m  = stx[t*2] * (1.0f/CNTF);
    vv = fmaxf(stx[t*2+1]*(1.0f/CNTF) - m*m, 0.0f);
    iv = 1.0f/sqrtf(vv + BNEPS);
    gm = wx_bn_g[t];
    lax[t] = gm*iv; lbx[t] = wx_bn_b[t] - m*gm*iv;
    lpw[t] = psi_w[t];
  }
  __syncthreads();
  const int p = blockIdx.x*256 + t;
  const u16t* rg = yg + (size_t)p*64;
  const u16t* rx = yx + (size_t)p*64;
  float acc = psi_b[0];
  #pragma unroll
  for (int u = 0; u < 8; ++u){
    uint4 qg = *reinterpret_cast<const uint4*>(rg + u*8);
    uint4 qx = *reinterpret_cast<const uint4*>(rx + u*8);
    const u32t* g4 = reinterpret_cast<const u32t*>(&qg);
    const u32t* x4 = reinterpret_cast<const u32t*>(&qx);
    #pragma unroll
    for (int e = 0; e < 4; ++e){
      int j = u*8 + e*2;
      float gv0 = fmaf(b2f((u16t)g4[e]),        lag[j],   lbg[j]);
      float xv0 = fmaf(b2f((u16t)x4[e]),        lax[j],   lbx[j]);
      float gv1 = fmaf(b2f((u16t)(g4[e]>>16)),  lag[j+1], lbg[j+1]);
      float xv1 = fmaf(b2f((u16t)(x4[e]>>16)),  lax[j+1], lbx[j+1]);
      acc = fmaf(lpw[j],   lrelu(gv0 + xv0), acc);
      acc = fmaf(lpw[j+1], lrelu(gv1 + xv1), acc);
    }
  }
  psipre[p] = acc;
  float s = acc, q = acc*acc;
  #pragma unroll
  for (int o = 32; o; o >>= 1){ s += __shfl_xor(s, o); q += __shfl_xor(q, o); }
  if ((t & 63) == 0){ red[(t>>6)*2] = s; red[(t>>6)*2+1] = q; }
  __syncthreads();
  if (t == 0){
    atomicAdd(&stpsi[0], red[0]+red[2]+red[4]+red[6]);
    atomicAdd(&stpsi[1], red[1]+red[3]+red[5]+red[7]);
  }
}

// ---- bn1 + lrelu in place on h1 [P][256] bf16 ----
__global__ __launch_bounds__(256) void bnrelu256_kernel(u16t* __restrict__ x, const float* __restrict__ st,
                                                        const float* __restrict__ g, const float* __restrict__ bb){
  __shared__ float sa[256], sc[256];
  const int t = threadIdx.x;
  {
    float m  = st[t*2]*(1.0f/CNTF);
    float vv = fmaxf(st[t*2+1]*(1.0f/CNTF) - m*m, 0.0f);
    float iv = 1.0f/sqrtf(vv + BNEPS);
    float gm = g[t];
    sa[t] = gm*iv; sc[t] = bb[t] - m*gm*iv;
  }
  __syncthreads();
  size_t e4 = ((size_t)blockIdx.x*256 + t)*4;
  int c0 = (int)(e4 & 255);
  uint2 v = *reinterpret_cast<uint2*>(x + e4);
  float f0 = lrelu(fmaf(b2f((u16t)v.x),        sa[c0],   sc[c0]));
  float f1 = lrelu(fmaf(b2f((u16t)(v.x>>16)),  sa[c0+1], sc[c0+1]));
  float f2 = lrelu(fmaf(b2f((u16t)v.y),        sa[c0+2], sc[c0+2]));
  float f3 = lrelu(fmaf(b2f((u16t)(v.y>>16)),  sa[c0+3], sc[c0+3]));
  v.x = (u32t)f2b(f0) | ((u32t)f2b(f1) << 16);
  v.y = (u32t)f2b(f2) | ((u32t)f2b(f3) << 16);
  *reinterpret_cast<uint2*>(x + e4) = v;
}

// ---- final: out[b][m][n] f32 = lrelu(bn2(h2[b][n][m])) via LDS tile transpose ----
__global__ __launch_bounds__(256) void final_kernel(const u16t* __restrict__ h2, const float* __restrict__ st,
                                                    const float* __restrict__ g, const float* __restrict__ bb,
                                                    float* __restrict__ out){
  __shared__ float am[128], cm[128];
  __shared__ float tile[64][129];
  const int t = threadIdx.x;
  if (t < 128){
    float m  = st[t*2]*(1.0f/CNTF);
    float vv = fmaxf(st[t*2+1]*(1.0f/CNTF) - m*m, 0.0f);
    float iv = 1.0f/sqrtf(vv + BNEPS);
    float gm = g[t];
    am[t] = gm*iv; cm[t] = bb[t] - m*gm*iv;
  }
  __syncthreads();
  const int n0 = blockIdx.x * 64;
  const int b  = blockIdx.y;
  #pragma unroll
  for (int i = 0; i < 32; ++i){
    int idx = t + i*256;
    int mm = idx & 127, nn = idx >> 7;
    float v = fmaf(b2f(h2[((size_t)b*NPTS + n0 + nn)*128 + mm]), am[mm], cm[mm]);
    tile[nn][mm] = lrelu(v);
  }
  __syncthreads();
  #pragma unroll
  for (int i = 0; i < 32; ++i){
    int idx = t + i*256;
    int nn = idx & 63, mm = idx >> 6;
    out[((size_t)(b*128 + mm))*NPTS + n0 + nn] = tile[nn][mm];
  }
}

extern "C" void kernel_launch(void* const* d_in, const int* in_sizes, int n_in,
                              void* d_out, int out_size, void* d_ws, size_t ws_size,
                              hipStream_t stream){
  const float* xyz1    = (const float*)d_in[0];
  const float* xyz2    = (const float*)d_in[1];
  const float* points1 = (const float*)d_in[2];
  const float* points2 = (const float*)d_in[3];
  const float* conv1_w = (const float*)d_in[4];
  const float* conv1_b = (const float*)d_in[5];
  const float* bn1_g   = (const float*)d_in[6];
  const float* bn1_b   = (const float*)d_in[7];
  const float* conv2_w = (const float*)d_in[8];
  const float* conv2_b = (const float*)d_in[9];
  const float* bn2_g   = (const float*)d_in[10];
  const float* bn2_b   = (const float*)d_in[11];
  const float* wg_w    = (const float*)d_in[12];
  const float* wg_b    = (const float*)d_in[13];
  const float* wg_bn_g = (const float*)d_in[14];
  const float* wg_bn_b = (const float*)d_in[15];
  const float* wx_w    = (const float*)d_in[16];
  const float* wx_b    = (const float*)d_in[17];
  const float* wx_bn_g = (const float*)d_in[18];
  const float* wx_bn_b = (const float*)d_in[19];
  const float* psi_w   = (const float*)d_in[20];
  const float* psi_b   = (const float*)d_in[21];
  const float* psi_bn_g= (const float*)d_in[22];
  const float* psi_bn_b= (const float*)d_in[23];

  char* ws = (char*)d_ws;
  float* stats  = (float*)(ws + O_STATS);
  u16t*  wb     = (u16t*)(ws + O_WB);
  float* psipre = (float*)(ws + O_PSIPRE);
  float4* sp    = (float4*)(ws + O_SP);
  u16t*  p2t    = (u16t*)(ws + O_P2T);
  float* part   = (float*)(ws + O_PART);
  u16t*  p1t    = (u16t*)(ws + O_P1T);
  u16t*  itp    = (u16t*)(ws + O_INT);
  u16t*  h1t    = (u16t*)(ws + O_H1);
  float* pd     = (float*)(ws + O_PD);
  int*   pi     = (int*)(ws + O_PI);
  int*   idx3   = (int*)(ws + O_IDX3);
  float* w3     = (float*)(ws + O_W3);
  u16t*  ygt    = (u16t*)(ws + O_YG);
  u16t*  yxt    = (u16t*)(ws + O_YX);
  u16t*  h2t    = (u16t*)(ws + O_H2);

  hipMemsetAsync(ws + O_STATS, 0, 8192, stream);

  knn_prep_kernel<<<(Bq*SPTS)/256, 256, 0, stream>>>(xyz2, sp);
  knn_part_kernel<<<dim3(NPTS/256, NCH, Bq), 256, 0, stream>>>(xyz1, sp, pd, pi);
  knn_merge_kernel<<<(Bq*NPTS)/256, 256, 0, stream>>>(pd, pi, idx3, w3);
  tpose_kernel<256, SPTS><<<dim3(SPTS/64, 4, Bq), 256, 0, stream>>>(points2, p2t);
  interp_kernel<<<(Bq*NPTS)/8, 256, 0, stream>>>(p2t, idx3, w3, itp);
  tpose_kernel<128, NPTS><<<dim3(NPTS/64, 2, Bq), 256, 0, stream>>>(points1, p1t);
  wcvt_kernel<<<(WTOTAL+255)/256, 256, 0, stream>>>(conv1_w, conv2_w, wg_w, wx_w, wb);

  mfma_conv_kernel<256, 64, false><<<Bq*(NPTS/64), 256, 0, stream>>>(itp, nullptr, wb+WOFF_WG, wg_b, ygt, part,
                                                                     nullptr, nullptr, nullptr, nullptr);
  reduce_stats_kernel<128><<<4, 256, 0, stream>>>(part, stats+ST_WG);
  mfma_conv_kernel<128, 64, false><<<Bq*(NPTS/64), 256, 0, stream>>>(p1t, nullptr, wb+WOFF_WX, wx_b, yxt, part,
                                                                     nullptr, nullptr, nullptr, nullptr);
  reduce_stats_kernel<128><<<4, 256, 0, stream>>>(part, stats+ST_WX);
  gate_kernel<<<256, 256, 0, stream>>>(ygt, yxt, stats+ST_WG, stats+ST_WX,
                                       wg_bn_g, wg_bn_b, wx_bn_g, wx_bn_b,
                                       psi_w, psi_b, psipre, stats+ST_PSI);

  mfma_conv_kernel<384, 256, true><<<Bq*(NPTS/64), 256, 0, stream>>>(p1t, itp, wb+WOFF_C1, conv1_b, h1t, part,
                                                                     psipre, stats+ST_PSI, psi_bn_g, psi_bn_b);
  reduce_stats_kernel<512><<<16, 256, 0, stream>>>(part, stats+ST_BN1);
  bnrelu256_kernel<<<16384, 256, 0, stream>>>(h1t, stats+ST_BN1, bn1_g, bn1_b);

  mfma_conv_kernel<256, 128, false><<<Bq*(NPTS/64), 256, 0, stream>>>(h1t, nullptr, wb+WOFF_C2, conv2_b, h2t, part,
                                                                      nullptr, nullptr, nullptr, nullptr);
  reduce_stats_kernel<256><<<8, 256, 0, stream>>>(part, stats+ST_BN2);
  final_kernel<<<dim3(NPTS/64, Bq), 256, 0, stream>>>(h2t, stats+ST_BN2, bn2_g, bn2_b, (float*)d_out);
}

// Round 13
// 212.454 us; speedup vs baseline: 5.1974x; 1.0551x over previous
//
#include <hip/hip_runtime.h>
#include <hip/hip_bf16.h>

#define Bq    4
#define NPTS  16384
#define SPTS  2048
#define NCH   8
#define SCH   (SPTS/NCH)   // 256
#define CNTF  65536.0f
#define BNEPS 1e-5f

typedef unsigned short u16t;
typedef unsigned int   u32t;
typedef __attribute__((ext_vector_type(8))) short s16x8;
typedef __attribute__((ext_vector_type(4))) float f32x4;

#define AS1(p) ((const __attribute__((address_space(1))) void*)(p))
#define AS3(p) ((__attribute__((address_space(3))) void*)(p))

__device__ __forceinline__ float b2f(u16t u){
  union { u32t i; float f; } v; v.i = ((u32t)u) << 16; return v.f;
}
__device__ __forceinline__ u16t f2b(float f){
  __hip_bfloat16 h = __float2bfloat16(f);
  return *reinterpret_cast<u16t*>(&h);
}
__device__ __forceinline__ float lrelu(float x){ return x >= 0.0f ? x : 0.2f*x; }

// ---- stats f32 offsets: per-channel [sum,sumsq] pairs ----
#define ST_WG  0
#define ST_WX  128
#define ST_PSI 256
#define ST_BN1 272
#define ST_BN2 784

// ---- bf16 weight element offsets inside WB region ----
#define WOFF_C1 0
#define WOFF_C2 98304
#define WOFF_WG 131072
#define WOFF_WX 147456
#define WTOTAL  155648

// ---- ws byte offsets (time-disjoint aliasing; total ~84.6 MB) ----
#define O_STATS  0u
#define O_WB     8192u
#define O_PSIPRE 319488u        // 262144 B; first 128 KB doubles as packed-xyz2 sp
#define O_SP     O_PSIPRE
#define O_P2T    581632u        // 4 MB bf16 [B][S][256]; dead after interp
#define O_PART   O_P2T          // conv stats partials [512][<=512] f32 = 1 MB, used after interp
#define O_P1T    4775936u       // 16.7 MB bf16 [B][N][128]
#define O_INT    21553152u      // 33.5 MB bf16 [B][N][256] interp; h2t aliases later
#define O_H1     55107584u      // 33.5 MB bf16 [B][N][256] h1; bnrelu IN PLACE
#define O_PD     O_H1
#define O_PI     (O_H1 + 6291456u)
#define O_IDX3   (O_H1 + 12582912u)
#define O_W3     (O_H1 + 13369344u)
#define O_YG     O_H1
#define O_YX     (O_H1 + 8388608u)
#define O_H2     O_INT
// end = 55107584 + 33554432 = 88662016 B

// ---- pack xyz2 -> sp[B][S] = (x,y,z,|s|^2) ----
__global__ __launch_bounds__(256) void knn_prep_kernel(const float* __restrict__ xyz2, float4* __restrict__ sp){
  int i = blockIdx.x*256 + threadIdx.x;
  int b = i >> 11, s = i & (SPTS-1);
  float x = xyz2[(b*3+0)*SPTS+s];
  float y = xyz2[(b*3+1)*SPTS+s];
  float z = xyz2[(b*3+2)*SPTS+s];
  sp[i] = make_float4(x, y, z, x*x+y*y+z*z);
}

// ---- 3-NN part 1 (unchanged, VALU-floor) ----
__global__ __launch_bounds__(256) void knn_part_kernel(const float* __restrict__ xyz1, const float4* __restrict__ sp,
                                                       float* __restrict__ pd, int* __restrict__ pi){
  const int b = blockIdx.z;
  const int c = blockIdx.y;
  const int n = blockIdx.x*256 + threadIdx.x;
  const float4* cp = sp + (size_t)b*SPTS + c*SCH;
  float px = xyz1[(b*3+0)*NPTS+n];
  float py = xyz1[(b*3+1)*NPTS+n];
  float pz = xyz1[(b*3+2)*NPTS+n];
  float s1 = px*px+py*py+pz*pz;
  float d0=3.4e38f, d1=3.4e38f, d2=3.4e38f;
  int   i0=0, i1=0, i2=0;
  const int cbase = c*SCH;
  #pragma unroll 8
  for (int s=0; s<SCH; ++s){
    float4 q = cp[s];
    float dot = fmaf(pz, q.z, fmaf(py, q.y, px*q.x));
    float key = (s1 + q.w) - 2.0f*dot;
    int gi = cbase + s;
    bool c0 = key < d0, c1 = key < d1, c2 = key < d2;
    int ni2 = c1 ? i1 : (c2 ? gi : i2);
    int ni1 = c0 ? i0 : (c1 ? gi : i1);
    i0 = c0 ? gi : i0;
    float nd2 = fminf(d2, fmaxf(d1, key));
    d1 = __builtin_amdgcn_fmed3f(d0, d1, key);
    d0 = fminf(d0, key);
    d2 = nd2; i1 = ni1; i2 = ni2;
  }
  size_t base = (((size_t)b*NPTS + n)*NCH + c)*3;
  pd[base]=d0; pd[base+1]=d1; pd[base+2]=d2;
  pi[base]=i0; pi[base+1]=i1; pi[base+2]=i2;
}

// ---- 3-NN part 2 (unchanged) ----
__global__ __launch_bounds__(256) void knn_merge_kernel(const float* __restrict__ pd, const int* __restrict__ pi,
                                                        int* __restrict__ idx3, float* __restrict__ w3){
  const int p = blockIdx.x*256 + threadIdx.x;
  const float* dp = pd + (size_t)p*NCH*3;
  const int*   ip = pi + (size_t)p*NCH*3;
  float d0=3.4e38f, d1=3.4e38f, d2=3.4e38f;
  int   i0=0, i1=0, i2=0;
  #pragma unroll
  for (int k=0; k<NCH*3; ++k){
    float key = dp[k]; int gi = ip[k];
    bool c0 = key < d0, c1 = key < d1, c2 = key < d2;
    int ni2 = c1 ? i1 : (c2 ? gi : i2);
    int ni1 = c0 ? i0 : (c1 ? gi : i1);
    i0 = c0 ? gi : i0;
    float nd2 = fminf(d2, fmaxf(d1, key));
    d1 = __builtin_amdgcn_fmed3f(d0, d1, key);
    d0 = fminf(d0, key);
    d2 = nd2; i1 = ni1; i2 = ni2;
  }
  float r0=1.0f/(d0+1e-8f), r1=1.0f/(d1+1e-8f), r2=1.0f/(d2+1e-8f);
  float rs = r0+r1+r2;
  size_t base = (size_t)p*3;
  idx3[base]=i0; idx3[base+1]=i1; idx3[base+2]=i2;
  w3[base]=r0/rs; w3[base+1]=r1/rs; w3[base+2]=r2/rs;
}

// ---- tiled transpose: src f32 [B][C][NN] -> dst bf16 [B][NN][C] ----
template<int C, int NN>
__global__ __launch_bounds__(256) void tpose_kernel(const float* __restrict__ src, u16t* __restrict__ dst){
  __shared__ float tile[64][65];
  const int n0 = blockIdx.x * 64;
  const int c0 = blockIdx.y * 64;
  const int b  = blockIdx.z;
  const int t  = threadIdx.x;
  #pragma unroll
  for (int i = 0; i < 16; ++i){
    int idx = t + i*256;
    int cc = idx >> 6, nn = idx & 63;
    tile[cc][nn] = src[((size_t)b*C + c0 + cc)*NN + n0 + nn];
  }
  __syncthreads();
  #pragma unroll
  for (int i = 0; i < 16; ++i){
    int idx = t + i*256;
    int nn = idx >> 6, cc = idx & 63;
    dst[((size_t)b*NN + n0 + nn)*C + c0 + cc] = f2b(tile[cc][nn]);
  }
}

// ---- weight convert f32 -> bf16 into WB ----
__global__ __launch_bounds__(256) void wcvt_kernel(const float* __restrict__ w1, const float* __restrict__ w2,
                                                   const float* __restrict__ wg, const float* __restrict__ wx,
                                                   u16t* __restrict__ wb){
  int i = blockIdx.x*256 + threadIdx.x;
  if (i >= WTOTAL) return;
  float v;
  if      (i < WOFF_C2) v = w1[i];
  else if (i < WOFF_WG) v = w2[i - WOFF_C2];
  else if (i < WOFF_WX) v = wg[i - WOFF_WG];
  else                  v = wx[i - WOFF_WX];
  wb[i] = f2b(v);
}

// ---- interp: half-wave (32 lanes) per point (unchanged) ----
__global__ __launch_bounds__(256) void interp_kernel(const u16t* __restrict__ p2t, const int* __restrict__ idx3,
                                                     const float* __restrict__ w3, u16t* __restrict__ it){
  const int t = threadIdx.x;
  const int pid = blockIdx.x*8 + (t >> 5);
  const int l = t & 31;
  const int b = pid >> 14;
  size_t pb = (size_t)pid*3;
  int i0 = idx3[pb], i1 = idx3[pb+1], i2 = idx3[pb+2];
  float w0 = w3[pb], w1 = w3[pb+1], w2 = w3[pb+2];
  const u16t* r0 = p2t + ((size_t)b*SPTS + i0)*256 + l*8;
  const u16t* r1 = p2t + ((size_t)b*SPTS + i1)*256 + l*8;
  const u16t* r2 = p2t + ((size_t)b*SPTS + i2)*256 + l*8;
  uint4 q0 = *reinterpret_cast<const uint4*>(r0);
  uint4 q1 = *reinterpret_cast<const uint4*>(r1);
  uint4 q2 = *reinterpret_cast<const uint4*>(r2);
  const u32t* a0 = reinterpret_cast<const u32t*>(&q0);
  const u32t* a1 = reinterpret_cast<const u32t*>(&q1);
  const u32t* a2 = reinterpret_cast<const u32t*>(&q2);
  u32t ow[4];
  #pragma unroll
  for (int j = 0; j < 4; ++j){
    u32t u0 = a0[j], u1 = a1[j], u2 = a2[j];
    float lo = fmaf(w2, b2f((u16t)u2), fmaf(w1, b2f((u16t)u1), w0*b2f((u16t)u0)));
    float hi = fmaf(w2, b2f((u16t)(u2>>16)), fmaf(w1, b2f((u16t)(u1>>16)), w0*b2f((u16t)(u0>>16))));
    ow[j] = (u32t)f2b(lo) | ((u32t)f2b(hi) << 16);
  }
  *reinterpret_cast<uint4*>(it + (size_t)pid*256 + l*8) = make_uint4(ow[0], ow[1], ow[2], ow[3]);
}

// ---- MFMA conv1x1, 128-point tiles: LDS-staged acts (gload_lds w16, dbuf, XOR-swz),
//      psi-fold (SPLIT), per-block stats partials, C-tile via LDS in two 64-row passes ----
template<int CIN, int OUT, bool SPLIT>
__global__ __launch_bounds__(256, 1) void mfma_conv_kernel(const u16t* __restrict__ xa, const u16t* __restrict__ xb,
                                                           const u16t* __restrict__ W, const float* __restrict__ bias,
                                                           u16t* __restrict__ y, float* __restrict__ partial,
                                                           const float* __restrict__ psipre, const float* __restrict__ stpsi,
                                                           const float* __restrict__ pbn_g, const float* __restrict__ pbn_b){
  constexpr int MW = OUT/4;      // per-wave M slice
  constexpr int MF = MW/16;      // m-fragments per wave
  constexpr int NC = CIN/64;     // 64-channel k-chunks
  constexpr int CSTR = OUT + 8;  // padded ctile row stride (elems)
  constexpr int LDSE = (64*CSTR > 16384) ? 64*CSTR : 16384;   // staging dbuf (2x8192) unions ctile
  __shared__ u16t lds[LDSE];
  const int bid = blockIdx.x;
  const int b = bid >> 7;                 // 128 tiles per batch
  const int n0 = (bid & 127) * 128;       // 128-point tile
  const int wv = threadIdx.x >> 6;
  const int lane = threadIdx.x & 63;
  const int lr = lane & 15;
  const int kg = lane >> 4;
  const int m0 = wv * MW;
  const int t = threadIdx.x;

  float psiv[8];
  if (SPLIT){
    float m  = stpsi[0]*(1.0f/CNTF);
    float vv = fmaxf(stpsi[1]*(1.0f/CNTF) - m*m, 0.0f);
    float iv = 1.0f/sqrtf(vv + BNEPS);
    float ap = pbn_g[0]*iv;
    float bp = pbn_b[0] - m*ap;
    #pragma unroll
    for (int nf = 0; nf < 8; ++nf){
      float z = fmaf(psipre[b*NPTS + n0 + nf*16 + lr], ap, bp);
      psiv[nf] = 1.0f/(1.0f + expf(-z));
    }
  }

  f32x4 acc[MF][8];
  #pragma unroll
  for (int mf = 0; mf < MF; ++mf)
    #pragma unroll
    for (int nf = 0; nf < 8; ++nf){ acc[mf][nf][0]=0.f; acc[mf][nf][1]=0.f; acc[mf][nf][2]=0.f; acc[mf][nf][3]=0.f; }

  const u16t* wrow[MF];
  #pragma unroll
  for (int mf = 0; mf < MF; ++mf)
    wrow[mf] = W + (size_t)(m0 + mf*16 + lr)*CIN + kg*8;

  const int prow0 = wv*32 + (lane>>3);                 // +8 per staging instr (row&7 unchanged)
  const int gslot = (lane & 7) ^ ((lane >> 3) & 7);    // pre-swizzled source slot
  int rdoff[2][8];
  #pragma unroll
  for (int ks = 0; ks < 2; ++ks)
    #pragma unroll
    for (int nf = 0; nf < 8; ++nf)
      rdoff[ks][nf] = (nf*16 + lr)*64 + (((ks*4 + kg) ^ (lr & 7)) << 3);

  auto stage = [&](int c, int buf){
    #pragma unroll
    for (int i = 0; i < 4; ++i){
      int p = prow0 + i*8;
      const u16t* g;
      if (SPLIT){
        if (c < 2) g = xa + ((size_t)b*NPTS + n0 + p)*128 + c*64     + gslot*8;
        else       g = xb + ((size_t)b*NPTS + n0 + p)*256 + (c-2)*64 + gslot*8;
      } else {
        g = xa + ((size_t)b*NPTS + n0 + p)*CIN + c*64 + gslot*8;
      }
      u16t* l = lds + buf*8192 + (wv*32 + i*8)*64;   // wave-uniform base; HW adds lane*16B
      __builtin_amdgcn_global_load_lds(AS1(g), AS3(l), 16, 0, 0);
    }
  };

  stage(0, 0);
  __syncthreads();
  #pragma unroll
  for (int c = 0; c < NC; ++c){
    if (c + 1 < NC) stage(c+1, (c+1)&1);
    #pragma unroll
    for (int ks = 0; ks < 2; ++ks){
      const int k0 = c*2 + ks;
      s16x8 av[MF];
      #pragma unroll
      for (int mf = 0; mf < MF; ++mf)
        av[mf] = *reinterpret_cast<const s16x8*>(wrow[mf] + k0*32);
      #pragma unroll
      for (int h = 0; h < 2; ++h){
        s16x8 bv[4];
        #pragma unroll
        for (int j = 0; j < 4; ++j)
          bv[j] = *reinterpret_cast<const s16x8*>(lds + (c&1)*8192 + rdoff[ks][h*4+j]);
        #pragma unroll
        for (int mf = 0; mf < MF; ++mf)
          #pragma unroll
          for (int j = 0; j < 4; ++j)
            acc[mf][h*4+j] = __builtin_amdgcn_mfma_f32_16x16x32_bf16(av[mf], bv[j], acc[mf][h*4+j], 0, 0, 0);
      }
    }
    if (SPLIT && c == 1){
      #pragma unroll
      for (int mf = 0; mf < MF; ++mf)
        #pragma unroll
        for (int nf = 0; nf < 8; ++nf){
          acc[mf][nf][0] *= psiv[nf]; acc[mf][nf][1] *= psiv[nf];
          acc[mf][nf][2] *= psiv[nf]; acc[mf][nf][3] *= psiv[nf];
        }
    }
    __syncthreads();   // drains stage(c+1) vmcnt + syncs buf readers; after last iter, sbuf dead
  }

  // stats pass: bias into acc, accumulate per-channel sum/sumsq over all 8 nf
  #pragma unroll
  for (int mf = 0; mf < MF; ++mf){
    int mb = m0 + mf*16 + kg*4;
    float4 bs = *reinterpret_cast<const float4*>(bias + mb);
    float s0=0.f,s1=0.f,s2=0.f,s3=0.f,q0=0.f,q1=0.f,q2=0.f,q3=0.f;
    #pragma unroll
    for (int nf = 0; nf < 8; ++nf){
      float v0 = acc[mf][nf][0] + bs.x;
      float v1 = acc[mf][nf][1] + bs.y;
      float v2 = acc[mf][nf][2] + bs.z;
      float v3 = acc[mf][nf][3] + bs.w;
      acc[mf][nf][0]=v0; acc[mf][nf][1]=v1; acc[mf][nf][2]=v2; acc[mf][nf][3]=v3;
      s0+=v0; q0+=v0*v0; s1+=v1; q1+=v1*v1;
      s2+=v2; q2+=v2*v2; s3+=v3; q3+=v3*v3;
    }
    #pragma unroll
    for (int o = 1; o < 16; o <<= 1){
      s0 += __shfl_xor(s0, o); s1 += __shfl_xor(s1, o);
      s2 += __shfl_xor(s2, o); s3 += __shfl_xor(s3, o);
      q0 += __shfl_xor(q0, o); q1 += __shfl_xor(q1, o);
      q2 += __shfl_xor(q2, o); q3 += __shfl_xor(q3, o);
    }
    if (lr == 0){
      float* pp = partial + (size_t)bid*(OUT*2) + mb*2;
      pp[0]=s0; pp[1]=q0; pp[2]=s1; pp[3]=q1;
      pp[4]=s2; pp[5]=q2; pp[6]=s3; pp[7]=q3;
    }
  }

  // C-tile: two 64-row passes through LDS, full-row coalesced global stores
  constexpr int CH8 = OUT/8;
  #pragma unroll
  for (int h = 0; h < 2; ++h){
    __syncthreads();   // lds free (staging dead / previous copyout done)
    #pragma unroll
    for (int mf = 0; mf < MF; ++mf){
      int mb = m0 + mf*16 + kg*4;
      #pragma unroll
      for (int j = 0; j < 4; ++j){
        int row = j*16 + lr;
        f32x4 v = acc[mf][h*4+j];
        uint2 pv;
        pv.x = (u32t)f2b(v[0]) | ((u32t)f2b(v[1]) << 16);
        pv.y = (u32t)f2b(v[2]) | ((u32t)f2b(v[3]) << 16);
        *reinterpret_cast<uint2*>(&lds[row*CSTR + mb]) = pv;
      }
    }
    __syncthreads();
    #pragma unroll
    for (int i = 0; i < (64*CH8)/256; ++i){
      int idx = t + i*256;
      int row = idx / CH8, c8 = idx % CH8;
      uint4 v = *reinterpret_cast<const uint4*>(&lds[row*CSTR + c8*8]);
      *reinterpret_cast<uint4*>(y + ((size_t)b*NPTS + n0 + h*64 + row)*OUT + c8*8) = v;
    }
  }
}

// ---- reduce conv partials [512][E] -> stats[E] (no atomics) ----
template<int E>
__global__ __launch_bounds__(256) void reduce_stats_kernel(const float* __restrict__ p, float* __restrict__ st){
  __shared__ float ls[8][32];
  const int t = threadIdx.x;
  const int kq = t >> 5, es = t & 31;
  const int e = blockIdx.x*32 + es;
  float s = 0.f;
  const float* pp = p + (size_t)kq*64*E + e;
  #pragma unroll 16
  for (int i = 0; i < 64; ++i) s += pp[(size_t)i*E];
  ls[kq][es] = s;
  __syncthreads();
  if (kq == 0){
    st[e] = ((ls[0][es]+ls[1][es])+(ls[2][es]+ls[3][es]))
          + ((ls[4][es]+ls[5][es])+(ls[6][es]+ls[7][es]));
  }
}

// ---- gate (unchanged) ----
__global__ __launch_bounds__(256) void gate_kernel(const u16t* __restrict__ yg, const u16t* __restrict__ yx,
                                                   const float* __restrict__ stg, const float* __restrict__ stx,
                                                   const float* __restrict__ wg_bn_g, const float* __restrict__ wg_bn_b,
                                                   const float* __restrict__ wx_bn_g, const float* __restrict__ wx_bn_b,
                                                   const float* __restrict__ psi_w, const float* __restrict__ psi_b,
                                                   float* __restrict__ psipre, float* __restrict__ stpsi){
  __shared__ float lag[64], lbg[64], lax[64], lbx[64], lpw[64];
  __shared__ float red[8];
  const int t = threadIdx.x;
  if (t < 64){
    float m  = stg[t*2] * (1.0f/CNTF);
    float vv = fmaxf(stg[t*2+1]*(1.0f/CNTF) - m*m, 0.0f);
    float iv = 1.0f/sqrtf(vv + BNEPS);
    float gm = wg_bn_g[t];
    lag[t] = gm*iv; lbg[t] = wg_bn_b[t] - m*gm*iv;
    m  = stx[t*2] * (1.0f/CNTF);
    vv = fmaxf(stx[t*2+1]*(1.0f/CNTF) - m*m, 0.0f);
    iv = 1.0f/sqrtf(vv + BNEPS);
    gm = wx_bn_g[t];
    lax[t] = gm*iv; lbx[t] = wx_bn_b[t] - m*gm*iv;
    lpw[t] = psi_w[t];
  }
  __syncthreads();
  const int p = blockIdx.x*256 + t;
  const u16t* rg = yg + (size_t)p*64;
  const u16t* rx = yx + (size_t)p*64;
  float acc = psi_b[0];
  #pragma unroll
  for (int u = 0; u < 8; ++u){
    uint4 qg = *reinterpret_cast<const uint4*>(rg + u*8);
    uint4 qx = *reinterpret_cast<const uint4*>(rx + u*8);
    const u32t* g4 = reinterpret_cast<const u32t*>(&qg);
    const u32t* x4 = reinterpret_cast<const u32t*>(&qx);
    #pragma unroll
    for (int e = 0; e < 4; ++e){
      int j = u*8 + e*2;
      float gv0 = fmaf(b2f((u16t)g4[e]),        lag[j],   lbg[j]);
      float xv0 = fmaf(b2f((u16t)x4[e]),        lax[j],   lbx[j]);
      float gv1 = fmaf(b2f((u16t)(g4[e]>>16)),  lag[j+1], lbg[j+1]);
      float xv1 = fmaf(b2f((u16t)(x4[e]>>16)),  lax[j+1], lbx[j+1]);
      acc = fmaf(lpw[j],   lrelu(gv0 + xv0), acc);
      acc = fmaf(lpw[j+1], lrelu(gv1 + xv1), acc);
    }
  }
  psipre[p] = acc;
  float s = acc, q = acc*acc;
  #pragma unroll
  for (int o = 32; o; o >>= 1){ s += __shfl_xor(s, o); q += __shfl_xor(q, o); }
  if ((t & 63) == 0){ red[(t>>6)*2] = s; red[(t>>6)*2+1] = q; }
  __syncthreads();
  if (t == 0){
    atomicAdd(&stpsi[0], red[0]+red[2]+red[4]+red[6]);
    atomicAdd(&stpsi[1], red[1]+red[3]+red[5]+red[7]);
  }
}

// ---- bn1 + lrelu in place on h1 [P][256] bf16 ----
__global__ __launch_bounds__(256) void bnrelu256_kernel(u16t* __restrict__ x, const float* __restrict__ st,
                                                        const float* __restrict__ g, const float* __restrict__ bb){
  __shared__ float sa[256], sc[256];
  const int t = threadIdx.x;
  {
    float m  = st[t*2]*(1.0f/CNTF);
    float vv = fmaxf(st[t*2+1]*(1.0f/CNTF) - m*m, 0.0f);
    float iv = 1.0f/sqrtf(vv + BNEPS);
    float gm = g[t];
    sa[t] = gm*iv; sc[t] = bb[t] - m*gm*iv;
  }
  __syncthreads();
  size_t e4 = ((size_t)blockIdx.x*256 + t)*4;
  int c0 = (int)(e4 & 255);
  uint2 v = *reinterpret_cast<uint2*>(x + e4);
  float f0 = lrelu(fmaf(b2f((u16t)v.x),        sa[c0],   sc[c0]));
  float f1 = lrelu(fmaf(b2f((u16t)(v.x>>16)),  sa[c0+1], sc[c0+1]));
  float f2 = lrelu(fmaf(b2f((u16t)v.y),        sa[c0+2], sc[c0+2]));
  float f3 = lrelu(fmaf(b2f((u16t)(v.y>>16)),  sa[c0+3], sc[c0+3]));
  v.x = (u32t)f2b(f0) | ((u32t)f2b(f1) << 16);
  v.y = (u32t)f2b(f2) | ((u32t)f2b(f3) << 16);
  *reinterpret_cast<uint2*>(x + e4) = v;
}

// ---- final: out[b][m][n] f32 = lrelu(bn2(h2[b][n][m])) via LDS tile transpose ----
__global__ __launch_bounds__(256) void final_kernel(const u16t* __restrict__ h2, const float* __restrict__ st,
                                                    const float* __restrict__ g, const float* __restrict__ bb,
                                                    float* __restrict__ out){
  __shared__ float am[128], cm[128];
  __shared__ float tile[64][129];
  const int t = threadIdx.x;
  if (t < 128){
    float m  = st[t*2]*(1.0f/CNTF);
    float vv = fmaxf(st[t*2+1]*(1.0f/CNTF) - m*m, 0.0f);
    float iv = 1.0f/sqrtf(vv + BNEPS);
    float gm = g[t];
    am[t] = gm*iv; cm[t] = bb[t] - m*gm*iv;
  }
  __syncthreads();
  const int n0 = blockIdx.x * 64;
  const int b  = blockIdx.y;
  #pragma unroll
  for (int i = 0; i < 32; ++i){
    int idx = t + i*256;
    int mm = idx & 127, nn = idx >> 7;
    float v = fmaf(b2f(h2[((size_t)b*NPTS + n0 + nn)*128 + mm]), am[mm], cm[mm]);
    tile[nn][mm] = lrelu(v);
  }
  __syncthreads();
  #pragma unroll
  for (int i = 0; i < 32; ++i){
    int idx = t + i*256;
    int nn = idx & 63, mm = idx >> 6;
    out[((size_t)(b*128 + mm))*NPTS + n0 + nn] = tile[nn][mm];
  }
}

extern "C" void kernel_launch(void* const* d_in, const int* in_sizes, int n_in,
                              void* d_out, int out_size, void* d_ws, size_t ws_size,
                              hipStream_t stream){
  const float* xyz1    = (const float*)d_in[0];
  const float* xyz2    = (const float*)d_in[1];
  const float* points1 = (const float*)d_in[2];
  const float* points2 = (const float*)d_in[3];
  const float* conv1_w = (const float*)d_in[4];
  const float* conv1_b = (const float*)d_in[5];
  const float* bn1_g   = (const float*)d_in[6];
  const float* bn1_b   = (const float*)d_in[7];
  const float* conv2_w = (const float*)d_in[8];
  const float* conv2_b = (const float*)d_in[9];
  const float* bn2_g   = (const float*)d_in[10];
  const float* bn2_b   = (const float*)d_in[11];
  const float* wg_w    = (const float*)d_in[12];
  const float* wg_b    = (const float*)d_in[13];
  const float* wg_bn_g = (const float*)d_in[14];
  const float* wg_bn_b = (const float*)d_in[15];
  const float* wx_w    = (const float*)d_in[16];
  const float* wx_b    = (const float*)d_in[17];
  const float* wx_bn_g = (const float*)d_in[18];
  const float* wx_bn_b = (const float*)d_in[19];
  const float* psi_w   = (const float*)d_in[20];
  const float* psi_b   = (const float*)d_in[21];
  const float* psi_bn_g= (const float*)d_in[22];
  const float* psi_bn_b= (const float*)d_in[23];

  char* ws = (char*)d_ws;
  float* stats  = (float*)(ws + O_STATS);
  u16t*  wb     = (u16t*)(ws + O_WB);
  float* psipre = (float*)(ws + O_PSIPRE);
  float4* sp    = (float4*)(ws + O_SP);
  u16t*  p2t    = (u16t*)(ws + O_P2T);
  float* part   = (float*)(ws + O_PART);
  u16t*  p1t    = (u16t*)(ws + O_P1T);
  u16t*  itp    = (u16t*)(ws + O_INT);
  u16t*  h1t    = (u16t*)(ws + O_H1);
  float* pd     = (float*)(ws + O_PD);
  int*   pi     = (int*)(ws + O_PI);
  int*   idx3   = (int*)(ws + O_IDX3);
  float* w3     = (float*)(ws + O_W3);
  u16t*  ygt    = (u16t*)(ws + O_YG);
  u16t*  yxt    = (u16t*)(ws + O_YX);
  u16t*  h2t    = (u16t*)(ws + O_H2);

  hipMemsetAsync(ws + O_STATS, 0, 8192, stream);

  knn_prep_kernel<<<(Bq*SPTS)/256, 256, 0, stream>>>(xyz2, sp);
  knn_part_kernel<<<dim3(NPTS/256, NCH, Bq), 256, 0, stream>>>(xyz1, sp, pd, pi);
  knn_merge_kernel<<<(Bq*NPTS)/256, 256, 0, stream>>>(pd, pi, idx3, w3);
  tpose_kernel<256, SPTS><<<dim3(SPTS/64, 4, Bq), 256, 0, stream>>>(points2, p2t);
  interp_kernel<<<(Bq*NPTS)/8, 256, 0, stream>>>(p2t, idx3, w3, itp);
  tpose_kernel<128, NPTS><<<dim3(NPTS/64, 2, Bq), 256, 0, stream>>>(points1, p1t);
  wcvt_kernel<<<(WTOTAL+255)/256, 256, 0, stream>>>(conv1_w, conv2_w, wg_w, wx_w, wb);

  mfma_conv_kernel<256, 64, false><<<Bq*(NPTS/128), 256, 0, stream>>>(itp, nullptr, wb+WOFF_WG, wg_b, ygt, part,
                                                                      nullptr, nullptr, nullptr, nullptr);
  reduce_stats_kernel<128><<<4, 256, 0, stream>>>(part, stats+ST_WG);
  mfma_conv_kernel<128, 64, false><<<Bq*(NPTS/128), 256, 0, stream>>>(p1t, nullptr, wb+WOFF_WX, wx_b, yxt, part,
                                                                      nullptr, nullptr, nullptr, nullptr);
  reduce_stats_kernel<128><<<4, 256, 0, stream>>>(part, stats+ST_WX);
  gate_kernel<<<256, 256, 0, stream>>>(ygt, yxt, stats+ST_WG, stats+ST_WX,
                                       wg_bn_g, wg_bn_b, wx_bn_g, wx_bn_b,
                                       psi_w, psi_b, psipre, stats+ST_PSI);

  mfma_conv_kernel<384, 256, true><<<Bq*(NPTS/128), 256, 0, stream>>>(p1t, itp, wb+WOFF_C1, conv1_b, h1t, part,
                                                                      psipre, stats+ST_PSI, psi_bn_g, psi_bn_b);
  reduce_stats_kernel<512><<<16, 256, 0, stream>>>(part, stats+ST_BN1);
  bnrelu256_kernel<<<16384, 256, 0, stream>>>(h1t, stats+ST_BN1, bn1_g, bn1_b);

  mfma_conv_kernel<256, 128, false><<<Bq*(NPTS/128), 256, 0, stream>>>(h1t, nullptr, wb+WOFF_C2, conv2_b, h2t, part,
                                                                       nullptr, nullptr, nullptr, nullptr);
  reduce_stats_kernel<256><<<8, 256, 0, stream>>>(part, stats+ST_BN2);
  final_kernel<<<dim3(NPTS/64, Bq), 256, 0, stream>>>(h2t, stats+ST_BN2, bn2_g, bn2_b, (float*)d_out);
}